// Round 12
// baseline (223.325 us; speedup 1.0000x reference)
//
#include <hip/hip_runtime.h>

#define C_DIM  384
#define HEADS  6
#define HD     64
#define FF_DIM 1536
#define LN_EPS 1e-3f
#define TSEQ   2048
#define BATCH  4
#define LOG2E  1.4426950408889634f
#define QK_SCALE 0.18033688011112042f   // 0.125 * log2(e), folded into Q

typedef __attribute__((ext_vector_type(4))) float          f32x4;
typedef __attribute__((ext_vector_type(4))) float          float4_t;
typedef __attribute__((ext_vector_type(8))) short          bfrag;     // 8 bf16
typedef __attribute__((ext_vector_type(4))) unsigned short ushort4_t;
typedef __attribute__((ext_vector_type(8))) unsigned short ushort8_t;

__device__ inline unsigned short f2bf(float f) {
    unsigned int u = __builtin_bit_cast(unsigned int, f);
    u += 0x7fff + ((u >> 16) & 1);          // RNE
    return (unsigned short)(u >> 16);
}
// truncating convert — P matrix only (values in [0,1], re-normalized)
__device__ inline unsigned short f2bf_t(float f) {
    return (unsigned short)(__builtin_bit_cast(unsigned int, f) >> 16);
}

// async global->LDS, 16 B per lane. LDS dest is wave-uniform base + lane*16.
__device__ inline void gload_lds16(const void* g, void* l) {
    __builtin_amdgcn_global_load_lds(
        (const __attribute__((address_space(1))) unsigned int*)g,
        (__attribute__((address_space(3))) unsigned int*)l,
        16, 0, 0);
}

// ---------------------------------------------------------------------------
// Batched transpose+convert of the four 384x384 weights: W[K][N] f32 -> Wt[N][K] bf16.
// ---------------------------------------------------------------------------
__global__ __launch_bounds__(256)
void transpose_w4(const float* __restrict__ Wq, const float* __restrict__ Wk,
                  const float* __restrict__ Wv, const float* __restrict__ Wo,
                  unsigned short* __restrict__ Dq, unsigned short* __restrict__ Dk,
                  unsigned short* __restrict__ Dv, unsigned short* __restrict__ Do_)
{
    __shared__ float tile[32][33];
    const int z = blockIdx.z;
    const float* W = z == 0 ? Wq : (z == 1 ? Wk : (z == 2 ? Wv : Wo));
    unsigned short* D = z == 0 ? Dq : (z == 1 ? Dk : (z == 2 ? Dv : Do_));
    const int tx = threadIdx.x, ty = threadIdx.y;
    const int n0 = blockIdx.x * 32, k0 = blockIdx.y * 32;
    #pragma unroll
    for (int i = 0; i < 32; i += 8)
        tile[ty + i][tx] = W[(size_t)(k0 + ty + i) * C_DIM + n0 + tx];
    __syncthreads();
    #pragma unroll
    for (int i = 0; i < 32; i += 8)
        D[(size_t)(n0 + ty + i) * C_DIM + k0 + tx] = f2bf(tile[tx][ty + i]);
}

// generic transpose: W[K][N] f32 -> Wt[N][K] bf16
__global__ __launch_bounds__(256)
void transpose_w(const float* __restrict__ W, unsigned short* __restrict__ Wt, int K, int N)
{
    __shared__ float tile[32][33];
    const int tx = threadIdx.x, ty = threadIdx.y;
    const int n0 = blockIdx.x * 32, k0 = blockIdx.y * 32;
    #pragma unroll
    for (int i = 0; i < 32; i += 8)
        tile[ty + i][tx] = W[(size_t)(k0 + ty + i) * N + n0 + tx];
    __syncthreads();
    #pragma unroll
    for (int i = 0; i < 32; i += 8)
        Wt[(size_t)(n0 + ty + i) * K + k0 + tx] = f2bf(tile[tx][ty + i]);
}

__global__ __launch_bounds__(256)
void cvt_f32_bf16_x4(const float* __restrict__ in, unsigned short* __restrict__ out, int n4)
{
    int i = blockIdx.x * 256 + threadIdx.x;
    if (i >= n4) return;
    float4_t v = ((const float4_t*)in)[i];
    ushort4_t o = { f2bf(v.x), f2bf(v.y), f2bf(v.z), f2bf(v.w) };
    ((ushort4_t*)out)[i] = o;
}

// ---------------------------------------------------------------------------
// V transpose + K repack: qkv v-cols -> vt[bh][d][t]; qkv k-cols -> ktc[bh][t][d]
// (contiguous 128B rows per head -> K tile = one 8KB contiguous block).
// ---------------------------------------------------------------------------
__global__ __launch_bounds__(256)
void vtrans_kernel(const unsigned short* __restrict__ qkv,
                   unsigned short* __restrict__ vt,
                   unsigned short* __restrict__ ktc)
{
    __shared__ unsigned short tile[32][34];
    const int tx = threadIdx.x, ty = threadIdx.y;
    const int bh = blockIdx.z, b = bh / HEADS, h = bh % HEADS;
    const int t0 = blockIdx.x * 32, d0 = blockIdx.y * 32;
    #pragma unroll
    for (int i = 0; i < 32; i += 8) {
        tile[ty + i][tx] = qkv[(size_t)(b * TSEQ + t0 + ty + i) * 1152 + 2 * C_DIM + h * HD + d0 + tx];
        // K repack (no transpose, just de-stride)
        ktc[((size_t)bh * TSEQ + t0 + ty + i) * HD + d0 + tx] =
            qkv[(size_t)(b * TSEQ + t0 + ty + i) * 1152 + C_DIM + h * HD + d0 + tx];
    }
    __syncthreads();
    #pragma unroll
    for (int i = 0; i < 32; i += 8)
        vt[((size_t)bh * HD + d0 + ty + i) * TSEQ + t0 + tx] = tile[tx][ty + i];
}

// ---------------------------------------------------------------------------
// LDS-staged bf16 MFMA GEMM (m97 structure), fragment-major gload_lds staging.
// QSCALE: multiply output cols < C_DIM by QK_SCALE (folds attn scale into Q).
// ---------------------------------------------------------------------------
template<int OBF16, int BIAS, int RELU, int QSCALE>
__global__ __launch_bounds__(256)
void gemm_lds(const unsigned short* __restrict__ A, const unsigned short* __restrict__ Bt,
              const float* __restrict__ bias, void* __restrict__ Cv,
              int M, int N, int K)
{
    __shared__ __align__(16) unsigned short As[16 * 512];   // 16 frags x 1KB
    __shared__ __align__(16) unsigned short Bs[16 * 512];

    const int t = threadIdx.x, lane = t & 63, w = t >> 6;
    const int ln16 = lane & 15, hi16 = lane >> 4;
    const int wr = w >> 1, wc = w & 1;
    const int row0 = blockIdx.y * 128, col0 = blockIdx.x * 128;

    f32x4 acc[4][4] = {};

    for (int k0 = 0; k0 < K; k0 += 64) {
        #pragma unroll
        for (int i = 0; i < 4; ++i) {
            const int f  = w * 4 + i;
            const int ks = f >> 3, rf = f & 7;
            const int row = rf * 16 + ln16;
            const int kc  = k0 + ks * 32 + hi16 * 8;
            gload_lds16(&A [(size_t)(row0 + row) * K + kc], &As[f * 512]);
            gload_lds16(&Bt[(size_t)(col0 + row) * K + kc], &Bs[f * 512]);
        }
        __syncthreads();
        #pragma unroll
        for (int ks = 0; ks < 2; ++ks) {
            bfrag a[4], b[4];
            #pragma unroll
            for (int i = 0; i < 4; ++i)
                a[i] = *(const bfrag*)&As[(ks * 8 + wr * 4 + i) * 512 + lane * 8];
            #pragma unroll
            for (int j = 0; j < 4; ++j)
                b[j] = *(const bfrag*)&Bs[(ks * 8 + wc * 4 + j) * 512 + lane * 8];
            #pragma unroll
            for (int i = 0; i < 4; ++i)
                #pragma unroll
                for (int j = 0; j < 4; ++j)
                    acc[i][j] = __builtin_amdgcn_mfma_f32_16x16x32_bf16(a[i], b[j], acc[i][j], 0, 0, 0);
        }
        __syncthreads();
    }

    #pragma unroll
    for (int j = 0; j < 4; ++j) {
        const int col = col0 + wc * 64 + j * 16 + ln16;
        const float bv = BIAS ? bias[col] : 0.0f;
        const float sc = (QSCALE && col < C_DIM) ? QK_SCALE : 1.0f;
        #pragma unroll
        for (int i = 0; i < 4; ++i) {
            #pragma unroll
            for (int e = 0; e < 4; ++e) {
                const int row = row0 + wr * 64 + i * 16 + hi16 * 4 + e;
                float v = acc[i][j][e] + bv;
                if (RELU) v = fmaxf(v, 0.0f);
                if (QSCALE) v *= sc;
                if (OBF16) ((unsigned short*)Cv)[(size_t)row * N + col] = f2bf(v);
                else       ((float*)Cv)[(size_t)row * N + col] = v;
            }
        }
    }
}

// ---------------------------------------------------------------------------
// attention helpers
// ---------------------------------------------------------------------------
__device__ inline void qk16(const bfrag (&qf)[2][2], const bfrag (&kf)[4][2],
                            f32x4 (&sf)[2][4])
{
    #pragma unroll
    for (int jt = 0; jt < 4; ++jt)
        #pragma unroll
        for (int ks = 0; ks < 2; ++ks) {
            sf[0][jt] = __builtin_amdgcn_mfma_f32_16x16x32_bf16(qf[0][ks], kf[jt][ks], sf[0][jt], 0, 0, 0);
            sf[1][jt] = __builtin_amdgcn_mfma_f32_16x16x32_bf16(qf[1][ks], kf[jt][ks], sf[1][jt], 0, 0, 0);
        }
}

// softmax + PV. Mask applied on the fly (no p[] temp -> lower VGPR pressure).
__device__ inline void softmax_pv(f32x4 (&sf)[2][4], const bfrag (&vf)[4][2],
                                  f32x4 (&acc)[2][4],
                                  float (&mrow)[2][4], float (&lrow)[2][4],
                                  unsigned short (*Ps)[72],
                                  int tok0, int kt, bool last, int ln16, int hi16)
{
    // masked lane-local max per (rf,e)
    float lmax[2][4];
    bool need = false;
    #pragma unroll
    for (int rf = 0; rf < 2; ++rf)
        #pragma unroll
        for (int e = 0; e < 4; ++e) {
            const int row = tok0 + rf * 16 + hi16 * 4 + e;
            float mx = -1e30f;
            #pragma unroll
            for (int jt = 0; jt < 4; ++jt) {
                float sv = sf[rf][jt][e];
                if (last && (kt * 64 + jt * 16 + ln16 > row)) sv = -1e30f;
                mx = fmaxf(mx, sv);
            }
            lmax[rf][e] = mx;
            need = need || (mx > mrow[rf][e] + 8.0f);
        }
    if (__any(need)) {
        #pragma unroll
        for (int rf = 0; rf < 2; ++rf)
            #pragma unroll
            for (int e = 0; e < 4; ++e) {
                float rm = lmax[rf][e];
                rm = fmaxf(rm, __shfl_xor(rm, 1));
                rm = fmaxf(rm, __shfl_xor(rm, 2));
                rm = fmaxf(rm, __shfl_xor(rm, 4));
                rm = fmaxf(rm, __shfl_xor(rm, 8));
                const float mn = fmaxf(mrow[rf][e], rm);
                const float corr = exp2f(mrow[rf][e] - mn);
                mrow[rf][e] = mn;
                lrow[rf][e] *= corr;
                #pragma unroll
                for (int dt = 0; dt < 4; ++dt) acc[rf][dt][e] *= corr;
            }
    }

    // exp2 (mask recomputed), per-lane l partial, P -> LDS
    #pragma unroll
    for (int rf = 0; rf < 2; ++rf)
        #pragma unroll
        for (int jt = 0; jt < 4; ++jt)
            #pragma unroll
            for (int e = 0; e < 4; ++e) {
                const int row = tok0 + rf * 16 + hi16 * 4 + e;
                float sv = sf[rf][jt][e];
                if (last && (kt * 64 + jt * 16 + ln16 > row)) sv = -1e30f;
                const float pe = exp2f(sv - mrow[rf][e]);
                lrow[rf][e] += pe;
                Ps[rf * 16 + hi16 * 4 + e][jt * 16 + ln16] = f2bf_t(pe);
            }

    // PV
    bfrag pf[2][2];
    #pragma unroll
    for (int rf = 0; rf < 2; ++rf)
        #pragma unroll
        for (int ks = 0; ks < 2; ++ks)
            pf[rf][ks] = *(const bfrag*)&Ps[rf * 16 + ln16][ks * 32 + hi16 * 8];
    #pragma unroll
    for (int ks = 0; ks < 2; ++ks)
        #pragma unroll
        for (int rf = 0; rf < 2; ++rf)
            #pragma unroll
            for (int dt = 0; dt < 4; ++dt)
                acc[rf][dt] = __builtin_amdgcn_mfma_f32_16x16x32_bf16(pf[rf][ks], vf[dt][ks], acc[rf][dt], 0, 0, 0);
}

// ---------------------------------------------------------------------------
// Flash attention, 1 wave per 32-row strip (r4 shape), contiguous-K (ktc),
// 2-deep K/V register pipeline: tile kt+1's kf AND vf are issued a FULL
// iteration before use (counted-vmcnt covers even L2-miss latency).
// bid&7 XCD swizzle (round-robin confirmed r10); heavy strips first.
// ---------------------------------------------------------------------------
__global__ __launch_bounds__(64)
void attn_kernel(const unsigned short* __restrict__ qkv,
                 const unsigned short* __restrict__ ktc,
                 const unsigned short* __restrict__ vt,
                 unsigned short* __restrict__ att)
{
    __shared__ __align__(16) unsigned short Ps[32][72];
    const int lane = threadIdx.x;
    const int ln16 = lane & 15, hi16 = lane >> 4;
    const int bid = blockIdx.x;            // 0..1535
    const int xcd = bid & 7;
    const int i2  = bid >> 3;              // 0..191
    const int bh  = xcd * 3 + (i2 >> 6);   // 3 bh per XCD
    const int qw  = 63 - (i2 & 63);        // heavy strips first
    const int b   = bh / HEADS, h = bh % HEADS;
    const int tok0 = qw * 32;
    const size_t qrow0 = (size_t)b * TSEQ;
    const int NT = (qw >> 1) + 1;

    bfrag qf[2][2];
    #pragma unroll
    for (int rf = 0; rf < 2; ++rf)
        #pragma unroll
        for (int ks = 0; ks < 2; ++ks)
            qf[rf][ks] = *(const bfrag*)&qkv[(qrow0 + tok0 + rf * 16 + ln16) * 1152 + h * HD + ks * 32 + hi16 * 8];

    f32x4 acc[2][4] = {};
    float mrow[2][4], lrow[2][4];
    #pragma unroll
    for (int rf = 0; rf < 2; ++rf)
        #pragma unroll
        for (int e = 0; e < 4; ++e) { mrow[rf][e] = -1e30f; lrow[rf][e] = 0.0f; }

    const unsigned short* Kb = ktc + (size_t)bh * TSEQ * HD;
    const unsigned short* Vb = vt  + (size_t)bh * HD * TSEQ;

    auto loadK = [&](bfrag (&kf)[4][2], int kt) {
        #pragma unroll
        for (int jt = 0; jt < 4; ++jt)
            #pragma unroll
            for (int ks = 0; ks < 2; ++ks)
                kf[jt][ks] = *(const bfrag*)&Kb[(size_t)(kt * 64 + jt * 16 + ln16) * HD + ks * 32 + hi16 * 8];
    };
    auto loadV = [&](bfrag (&vf)[4][2], int kt) {
        #pragma unroll
        for (int dt = 0; dt < 4; ++dt)
            #pragma unroll
            for (int ks = 0; ks < 2; ++ks)
                vf[dt][ks] = *(const bfrag*)&Vb[(size_t)(dt * 16 + ln16) * TSEQ + kt * 64 + ks * 32 + hi16 * 8];
    };

    bfrag kfa[4][2], vfa[4][2], kfb[4][2], vfb[4][2];
    loadK(kfa, 0); loadV(vfa, 0);
    int kt = 0;
    for (;;) {
        if (kt + 1 < NT) { loadK(kfb, kt + 1); loadV(vfb, kt + 1); }
        {
            f32x4 sf[2][4] = {};
            qk16(qf, kfa, sf);
            softmax_pv(sf, vfa, acc, mrow, lrow, Ps, tok0, kt, kt == NT - 1, ln16, hi16);
        }
        if (++kt >= NT) break;
        if (kt + 1 < NT) { loadK(kfa, kt + 1); loadV(vfa, kt + 1); }
        {
            f32x4 sf[2][4] = {};
            qk16(qf, kfb, sf);
            softmax_pv(sf, vfb, acc, mrow, lrow, Ps, tok0, kt, kt == NT - 1, ln16, hi16);
        }
        if (++kt >= NT) break;
    }

    // epilogue: reduce l across the 16-lane groups, normalize, store
    #pragma unroll
    for (int rf = 0; rf < 2; ++rf)
        #pragma unroll
        for (int e = 0; e < 4; ++e) {
            float l = lrow[rf][e];
            l += __shfl_xor(l, 1);
            l += __shfl_xor(l, 2);
            l += __shfl_xor(l, 4);
            l += __shfl_xor(l, 8);
            const float inv = 1.0f / l;
            const size_t row = qrow0 + tok0 + rf * 16 + hi16 * 4 + e;
            #pragma unroll
            for (int dt = 0; dt < 4; ++dt)
                att[row * C_DIM + h * HD + dt * 16 + ln16] = f2bf(acc[rf][dt][e] * inv);
        }
}

// ---------------------------------------------------------------------------
// Fused residual add + LayerNorm; optionally also emits bf16 copy.
// ---------------------------------------------------------------------------
template<int WB>
__global__ __launch_bounds__(256)
void ln_residual_kernel(const float* __restrict__ A, const float* __restrict__ R,
                        const float* __restrict__ gamma, const float* __restrict__ beta,
                        float* __restrict__ out, unsigned short* __restrict__ outb, int Mrows)
{
    const int lane = threadIdx.x & 63;
    const int wv   = threadIdx.x >> 6;
    const int row  = blockIdx.x * 4 + wv;
    if (row >= Mrows) return;
    const size_t off = (size_t)row * C_DIM;

    float v[6];
    float sum = 0.0f;
    #pragma unroll
    for (int j = 0; j < 6; ++j) {
        const int c = lane + 64 * j;
        v[j] = A[off + c] + R[off + c];
        sum += v[j];
    }
    #pragma unroll
    for (int o = 1; o < 64; o <<= 1) sum += __shfl_xor(sum, o);
    const float mu = sum * (1.0f / C_DIM);

    float sq = 0.0f;
    #pragma unroll
    for (int j = 0; j < 6; ++j) { const float d = v[j] - mu; sq = fmaf(d, d, sq); }
    #pragma unroll
    for (int o = 1; o < 64; o <<= 1) sq += __shfl_xor(sq, o);
    const float rstd = rsqrtf(sq * (1.0f / C_DIM) + LN_EPS);

    #pragma unroll
    for (int j = 0; j < 6; ++j) {
        const int c = lane + 64 * j;
        const float r = (v[j] - mu) * rstd * gamma[c] + beta[c];
        out[off + c] = r;
        if (WB) outb[off + c] = f2bf(r);
    }
}

// ---------------------------------------------------------------------------
extern "C" void kernel_launch(void* const* d_in, const int* in_sizes, int n_in,
                              void* d_out, int out_size, void* d_ws, size_t ws_size,
                              hipStream_t stream)
{
    const float* x   = (const float*)d_in[0];
    const float* Wq  = (const float*)d_in[1];
    const float* Wk  = (const float*)d_in[2];
    const float* Wv  = (const float*)d_in[3];
    const float* Wo  = (const float*)d_in[4];
    const float* bo  = (const float*)d_in[5];
    const float* W1  = (const float*)d_in[6];
    const float* b1  = (const float*)d_in[7];
    const float* W2  = (const float*)d_in[8];
    const float* b2  = (const float*)d_in[9];
    const float* g1  = (const float*)d_in[10];
    const float* be1 = (const float*)d_in[11];
    const float* g2  = (const float*)d_in[12];
    const float* be2 = (const float*)d_in[13];
    float* out = (float*)d_out;

    const int M = BATCH * TSEQ;                  // 8192
    const size_t MC = (size_t)M * C_DIM;

    // ---- workspace layout (bytes) ----
    char* ws = (char*)d_ws;
    unsigned short* qkv = (unsigned short*)ws;                       // M*1152*2 = 18.87 MB
    unsigned short* vt  = (unsigned short*)(ws + (size_t)M*1152*2);  // 6.29 MB
    unsigned short* att = (unsigned short*)(ws + (size_t)M*1152*2 + (size_t)BATCH*HEADS*HD*TSEQ*2); // 6.29 MB
    unsigned short* h1  = (unsigned short*)ws;                       // M*1536*2, aliases qkv+vt
    char* p2 = ws + (size_t)M*1152*2 + (size_t)BATCH*HEADS*HD*TSEQ*2 + MC*2;   // 31.46 MB mark
    unsigned short* xb  = (unsigned short*)p2;                       // MC bf16 (dead after QKV gemm)
    unsigned short* ktc = xb;                                        // aliases xb: 24*2048*64 bf16 = same size
    float* y   = (float*)(p2 + MC*2);                                // MC f32
    float* x1  = (float*)(p2 + MC*2 + MC*4);                         // MC f32
    unsigned short* x1b = (unsigned short*)(p2 + MC*2 + 2*MC*4);     // MC bf16
    char* p3 = p2 + MC*2 + 2*MC*4 + MC*2;
    unsigned short* Wqkv_t = (unsigned short*)p3;                        // [1152][384]
    unsigned short* Wo_t   = Wqkv_t + (size_t)3*C_DIM*C_DIM;             // [384][384]
    unsigned short* W1_t   = Wo_t   + (size_t)C_DIM*C_DIM;               // [1536][384]
    unsigned short* W2_t   = W1_t   + (size_t)FF_DIM*C_DIM;              // [384][1536]

    dim3 b256(256), b328(32, 8);

    // ---- weight transposes (f32 -> bf16 [N][K]) ----
    transpose_w4<<<dim3(C_DIM/32, C_DIM/32, 4), b328, 0, stream>>>(
        Wq, Wk, Wv, Wo,
        Wqkv_t, Wqkv_t + (size_t)C_DIM*C_DIM, Wqkv_t + (size_t)2*C_DIM*C_DIM, Wo_t);
    transpose_w<<<dim3(FF_DIM/32, C_DIM/32), b328, 0, stream>>>(W1, W1_t, C_DIM, FF_DIM);
    transpose_w<<<dim3(C_DIM/32, FF_DIM/32), b328, 0, stream>>>(W2, W2_t, FF_DIM, C_DIM);

    // ---- x -> bf16 ----
    cvt_f32_bf16_x4<<<dim3((MC/4 + 255)/256), b256, 0, stream>>>(x, xb, (int)(MC/4));

    // ---- qkv = xb @ Wqkv (Q cols pre-scaled by 0.125*log2e) ----
    gemm_lds<1, 0, 0, 1><<<dim3(3*C_DIM/128, M/128), b256, 0, stream>>>(
        xb, Wqkv_t, nullptr, qkv, M, 3*C_DIM, C_DIM);

    // ---- V transpose + K repack (ktc overwrites dead xb) ----
    vtrans_kernel<<<dim3(TSEQ/32, HD/32, BATCH*HEADS), b328, 0, stream>>>(qkv, vt, ktc);

    // ---- attention: 1536 single-strip waves, contiguous K, 2-deep pipeline ----
    attn_kernel<<<dim3(1536), dim3(64), 0, stream>>>(qkv, ktc, vt, att);

    // ---- y = att @ Wo + bo ----
    gemm_lds<0, 1, 0, 0><<<dim3(C_DIM/128, M/128), b256, 0, stream>>>(
        att, Wo_t, bo, y, M, C_DIM, C_DIM);

    // ---- x1 = LN(x + y), also bf16 ----
    ln_residual_kernel<1><<<dim3(M/4), b256, 0, stream>>>(x, y, g1, be1, x1, x1b, M);

    // ---- h1 = relu(x1b @ W1 + b1) ----
    gemm_lds<1, 1, 1, 0><<<dim3(FF_DIM/128, M/128), b256, 0, stream>>>(
        x1b, W1_t, b1, h1, M, FF_DIM, C_DIM);

    // ---- y = h1 @ W2 + b2 ----
    gemm_lds<0, 1, 0, 0><<<dim3(C_DIM/128, M/128), b256, 0, stream>>>(
        h1, W2_t, b2, y, M, C_DIM, FF_DIM);

    // ---- out = LN(x1 + y) ----
    ln_residual_kernel<0><<<dim3(M/4), b256, 0, stream>>>(x1, y, g2, be2, out, nullptr, M);
}

// Round 13
// 222.606 us; speedup vs baseline: 1.0032x; 1.0032x over previous
//
#include <hip/hip_runtime.h>

#define C_DIM  384
#define HEADS  6
#define HD     64
#define FF_DIM 1536
#define LN_EPS 1e-3f
#define TSEQ   2048
#define BATCH  4
#define LOG2E  1.4426950408889634f
#define QK_SCALE 0.18033688011112042f   // 0.125 * log2(e), folded into Q

typedef __attribute__((ext_vector_type(4))) float          f32x4;
typedef __attribute__((ext_vector_type(4))) float          float4_t;
typedef __attribute__((ext_vector_type(8))) short          bfrag;     // 8 bf16
typedef __attribute__((ext_vector_type(4))) unsigned short ushort4_t;
typedef __attribute__((ext_vector_type(8))) unsigned short ushort8_t;

__device__ inline unsigned short f2bf(float f) {
    unsigned int u = __builtin_bit_cast(unsigned int, f);
    u += 0x7fff + ((u >> 16) & 1);          // RNE
    return (unsigned short)(u >> 16);
}
// truncating convert — P matrix only (values in [0,1], re-normalized)
__device__ inline unsigned short f2bf_t(float f) {
    return (unsigned short)(__builtin_bit_cast(unsigned int, f) >> 16);
}

// async global->LDS, 16 B per lane. LDS dest is wave-uniform base + lane*16.
__device__ inline void gload_lds16(const void* g, void* l) {
    __builtin_amdgcn_global_load_lds(
        (const __attribute__((address_space(1))) unsigned int*)g,
        (__attribute__((address_space(3))) unsigned int*)l,
        16, 0, 0);
}

// ---------------------------------------------------------------------------
// Batched transpose+convert of the four 384x384 weights: W[K][N] f32 -> Wt[N][K] bf16.
// ---------------------------------------------------------------------------
__global__ __launch_bounds__(256)
void transpose_w4(const float* __restrict__ Wq, const float* __restrict__ Wk,
                  const float* __restrict__ Wv, const float* __restrict__ Wo,
                  unsigned short* __restrict__ Dq, unsigned short* __restrict__ Dk,
                  unsigned short* __restrict__ Dv, unsigned short* __restrict__ Do_)
{
    __shared__ float tile[32][33];
    const int z = blockIdx.z;
    const float* W = z == 0 ? Wq : (z == 1 ? Wk : (z == 2 ? Wv : Wo));
    unsigned short* D = z == 0 ? Dq : (z == 1 ? Dk : (z == 2 ? Dv : Do_));
    const int tx = threadIdx.x, ty = threadIdx.y;
    const int n0 = blockIdx.x * 32, k0 = blockIdx.y * 32;
    #pragma unroll
    for (int i = 0; i < 32; i += 8)
        tile[ty + i][tx] = W[(size_t)(k0 + ty + i) * C_DIM + n0 + tx];
    __syncthreads();
    #pragma unroll
    for (int i = 0; i < 32; i += 8)
        D[(size_t)(n0 + ty + i) * C_DIM + k0 + tx] = f2bf(tile[tx][ty + i]);
}

// generic transpose: W[K][N] f32 -> Wt[N][K] bf16
__global__ __launch_bounds__(256)
void transpose_w(const float* __restrict__ W, unsigned short* __restrict__ Wt, int K, int N)
{
    __shared__ float tile[32][33];
    const int tx = threadIdx.x, ty = threadIdx.y;
    const int n0 = blockIdx.x * 32, k0 = blockIdx.y * 32;
    #pragma unroll
    for (int i = 0; i < 32; i += 8)
        tile[ty + i][tx] = W[(size_t)(k0 + ty + i) * N + n0 + tx];
    __syncthreads();
    #pragma unroll
    for (int i = 0; i < 32; i += 8)
        Wt[(size_t)(n0 + ty + i) * K + k0 + tx] = f2bf(tile[tx][ty + i]);
}

__global__ __launch_bounds__(256)
void cvt_f32_bf16_x4(const float* __restrict__ in, unsigned short* __restrict__ out, int n4)
{
    int i = blockIdx.x * 256 + threadIdx.x;
    if (i >= n4) return;
    float4_t v = ((const float4_t*)in)[i];
    ushort4_t o = { f2bf(v.x), f2bf(v.y), f2bf(v.z), f2bf(v.w) };
    ((ushort4_t*)out)[i] = o;
}

// ---------------------------------------------------------------------------
// V transpose + K repack: qkv v-cols -> vt[bh][d][t]; qkv k-cols -> ktc[bh][t][d]
// ---------------------------------------------------------------------------
__global__ __launch_bounds__(256)
void vtrans_kernel(const unsigned short* __restrict__ qkv,
                   unsigned short* __restrict__ vt,
                   unsigned short* __restrict__ ktc)
{
    __shared__ unsigned short tile[32][34];
    const int tx = threadIdx.x, ty = threadIdx.y;
    const int bh = blockIdx.z, b = bh / HEADS, h = bh % HEADS;
    const int t0 = blockIdx.x * 32, d0 = blockIdx.y * 32;
    #pragma unroll
    for (int i = 0; i < 32; i += 8) {
        tile[ty + i][tx] = qkv[(size_t)(b * TSEQ + t0 + ty + i) * 1152 + 2 * C_DIM + h * HD + d0 + tx];
        ktc[((size_t)bh * TSEQ + t0 + ty + i) * HD + d0 + tx] =
            qkv[(size_t)(b * TSEQ + t0 + ty + i) * 1152 + C_DIM + h * HD + d0 + tx];
    }
    __syncthreads();
    #pragma unroll
    for (int i = 0; i < 32; i += 8)
        vt[((size_t)bh * HD + d0 + ty + i) * TSEQ + t0 + tx] = tile[tx][ty + i];
}

// ---------------------------------------------------------------------------
// LDS-staged bf16 MFMA GEMM (m97 structure), fragment-major gload_lds staging.
// ---------------------------------------------------------------------------
template<int OBF16, int BIAS, int RELU, int QSCALE>
__global__ __launch_bounds__(256)
void gemm_lds(const unsigned short* __restrict__ A, const unsigned short* __restrict__ Bt,
              const float* __restrict__ bias, void* __restrict__ Cv,
              int M, int N, int K)
{
    __shared__ __align__(16) unsigned short As[16 * 512];   // 16 frags x 1KB
    __shared__ __align__(16) unsigned short Bs[16 * 512];

    const int t = threadIdx.x, lane = t & 63, w = t >> 6;
    const int ln16 = lane & 15, hi16 = lane >> 4;
    const int wr = w >> 1, wc = w & 1;
    const int row0 = blockIdx.y * 128, col0 = blockIdx.x * 128;

    f32x4 acc[4][4] = {};

    for (int k0 = 0; k0 < K; k0 += 64) {
        #pragma unroll
        for (int i = 0; i < 4; ++i) {
            const int f  = w * 4 + i;
            const int ks = f >> 3, rf = f & 7;
            const int row = rf * 16 + ln16;
            const int kc  = k0 + ks * 32 + hi16 * 8;
            gload_lds16(&A [(size_t)(row0 + row) * K + kc], &As[f * 512]);
            gload_lds16(&Bt[(size_t)(col0 + row) * K + kc], &Bs[f * 512]);
        }
        __syncthreads();
        #pragma unroll
        for (int ks = 0; ks < 2; ++ks) {
            bfrag a[4], b[4];
            #pragma unroll
            for (int i = 0; i < 4; ++i)
                a[i] = *(const bfrag*)&As[(ks * 8 + wr * 4 + i) * 512 + lane * 8];
            #pragma unroll
            for (int j = 0; j < 4; ++j)
                b[j] = *(const bfrag*)&Bs[(ks * 8 + wc * 4 + j) * 512 + lane * 8];
            #pragma unroll
            for (int i = 0; i < 4; ++i)
                #pragma unroll
                for (int j = 0; j < 4; ++j)
                    acc[i][j] = __builtin_amdgcn_mfma_f32_16x16x32_bf16(a[i], b[j], acc[i][j], 0, 0, 0);
        }
        __syncthreads();
    }

    #pragma unroll
    for (int j = 0; j < 4; ++j) {
        const int col = col0 + wc * 64 + j * 16 + ln16;
        const float bv = BIAS ? bias[col] : 0.0f;
        const float sc = (QSCALE && col < C_DIM) ? QK_SCALE : 1.0f;
        #pragma unroll
        for (int i = 0; i < 4; ++i) {
            #pragma unroll
            for (int e = 0; e < 4; ++e) {
                const int row = row0 + wr * 64 + i * 16 + hi16 * 4 + e;
                float v = acc[i][j][e] + bv;
                if (RELU) v = fmaxf(v, 0.0f);
                if (QSCALE) v *= sc;
                if (OBF16) ((unsigned short*)Cv)[(size_t)row * N + col] = f2bf(v);
                else       ((float*)Cv)[(size_t)row * N + col] = v;
            }
        }
    }
}

// ---------------------------------------------------------------------------
// attention helpers
// ---------------------------------------------------------------------------
__device__ inline void qk16(const bfrag (&qf)[2][2], const bfrag (&kf)[4][2],
                            f32x4 (&sf)[2][4])
{
    #pragma unroll
    for (int jt = 0; jt < 4; ++jt)
        #pragma unroll
        for (int ks = 0; ks < 2; ++ks) {
            sf[0][jt] = __builtin_amdgcn_mfma_f32_16x16x32_bf16(qf[0][ks], kf[jt][ks], sf[0][jt], 0, 0, 0);
            sf[1][jt] = __builtin_amdgcn_mfma_f32_16x16x32_bf16(qf[1][ks], kf[jt][ks], sf[1][jt], 0, 0, 0);
        }
}

// softmax + PV. Mask applied on the fly.
__device__ inline void softmax_pv(f32x4 (&sf)[2][4], const bfrag (&vf)[4][2],
                                  f32x4 (&acc)[2][4],
                                  float (&mrow)[2][4], float (&lrow)[2][4],
                                  unsigned short (*Ps)[72],
                                  int tok0, int kt, bool last, int ln16, int hi16)
{
    float lmax[2][4];
    bool need = false;
    #pragma unroll
    for (int rf = 0; rf < 2; ++rf)
        #pragma unroll
        for (int e = 0; e < 4; ++e) {
            const int row = tok0 + rf * 16 + hi16 * 4 + e;
            float mx = -1e30f;
            #pragma unroll
            for (int jt = 0; jt < 4; ++jt) {
                float sv = sf[rf][jt][e];
                if (last && (kt * 64 + jt * 16 + ln16 > row)) sv = -1e30f;
                mx = fmaxf(mx, sv);
            }
            lmax[rf][e] = mx;
            need = need || (mx > mrow[rf][e] + 8.0f);
        }
    if (__any(need)) {
        #pragma unroll
        for (int rf = 0; rf < 2; ++rf)
            #pragma unroll
            for (int e = 0; e < 4; ++e) {
                float rm = lmax[rf][e];
                rm = fmaxf(rm, __shfl_xor(rm, 1));
                rm = fmaxf(rm, __shfl_xor(rm, 2));
                rm = fmaxf(rm, __shfl_xor(rm, 4));
                rm = fmaxf(rm, __shfl_xor(rm, 8));
                const float mn = fmaxf(mrow[rf][e], rm);
                const float corr = exp2f(mrow[rf][e] - mn);
                mrow[rf][e] = mn;
                lrow[rf][e] *= corr;
                #pragma unroll
                for (int dt = 0; dt < 4; ++dt) acc[rf][dt][e] *= corr;
            }
    }

    #pragma unroll
    for (int rf = 0; rf < 2; ++rf)
        #pragma unroll
        for (int jt = 0; jt < 4; ++jt)
            #pragma unroll
            for (int e = 0; e < 4; ++e) {
                const int row = tok0 + rf * 16 + hi16 * 4 + e;
                float sv = sf[rf][jt][e];
                if (last && (kt * 64 + jt * 16 + ln16 > row)) sv = -1e30f;
                const float pe = exp2f(sv - mrow[rf][e]);
                lrow[rf][e] += pe;
                Ps[rf * 16 + hi16 * 4 + e][jt * 16 + ln16] = f2bf_t(pe);
            }

    bfrag pf[2][2];
    #pragma unroll
    for (int rf = 0; rf < 2; ++rf)
        #pragma unroll
        for (int ks = 0; ks < 2; ++ks)
            pf[rf][ks] = *(const bfrag*)&Ps[rf * 16 + ln16][ks * 32 + hi16 * 8];
    #pragma unroll
    for (int ks = 0; ks < 2; ++ks)
        #pragma unroll
        for (int rf = 0; rf < 2; ++rf)
            #pragma unroll
            for (int dt = 0; dt < 4; ++dt)
                acc[rf][dt] = __builtin_amdgcn_mfma_f32_16x16x32_bf16(pf[rf][ks], vf[dt][ks], acc[rf][dt], 0, 0, 0);
}

// ---------------------------------------------------------------------------
// Flash attention, 2-wave blocks sharing LDS-staged, double-buffered K/V.
// Wave wid handles strip qw = 63 - (2j + wid); both strips of a block have
// IDENTICAL NT = 32 - j -> zero divergence. K/V tiles (64x64 bf16 = 8 KB)
// staged via global_load_lds with XOR-chunk swizzle done BOTH-sides:
//   LDS dest linear; global source chunk = slot ^ (row&7); ds_read addr
//   applies the same XOR -> conflict-free reads (rule #21 compliant).
// One barrier per tile (T3-minimum 2-phase recipe): stage(next) issued
// before compute(current); __syncthreads drains vmcnt + guards reuse.
// Grid: 768 blocks, bid&7 XCD swizzle (round-robin confirmed), heavy-j first.
// ---------------------------------------------------------------------------
__global__ __launch_bounds__(128)
void attn_kernel(const unsigned short* __restrict__ qkv,
                 const unsigned short* __restrict__ ktc,
                 const unsigned short* __restrict__ vt,
                 unsigned short* __restrict__ att)
{
    __shared__ __align__(16) unsigned short Klds[2][4096];   // [buf] 8KB tiles
    __shared__ __align__(16) unsigned short Vlds[2][4096];
    __shared__ __align__(16) unsigned short Ps[2][32][72];   // per-wave P strip

    const int tid  = threadIdx.x;
    const int lane = tid & 63, wid = tid >> 6;
    const int ln16 = lane & 15, hi16 = lane >> 4;
    const int bid = blockIdx.x;            // 0..767
    const int xcd = bid & 7;
    const int i2  = bid >> 3;              // 0..95
    const int j   = i2 / 3;                // 0..31, heavy first
    const int bh  = xcd * 3 + (i2 % 3);
    const int qw  = 63 - (j * 2 + wid);    // strip for this wave
    const int b   = bh / HEADS, h = bh % HEADS;
    const int tok0 = qw * 32;
    const size_t qrow0 = (size_t)b * TSEQ;
    const int NT = 32 - j;                 // identical for both waves

    // Q fragments (registers, once)
    bfrag qf[2][2];
    #pragma unroll
    for (int rf = 0; rf < 2; ++rf)
        #pragma unroll
        for (int ks = 0; ks < 2; ++ks)
            qf[rf][ks] = *(const bfrag*)&qkv[(qrow0 + tok0 + rf * 16 + ln16) * 1152 + h * HD + ks * 32 + hi16 * 8];

    f32x4 acc[2][4] = {};
    float mrow[2][4], lrow[2][4];
    #pragma unroll
    for (int rf = 0; rf < 2; ++rf)
        #pragma unroll
        for (int e = 0; e < 4; ++e) { mrow[rf][e] = -1e30f; lrow[rf][e] = 0.0f; }

    const unsigned short* Kb = ktc + (size_t)bh * TSEQ * HD;
    const unsigned short* Vb = vt  + (size_t)bh * HD * TSEQ;

    // loop-invariant swizzled LDS byte offsets for fragment reads:
    // logical (row, cb) lives at byte row*128 + (cb ^ ((row&7)<<4))
    int off[4][2];
    #pragma unroll
    for (int jt = 0; jt < 4; ++jt)
        #pragma unroll
        for (int ks = 0; ks < 2; ++ks) {
            const int row = jt * 16 + ln16;
            off[jt][ks] = row * 128 + ((ks * 64 + hi16 * 16) ^ ((row & 7) << 4));
        }

    // stage one K+V tile pair into buffer `bf` (per wave: 4+4 gloads of 1KB)
    auto stage = [&](int bf, int kt) {
        #pragma unroll
        for (int i = 0; i < 4; ++i) {
            const int g   = wid * 4 + i;       // 0..7 across the 2 waves
            const int c16 = g * 64 + lane;     // dest 16B-chunk index
            const int r   = c16 >> 3;          // tile row
            const int s16 = (c16 & 7) ^ (r & 7);  // inverse-swizzled src chunk
            gload_lds16(&Kb[(size_t)(kt * 64 + r) * HD + s16 * 8], &Klds[bf][g * 512]);
            gload_lds16(&Vb[(size_t)r * TSEQ + kt * 64 + s16 * 8], &Vlds[bf][g * 512]);
        }
    };

    int buf = 0;
    stage(0, 0);
    __syncthreads();   // drains vmcnt -> buf0 ready

    for (int kt = 0; kt < NT; ++kt) {
        if (kt + 1 < NT) stage(buf ^ 1, kt + 1);   // async, in flight over compute

        // fragment reads from current buffer (swizzled addresses)
        const char* Kb8 = (const char*)&Klds[buf][0];
        const char* Vb8 = (const char*)&Vlds[buf][0];
        bfrag kf[4][2], vf[4][2];
        #pragma unroll
        for (int jt = 0; jt < 4; ++jt)
            #pragma unroll
            for (int ks = 0; ks < 2; ++ks) {
                kf[jt][ks] = *(const bfrag*)(Kb8 + off[jt][ks]);
                vf[jt][ks] = *(const bfrag*)(Vb8 + off[jt][ks]);
            }

        f32x4 sf[2][4] = {};
        qk16(qf, kf, sf);
        softmax_pv(sf, vf, acc, mrow, lrow, Ps[wid], tok0, kt, kt == NT - 1, ln16, hi16);

        __syncthreads();   // drains staging vmcnt + guards buffer reuse
        buf ^= 1;
    }

    // epilogue: reduce l across the 16-lane groups, normalize, store
    #pragma unroll
    for (int rf = 0; rf < 2; ++rf)
        #pragma unroll
        for (int e = 0; e < 4; ++e) {
            float l = lrow[rf][e];
            l += __shfl_xor(l, 1);
            l += __shfl_xor(l, 2);
            l += __shfl_xor(l, 4);
            l += __shfl_xor(l, 8);
            const float inv = 1.0f / l;
            const size_t row = qrow0 + tok0 + rf * 16 + hi16 * 4 + e;
            #pragma unroll
            for (int dt = 0; dt < 4; ++dt)
                att[row * C_DIM + h * HD + dt * 16 + ln16] = f2bf(acc[rf][dt][e] * inv);
        }
}

// ---------------------------------------------------------------------------
// Fused residual add + LayerNorm; optionally also emits bf16 copy.
// ---------------------------------------------------------------------------
template<int WB>
__global__ __launch_bounds__(256)
void ln_residual_kernel(const float* __restrict__ A, const float* __restrict__ R,
                        const float* __restrict__ gamma, const float* __restrict__ beta,
                        float* __restrict__ out, unsigned short* __restrict__ outb, int Mrows)
{
    const int lane = threadIdx.x & 63;
    const int wv   = threadIdx.x >> 6;
    const int row  = blockIdx.x * 4 + wv;
    if (row >= Mrows) return;
    const size_t off = (size_t)row * C_DIM;

    float v[6];
    float sum = 0.0f;
    #pragma unroll
    for (int j = 0; j < 6; ++j) {
        const int c = lane + 64 * j;
        v[j] = A[off + c] + R[off + c];
        sum += v[j];
    }
    #pragma unroll
    for (int o = 1; o < 64; o <<= 1) sum += __shfl_xor(sum, o);
    const float mu = sum * (1.0f / C_DIM);

    float sq = 0.0f;
    #pragma unroll
    for (int j = 0; j < 6; ++j) { const float d = v[j] - mu; sq = fmaf(d, d, sq); }
    #pragma unroll
    for (int o = 1; o < 64; o <<= 1) sq += __shfl_xor(sq, o);
    const float rstd = rsqrtf(sq * (1.0f / C_DIM) + LN_EPS);

    #pragma unroll
    for (int j = 0; j < 6; ++j) {
        const int c = lane + 64 * j;
        const float r = (v[j] - mu) * rstd * gamma[c] + beta[c];
        out[off + c] = r;
        if (WB) outb[off + c] = f2bf(r);
    }
}

// ---------------------------------------------------------------------------
extern "C" void kernel_launch(void* const* d_in, const int* in_sizes, int n_in,
                              void* d_out, int out_size, void* d_ws, size_t ws_size,
                              hipStream_t stream)
{
    const float* x   = (const float*)d_in[0];
    const float* Wq  = (const float*)d_in[1];
    const float* Wk  = (const float*)d_in[2];
    const float* Wv  = (const float*)d_in[3];
    const float* Wo  = (const float*)d_in[4];
    const float* bo  = (const float*)d_in[5];
    const float* W1  = (const float*)d_in[6];
    const float* b1  = (const float*)d_in[7];
    const float* W2  = (const float*)d_in[8];
    const float* b2  = (const float*)d_in[9];
    const float* g1  = (const float*)d_in[10];
    const float* be1 = (const float*)d_in[11];
    const float* g2  = (const float*)d_in[12];
    const float* be2 = (const float*)d_in[13];
    float* out = (float*)d_out;

    const int M = BATCH * TSEQ;                  // 8192
    const size_t MC = (size_t)M * C_DIM;

    // ---- workspace layout (bytes) ----
    char* ws = (char*)d_ws;
    unsigned short* qkv = (unsigned short*)ws;                       // M*1152*2 = 18.87 MB
    unsigned short* vt  = (unsigned short*)(ws + (size_t)M*1152*2);  // 6.29 MB
    unsigned short* att = (unsigned short*)(ws + (size_t)M*1152*2 + (size_t)BATCH*HEADS*HD*TSEQ*2); // 6.29 MB
    unsigned short* h1  = (unsigned short*)ws;                       // M*1536*2, aliases qkv+vt
    char* p2 = ws + (size_t)M*1152*2 + (size_t)BATCH*HEADS*HD*TSEQ*2 + MC*2;   // 31.46 MB mark
    unsigned short* xb  = (unsigned short*)p2;                       // MC bf16 (dead after QKV gemm)
    unsigned short* ktc = xb;                                        // aliases xb: 24*2048*64 bf16
    float* y   = (float*)(p2 + MC*2);                                // MC f32
    float* x1  = (float*)(p2 + MC*2 + MC*4);                         // MC f32
    unsigned short* x1b = (unsigned short*)(p2 + MC*2 + 2*MC*4);     // MC bf16
    char* p3 = p2 + MC*2 + 2*MC*4 + MC*2;
    unsigned short* Wqkv_t = (unsigned short*)p3;                        // [1152][384]
    unsigned short* Wo_t   = Wqkv_t + (size_t)3*C_DIM*C_DIM;             // [384][384]
    unsigned short* W1_t   = Wo_t   + (size_t)C_DIM*C_DIM;               // [1536][384]
    unsigned short* W2_t   = W1_t   + (size_t)FF_DIM*C_DIM;              // [384][1536]

    dim3 b256(256), b328(32, 8);

    // ---- weight transposes (f32 -> bf16 [N][K]) ----
    transpose_w4<<<dim3(C_DIM/32, C_DIM/32, 4), b328, 0, stream>>>(
        Wq, Wk, Wv, Wo,
        Wqkv_t, Wqkv_t + (size_t)C_DIM*C_DIM, Wqkv_t + (size_t)2*C_DIM*C_DIM, Wo_t);
    transpose_w<<<dim3(FF_DIM/32, C_DIM/32), b328, 0, stream>>>(W1, W1_t, C_DIM, FF_DIM);
    transpose_w<<<dim3(C_DIM/32, FF_DIM/32), b328, 0, stream>>>(W2, W2_t, FF_DIM, C_DIM);

    // ---- x -> bf16 ----
    cvt_f32_bf16_x4<<<dim3((MC/4 + 255)/256), b256, 0, stream>>>(x, xb, (int)(MC/4));

    // ---- qkv = xb @ Wqkv (Q cols pre-scaled by 0.125*log2e) ----
    gemm_lds<1, 0, 0, 1><<<dim3(3*C_DIM/128, M/128), b256, 0, stream>>>(
        xb, Wqkv_t, nullptr, qkv, M, 3*C_DIM, C_DIM);

    // ---- V transpose + K repack (ktc overwrites dead xb) ----
    vtrans_kernel<<<dim3(TSEQ/32, HD/32, BATCH*HEADS), b328, 0, stream>>>(qkv, vt, ktc);

    // ---- attention: 768 x 2-wave blocks, LDS-shared double-buffered K/V ----
    attn_kernel<<<dim3(768), dim3(128), 0, stream>>>(qkv, ktc, vt, att);

    // ---- y = att @ Wo + bo ----
    gemm_lds<0, 1, 0, 0><<<dim3(C_DIM/128, M/128), b256, 0, stream>>>(
        att, Wo_t, bo, y, M, C_DIM, C_DIM);

    // ---- x1 = LN(x + y), also bf16 ----
    ln_residual_kernel<1><<<dim3(M/4), b256, 0, stream>>>(x, y, g1, be1, x1, x1b, M);

    // ---- h1 = relu(x1b @ W1 + b1) ----
    gemm_lds<1, 1, 1, 0><<<dim3(FF_DIM/128, M/128), b256, 0, stream>>>(
        x1b, W1_t, b1, h1, M, FF_DIM, C_DIM);

    // ---- y = h1 @ W2 + b2 ----
    gemm_lds<0, 1, 0, 0><<<dim3(C_DIM/128, M/128), b256, 0, stream>>>(
        h1, W2_t, b2, y, M, C_DIM, FF_DIM);

    // ---- out = LN(x1 + y) ----
    ln_residual_kernel<0><<<dim3(M/4), b256, 0, stream>>>(x1, y, g2, be2, out, nullptr, M);
}

// Round 14
// 211.018 us; speedup vs baseline: 1.0583x; 1.0549x over previous
//
#include <hip/hip_runtime.h>

#define C_DIM  384
#define HEADS  6
#define HD     64
#define FF_DIM 1536
#define LN_EPS 1e-3f
#define TSEQ   2048
#define BATCH  4
#define LOG2E  1.4426950408889634f
#define QK_SCALE 0.18033688011112042f   // 0.125 * log2(e), folded into Q

typedef __attribute__((ext_vector_type(4))) float          f32x4;
typedef __attribute__((ext_vector_type(4))) float          float4_t;
typedef __attribute__((ext_vector_type(8))) short          bfrag;     // 8 bf16
typedef __attribute__((ext_vector_type(4))) unsigned short ushort4_t;
typedef __attribute__((ext_vector_type(8))) unsigned short ushort8_t;

__device__ inline unsigned short f2bf(float f) {
    unsigned int u = __builtin_bit_cast(unsigned int, f);
    u += 0x7fff + ((u >> 16) & 1);          // RNE
    return (unsigned short)(u >> 16);
}
// truncating convert — P matrix only (values in [0,1], re-normalized)
__device__ inline unsigned short f2bf_t(float f) {
    return (unsigned short)(__builtin_bit_cast(unsigned int, f) >> 16);
}

// async global->LDS, 16 B per lane. LDS dest is wave-uniform base + lane*16.
__device__ inline void gload_lds16(const void* g, void* l) {
    __builtin_amdgcn_global_load_lds(
        (const __attribute__((address_space(1))) unsigned int*)g,
        (__attribute__((address_space(3))) unsigned int*)l,
        16, 0, 0);
}

// ---------------------------------------------------------------------------
// Batched transpose+convert of the four 384x384 weights: W[K][N] f32 -> Wt[N][K] bf16.
// ---------------------------------------------------------------------------
__global__ __launch_bounds__(256)
void transpose_w4(const float* __restrict__ Wq, const float* __restrict__ Wk,
                  const float* __restrict__ Wv, const float* __restrict__ Wo,
                  unsigned short* __restrict__ Dq, unsigned short* __restrict__ Dk,
                  unsigned short* __restrict__ Dv, unsigned short* __restrict__ Do_)
{
    __shared__ float tile[32][33];
    const int z = blockIdx.z;
    const float* W = z == 0 ? Wq : (z == 1 ? Wk : (z == 2 ? Wv : Wo));
    unsigned short* D = z == 0 ? Dq : (z == 1 ? Dk : (z == 2 ? Dv : Do_));
    const int tx = threadIdx.x, ty = threadIdx.y;
    const int n0 = blockIdx.x * 32, k0 = blockIdx.y * 32;
    #pragma unroll
    for (int i = 0; i < 32; i += 8)
        tile[ty + i][tx] = W[(size_t)(k0 + ty + i) * C_DIM + n0 + tx];
    __syncthreads();
    #pragma unroll
    for (int i = 0; i < 32; i += 8)
        D[(size_t)(n0 + ty + i) * C_DIM + k0 + tx] = f2bf(tile[tx][ty + i]);
}

// generic transpose: W[K][N] f32 -> Wt[N][K] bf16
__global__ __launch_bounds__(256)
void transpose_w(const float* __restrict__ W, unsigned short* __restrict__ Wt, int K, int N)
{
    __shared__ float tile[32][33];
    const int tx = threadIdx.x, ty = threadIdx.y;
    const int n0 = blockIdx.x * 32, k0 = blockIdx.y * 32;
    #pragma unroll
    for (int i = 0; i < 32; i += 8)
        tile[ty + i][tx] = W[(size_t)(k0 + ty + i) * N + n0 + tx];
    __syncthreads();
    #pragma unroll
    for (int i = 0; i < 32; i += 8)
        Wt[(size_t)(n0 + ty + i) * K + k0 + tx] = f2bf(tile[tx][ty + i]);
}

__global__ __launch_bounds__(256)
void cvt_f32_bf16_x4(const float* __restrict__ in, unsigned short* __restrict__ out, int n4)
{
    int i = blockIdx.x * 256 + threadIdx.x;
    if (i >= n4) return;
    float4_t v = ((const float4_t*)in)[i];
    ushort4_t o = { f2bf(v.x), f2bf(v.y), f2bf(v.z), f2bf(v.w) };
    ((ushort4_t*)out)[i] = o;
}

// ---------------------------------------------------------------------------
// V transpose + K repack: qkv v-cols -> vt[bh][d][t]; qkv k-cols -> ktc[bh][t][d]
// ---------------------------------------------------------------------------
__global__ __launch_bounds__(256)
void vtrans_kernel(const unsigned short* __restrict__ qkv,
                   unsigned short* __restrict__ vt,
                   unsigned short* __restrict__ ktc)
{
    __shared__ unsigned short tile[32][34];
    const int tx = threadIdx.x, ty = threadIdx.y;
    const int bh = blockIdx.z, b = bh / HEADS, h = bh % HEADS;
    const int t0 = blockIdx.x * 32, d0 = blockIdx.y * 32;
    #pragma unroll
    for (int i = 0; i < 32; i += 8) {
        tile[ty + i][tx] = qkv[(size_t)(b * TSEQ + t0 + ty + i) * 1152 + 2 * C_DIM + h * HD + d0 + tx];
        ktc[((size_t)bh * TSEQ + t0 + ty + i) * HD + d0 + tx] =
            qkv[(size_t)(b * TSEQ + t0 + ty + i) * 1152 + C_DIM + h * HD + d0 + tx];
    }
    __syncthreads();
    #pragma unroll
    for (int i = 0; i < 32; i += 8)
        vt[((size_t)bh * HD + d0 + ty + i) * TSEQ + t0 + tx] = tile[tx][ty + i];
}

// ---------------------------------------------------------------------------
// LDS-staged bf16 MFMA GEMM, BM=128 x BN=128 (m97 structure), fragment-major
// gload_lds staging. QSCALE: scale output cols < C_DIM by QK_SCALE.
// ---------------------------------------------------------------------------
template<int OBF16, int BIAS, int RELU, int QSCALE>
__global__ __launch_bounds__(256)
void gemm_lds(const unsigned short* __restrict__ A, const unsigned short* __restrict__ Bt,
              const float* __restrict__ bias, void* __restrict__ Cv,
              int M, int N, int K)
{
    __shared__ __align__(16) unsigned short As[16 * 512];   // 16 frags x 1KB
    __shared__ __align__(16) unsigned short Bs[16 * 512];

    const int t = threadIdx.x, lane = t & 63, w = t >> 6;
    const int ln16 = lane & 15, hi16 = lane >> 4;
    const int wr = w >> 1, wc = w & 1;
    const int row0 = blockIdx.y * 128, col0 = blockIdx.x * 128;

    f32x4 acc[4][4] = {};

    for (int k0 = 0; k0 < K; k0 += 64) {
        #pragma unroll
        for (int i = 0; i < 4; ++i) {
            const int f  = w * 4 + i;
            const int ks = f >> 3, rf = f & 7;
            const int row = rf * 16 + ln16;
            const int kc  = k0 + ks * 32 + hi16 * 8;
            gload_lds16(&A [(size_t)(row0 + row) * K + kc], &As[f * 512]);
            gload_lds16(&Bt[(size_t)(col0 + row) * K + kc], &Bs[f * 512]);
        }
        __syncthreads();
        #pragma unroll
        for (int ks = 0; ks < 2; ++ks) {
            bfrag a[4], b[4];
            #pragma unroll
            for (int i = 0; i < 4; ++i)
                a[i] = *(const bfrag*)&As[(ks * 8 + wr * 4 + i) * 512 + lane * 8];
            #pragma unroll
            for (int j = 0; j < 4; ++j)
                b[j] = *(const bfrag*)&Bs[(ks * 8 + wc * 4 + j) * 512 + lane * 8];
            #pragma unroll
            for (int i = 0; i < 4; ++i)
                #pragma unroll
                for (int j = 0; j < 4; ++j)
                    acc[i][j] = __builtin_amdgcn_mfma_f32_16x16x32_bf16(a[i], b[j], acc[i][j], 0, 0, 0);
        }
        __syncthreads();
    }

    #pragma unroll
    for (int j = 0; j < 4; ++j) {
        const int col = col0 + wc * 64 + j * 16 + ln16;
        const float bv = BIAS ? bias[col] : 0.0f;
        const float sc = (QSCALE && col < C_DIM) ? QK_SCALE : 1.0f;
        #pragma unroll
        for (int i = 0; i < 4; ++i) {
            #pragma unroll
            for (int e = 0; e < 4; ++e) {
                const int row = row0 + wr * 64 + i * 16 + hi16 * 4 + e;
                float v = acc[i][j][e] + bv;
                if (RELU) v = fmaxf(v, 0.0f);
                if (QSCALE) v *= sc;
                if (OBF16) ((unsigned short*)Cv)[(size_t)row * N + col] = f2bf(v);
                else       ((float*)Cv)[(size_t)row * N + col] = v;
            }
        }
    }
}

// ---------------------------------------------------------------------------
// LDS-staged bf16 MFMA GEMM, BM=64 x BN=128 — for small-N GEMMs (N=384):
// doubles block count (384 blocks = 1.5/CU) and 24 KB LDS allows up to 6
// resident blocks/CU for cross-block latency hiding. 4 waves in 2x2; wave
// computes 32x64 via acc[2][4]; 6 gloads/wave/K-step.
// ---------------------------------------------------------------------------
template<int OBF16, int BIAS, int RELU>
__global__ __launch_bounds__(256)
void gemm_lds64(const unsigned short* __restrict__ A, const unsigned short* __restrict__ Bt,
                const float* __restrict__ bias, void* __restrict__ Cv,
                int M, int N, int K)
{
    __shared__ __align__(16) unsigned short As[8 * 512];    // 8 frags x 1KB (64x64)
    __shared__ __align__(16) unsigned short Bs[16 * 512];   // 16 frags (128x64)

    const int t = threadIdx.x, lane = t & 63, w = t >> 6;
    const int ln16 = lane & 15, hi16 = lane >> 4;
    const int wr = w >> 1, wc = w & 1;
    const int row0 = blockIdx.y * 64, col0 = blockIdx.x * 128;

    f32x4 acc[2][4] = {};

    for (int k0 = 0; k0 < K; k0 += 64) {
        // stage A: frag f = ks*4 + rf  (rf = row/16)
        #pragma unroll
        for (int i = 0; i < 2; ++i) {
            const int f  = w * 2 + i;
            const int ks = f >> 2, rf = f & 3;
            gload_lds16(&A[(size_t)(row0 + rf * 16 + ln16) * K + k0 + ks * 32 + hi16 * 8],
                        &As[f * 512]);
        }
        // stage B: frag f = ks*8 + cf  (cf = col/16)
        #pragma unroll
        for (int i = 0; i < 4; ++i) {
            const int f  = w * 4 + i;
            const int ks = f >> 3, cf = f & 7;
            gload_lds16(&Bt[(size_t)(col0 + cf * 16 + ln16) * K + k0 + ks * 32 + hi16 * 8],
                        &Bs[f * 512]);
        }
        __syncthreads();
        #pragma unroll
        for (int ks = 0; ks < 2; ++ks) {
            bfrag a[2], b[4];
            #pragma unroll
            for (int i = 0; i < 2; ++i)
                a[i] = *(const bfrag*)&As[(ks * 4 + wr * 2 + i) * 512 + lane * 8];
            #pragma unroll
            for (int j = 0; j < 4; ++j)
                b[j] = *(const bfrag*)&Bs[(ks * 8 + wc * 4 + j) * 512 + lane * 8];
            #pragma unroll
            for (int i = 0; i < 2; ++i)
                #pragma unroll
                for (int j = 0; j < 4; ++j)
                    acc[i][j] = __builtin_amdgcn_mfma_f32_16x16x32_bf16(a[i], b[j], acc[i][j], 0, 0, 0);
        }
        __syncthreads();
    }

    #pragma unroll
    for (int j = 0; j < 4; ++j) {
        const int col = col0 + wc * 64 + j * 16 + ln16;
        const float bv = BIAS ? bias[col] : 0.0f;
        #pragma unroll
        for (int i = 0; i < 2; ++i) {
            #pragma unroll
            for (int e = 0; e < 4; ++e) {
                const int row = row0 + wr * 32 + i * 16 + hi16 * 4 + e;
                float v = acc[i][j][e] + bv;
                if (RELU) v = fmaxf(v, 0.0f);
                if (OBF16) ((unsigned short*)Cv)[(size_t)row * N + col] = f2bf(v);
                else       ((float*)Cv)[(size_t)row * N + col] = v;
            }
        }
    }
}

// ---------------------------------------------------------------------------
// attention helpers
// ---------------------------------------------------------------------------
__device__ inline void qk16(const bfrag (&qf)[2][2], const bfrag (&kf)[4][2],
                            f32x4 (&sf)[2][4])
{
    #pragma unroll
    for (int jt = 0; jt < 4; ++jt)
        #pragma unroll
        for (int ks = 0; ks < 2; ++ks) {
            sf[0][jt] = __builtin_amdgcn_mfma_f32_16x16x32_bf16(qf[0][ks], kf[jt][ks], sf[0][jt], 0, 0, 0);
            sf[1][jt] = __builtin_amdgcn_mfma_f32_16x16x32_bf16(qf[1][ks], kf[jt][ks], sf[1][jt], 0, 0, 0);
        }
}

// softmax + PV. Mask applied on the fly.
__device__ inline void softmax_pv(f32x4 (&sf)[2][4], const bfrag (&vf)[4][2],
                                  f32x4 (&acc)[2][4],
                                  float (&mrow)[2][4], float (&lrow)[2][4],
                                  unsigned short (*Ps)[72],
                                  int tok0, int kt, bool last, int ln16, int hi16)
{
    float lmax[2][4];
    bool need = false;
    #pragma unroll
    for (int rf = 0; rf < 2; ++rf)
        #pragma unroll
        for (int e = 0; e < 4; ++e) {
            const int row = tok0 + rf * 16 + hi16 * 4 + e;
            float mx = -1e30f;
            #pragma unroll
            for (int jt = 0; jt < 4; ++jt) {
                float sv = sf[rf][jt][e];
                if (last && (kt * 64 + jt * 16 + ln16 > row)) sv = -1e30f;
                mx = fmaxf(mx, sv);
            }
            lmax[rf][e] = mx;
            need = need || (mx > mrow[rf][e] + 8.0f);
        }
    if (__any(need)) {
        #pragma unroll
        for (int rf = 0; rf < 2; ++rf)
            #pragma unroll
            for (int e = 0; e < 4; ++e) {
                float rm = lmax[rf][e];
                rm = fmaxf(rm, __shfl_xor(rm, 1));
                rm = fmaxf(rm, __shfl_xor(rm, 2));
                rm = fmaxf(rm, __shfl_xor(rm, 4));
                rm = fmaxf(rm, __shfl_xor(rm, 8));
                const float mn = fmaxf(mrow[rf][e], rm);
                const float corr = exp2f(mrow[rf][e] - mn);
                mrow[rf][e] = mn;
                lrow[rf][e] *= corr;
                #pragma unroll
                for (int dt = 0; dt < 4; ++dt) acc[rf][dt][e] *= corr;
            }
    }

    #pragma unroll
    for (int rf = 0; rf < 2; ++rf)
        #pragma unroll
        for (int jt = 0; jt < 4; ++jt)
            #pragma unroll
            for (int e = 0; e < 4; ++e) {
                const int row = tok0 + rf * 16 + hi16 * 4 + e;
                float sv = sf[rf][jt][e];
                if (last && (kt * 64 + jt * 16 + ln16 > row)) sv = -1e30f;
                const float pe = exp2f(sv - mrow[rf][e]);
                lrow[rf][e] += pe;
                Ps[rf * 16 + hi16 * 4 + e][jt * 16 + ln16] = f2bf_t(pe);
            }

    bfrag pf[2][2];
    #pragma unroll
    for (int rf = 0; rf < 2; ++rf)
        #pragma unroll
        for (int ks = 0; ks < 2; ++ks)
            pf[rf][ks] = *(const bfrag*)&Ps[rf * 16 + ln16][ks * 32 + hi16 * 8];
    #pragma unroll
    for (int ks = 0; ks < 2; ++ks)
        #pragma unroll
        for (int rf = 0; rf < 2; ++rf)
            #pragma unroll
            for (int dt = 0; dt < 4; ++dt)
                acc[rf][dt] = __builtin_amdgcn_mfma_f32_16x16x32_bf16(pf[rf][ks], vf[dt][ks], acc[rf][dt], 0, 0, 0);
}

// ---------------------------------------------------------------------------
// Flash attention, 2-wave blocks sharing LDS-staged, double-buffered K/V
// (unchanged from round 13; pinned at ~78 us by per-tile serial issue+latency).
// ---------------------------------------------------------------------------
__global__ __launch_bounds__(128)
void attn_kernel(const unsigned short* __restrict__ qkv,
                 const unsigned short* __restrict__ ktc,
                 const unsigned short* __restrict__ vt,
                 unsigned short* __restrict__ att)
{
    __shared__ __align__(16) unsigned short Klds[2][4096];   // [buf] 8KB tiles
    __shared__ __align__(16) unsigned short Vlds[2][4096];
    __shared__ __align__(16) unsigned short Ps[2][32][72];   // per-wave P strip

    const int tid  = threadIdx.x;
    const int lane = tid & 63, wid = tid >> 6;
    const int ln16 = lane & 15, hi16 = lane >> 4;
    const int bid = blockIdx.x;            // 0..767
    const int xcd = bid & 7;
    const int i2  = bid >> 3;              // 0..95
    const int j   = i2 / 3;                // 0..31, heavy first
    const int bh  = xcd * 3 + (i2 % 3);
    const int qw  = 63 - (j * 2 + wid);    // strip for this wave
    const int b   = bh / HEADS, h = bh % HEADS;
    const int tok0 = qw * 32;
    const size_t qrow0 = (size_t)b * TSEQ;
    const int NT = 32 - j;                 // identical for both waves

    bfrag qf[2][2];
    #pragma unroll
    for (int rf = 0; rf < 2; ++rf)
        #pragma unroll
        for (int ks = 0; ks < 2; ++ks)
            qf[rf][ks] = *(const bfrag*)&qkv[(qrow0 + tok0 + rf * 16 + ln16) * 1152 + h * HD + ks * 32 + hi16 * 8];

    f32x4 acc[2][4] = {};
    float mrow[2][4], lrow[2][4];
    #pragma unroll
    for (int rf = 0; rf < 2; ++rf)
        #pragma unroll
        for (int e = 0; e < 4; ++e) { mrow[rf][e] = -1e30f; lrow[rf][e] = 0.0f; }

    const unsigned short* Kb = ktc + (size_t)bh * TSEQ * HD;
    const unsigned short* Vb = vt  + (size_t)bh * HD * TSEQ;

    int off[4][2];
    #pragma unroll
    for (int jt = 0; jt < 4; ++jt)
        #pragma unroll
        for (int ks = 0; ks < 2; ++ks) {
            const int row = jt * 16 + ln16;
            off[jt][ks] = row * 128 + ((ks * 64 + hi16 * 16) ^ ((row & 7) << 4));
        }

    auto stage = [&](int bf, int kt) {
        #pragma unroll
        for (int i = 0; i < 4; ++i) {
            const int g   = wid * 4 + i;       // 0..7 across the 2 waves
            const int c16 = g * 64 + lane;     // dest 16B-chunk index
            const int r   = c16 >> 3;          // tile row
            const int s16 = (c16 & 7) ^ (r & 7);  // inverse-swizzled src chunk
            gload_lds16(&Kb[(size_t)(kt * 64 + r) * HD + s16 * 8], &Klds[bf][g * 512]);
            gload_lds16(&Vb[(size_t)r * TSEQ + kt * 64 + s16 * 8], &Vlds[bf][g * 512]);
        }
    };

    int buf = 0;
    stage(0, 0);
    __syncthreads();

    for (int kt = 0; kt < NT; ++kt) {
        if (kt + 1 < NT) stage(buf ^ 1, kt + 1);

        const char* Kb8 = (const char*)&Klds[buf][0];
        const char* Vb8 = (const char*)&Vlds[buf][0];
        bfrag kf[4][2], vf[4][2];
        #pragma unroll
        for (int jt = 0; jt < 4; ++jt)
            #pragma unroll
            for (int ks = 0; ks < 2; ++ks) {
                kf[jt][ks] = *(const bfrag*)(Kb8 + off[jt][ks]);
                vf[jt][ks] = *(const bfrag*)(Vb8 + off[jt][ks]);
            }

        f32x4 sf[2][4] = {};
        qk16(qf, kf, sf);
        softmax_pv(sf, vf, acc, mrow, lrow, Ps[wid], tok0, kt, kt == NT - 1, ln16, hi16);

        __syncthreads();
        buf ^= 1;
    }

    #pragma unroll
    for (int rf = 0; rf < 2; ++rf)
        #pragma unroll
        for (int e = 0; e < 4; ++e) {
            float l = lrow[rf][e];
            l += __shfl_xor(l, 1);
            l += __shfl_xor(l, 2);
            l += __shfl_xor(l, 4);
            l += __shfl_xor(l, 8);
            const float inv = 1.0f / l;
            const size_t row = qrow0 + tok0 + rf * 16 + hi16 * 4 + e;
            #pragma unroll
            for (int dt = 0; dt < 4; ++dt)
                att[row * C_DIM + h * HD + dt * 16 + ln16] = f2bf(acc[rf][dt][e] * inv);
        }
}

// ---------------------------------------------------------------------------
// Fused residual add + LayerNorm; optionally also emits bf16 copy.
// ---------------------------------------------------------------------------
template<int WB>
__global__ __launch_bounds__(256)
void ln_residual_kernel(const float* __restrict__ A, const float* __restrict__ R,
                        const float* __restrict__ gamma, const float* __restrict__ beta,
                        float* __restrict__ out, unsigned short* __restrict__ outb, int Mrows)
{
    const int lane = threadIdx.x & 63;
    const int wv   = threadIdx.x >> 6;
    const int row  = blockIdx.x * 4 + wv;
    if (row >= Mrows) return;
    const size_t off = (size_t)row * C_DIM;

    float v[6];
    float sum = 0.0f;
    #pragma unroll
    for (int j = 0; j < 6; ++j) {
        const int c = lane + 64 * j;
        v[j] = A[off + c] + R[off + c];
        sum += v[j];
    }
    #pragma unroll
    for (int o = 1; o < 64; o <<= 1) sum += __shfl_xor(sum, o);
    const float mu = sum * (1.0f / C_DIM);

    float sq = 0.0f;
    #pragma unroll
    for (int j = 0; j < 6; ++j) { const float d = v[j] - mu; sq = fmaf(d, d, sq); }
    #pragma unroll
    for (int o = 1; o < 64; o <<= 1) sq += __shfl_xor(sq, o);
    const float rstd = rsqrtf(sq * (1.0f / C_DIM) + LN_EPS);

    #pragma unroll
    for (int j = 0; j < 6; ++j) {
        const int c = lane + 64 * j;
        const float r = (v[j] - mu) * rstd * gamma[c] + beta[c];
        out[off + c] = r;
        if (WB) outb[off + c] = f2bf(r);
    }
}

// ---------------------------------------------------------------------------
extern "C" void kernel_launch(void* const* d_in, const int* in_sizes, int n_in,
                              void* d_out, int out_size, void* d_ws, size_t ws_size,
                              hipStream_t stream)
{
    const float* x   = (const float*)d_in[0];
    const float* Wq  = (const float*)d_in[1];
    const float* Wk  = (const float*)d_in[2];
    const float* Wv  = (const float*)d_in[3];
    const float* Wo  = (const float*)d_in[4];
    const float* bo  = (const float*)d_in[5];
    const float* W1  = (const float*)d_in[6];
    const float* b1  = (const float*)d_in[7];
    const float* W2  = (const float*)d_in[8];
    const float* b2  = (const float*)d_in[9];
    const float* g1  = (const float*)d_in[10];
    const float* be1 = (const float*)d_in[11];
    const float* g2  = (const float*)d_in[12];
    const float* be2 = (const float*)d_in[13];
    float* out = (float*)d_out;

    const int M = BATCH * TSEQ;                  // 8192
    const size_t MC = (size_t)M * C_DIM;

    // ---- workspace layout (bytes) ----
    char* ws = (char*)d_ws;
    unsigned short* qkv = (unsigned short*)ws;                       // M*1152*2 = 18.87 MB
    unsigned short* vt  = (unsigned short*)(ws + (size_t)M*1152*2);  // 6.29 MB
    unsigned short* att = (unsigned short*)(ws + (size_t)M*1152*2 + (size_t)BATCH*HEADS*HD*TSEQ*2); // 6.29 MB
    unsigned short* h1  = (unsigned short*)ws;                       // M*1536*2, aliases qkv+vt
    char* p2 = ws + (size_t)M*1152*2 + (size_t)BATCH*HEADS*HD*TSEQ*2 + MC*2;   // 31.46 MB mark
    unsigned short* xb  = (unsigned short*)p2;                       // MC bf16 (dead after QKV gemm)
    unsigned short* ktc = xb;                                        // aliases xb: 24*2048*64 bf16
    float* y   = (float*)(p2 + MC*2);                                // MC f32
    float* x1  = (float*)(p2 + MC*2 + MC*4);                         // MC f32
    unsigned short* x1b = (unsigned short*)(p2 + MC*2 + 2*MC*4);     // MC bf16
    char* p3 = p2 + MC*2 + 2*MC*4 + MC*2;
    unsigned short* Wqkv_t = (unsigned short*)p3;                        // [1152][384]
    unsigned short* Wo_t   = Wqkv_t + (size_t)3*C_DIM*C_DIM;             // [384][384]
    unsigned short* W1_t   = Wo_t   + (size_t)C_DIM*C_DIM;               // [1536][384]
    unsigned short* W2_t   = W1_t   + (size_t)FF_DIM*C_DIM;              // [384][1536]

    dim3 b256(256), b328(32, 8);

    // ---- weight transposes (f32 -> bf16 [N][K]) ----
    transpose_w4<<<dim3(C_DIM/32, C_DIM/32, 4), b328, 0, stream>>>(
        Wq, Wk, Wv, Wo,
        Wqkv_t, Wqkv_t + (size_t)C_DIM*C_DIM, Wqkv_t + (size_t)2*C_DIM*C_DIM, Wo_t);
    transpose_w<<<dim3(FF_DIM/32, C_DIM/32), b328, 0, stream>>>(W1, W1_t, C_DIM, FF_DIM);
    transpose_w<<<dim3(C_DIM/32, FF_DIM/32), b328, 0, stream>>>(W2, W2_t, FF_DIM, C_DIM);

    // ---- x -> bf16 ----
    cvt_f32_bf16_x4<<<dim3((MC/4 + 255)/256), b256, 0, stream>>>(x, xb, (int)(MC/4));

    // ---- qkv = xb @ Wqkv (Q cols pre-scaled by 0.125*log2e) ----
    gemm_lds<1, 0, 0, 1><<<dim3(3*C_DIM/128, M/128), b256, 0, stream>>>(
        xb, Wqkv_t, nullptr, qkv, M, 3*C_DIM, C_DIM);

    // ---- V transpose + K repack (ktc overwrites dead xb) ----
    vtrans_kernel<<<dim3(TSEQ/32, HD/32, BATCH*HEADS), b328, 0, stream>>>(qkv, vt, ktc);

    // ---- attention: 768 x 2-wave blocks, LDS-shared double-buffered K/V ----
    attn_kernel<<<dim3(768), dim3(128), 0, stream>>>(qkv, ktc, vt, att);

    // ---- y = att @ Wo + bo  (BM=64: 384 blocks, 1.5/CU) ----
    gemm_lds64<0, 1, 0><<<dim3(C_DIM/128, M/64), b256, 0, stream>>>(
        att, Wo_t, bo, y, M, C_DIM, C_DIM);

    // ---- x1 = LN(x + y), also bf16 ----
    ln_residual_kernel<1><<<dim3(M/4), b256, 0, stream>>>(x, y, g1, be1, x1, x1b, M);

    // ---- h1 = relu(x1b @ W1 + b1) ----
    gemm_lds<1, 1, 1, 0><<<dim3(FF_DIM/128, M/128), b256, 0, stream>>>(
        x1b, W1_t, b1, h1, M, FF_DIM, C_DIM);

    // ---- y = h1 @ W2 + b2  (BM=64: 384 blocks, K=1536) ----
    gemm_lds64<0, 1, 0><<<dim3(C_DIM/128, M/64), b256, 0, stream>>>(
        h1, W2_t, b2, y, M, C_DIM, FF_DIM);

    // ---- out = LN(x1 + y) ----
    ln_residual_kernel<0><<<dim3(M/4), b256, 0, stream>>>(x1, y, g2, be2, out, nullptr, M);
}

// Round 15
// 204.051 us; speedup vs baseline: 1.0945x; 1.0341x over previous
//
#include <hip/hip_runtime.h>

#define C_DIM  384
#define HEADS  6
#define HD     64
#define FF_DIM 1536
#define LN_EPS 1e-3f
#define TSEQ   2048
#define BATCH  4
#define LOG2E  1.4426950408889634f
#define QK_SCALE 0.18033688011112042f   // 0.125 * log2(e), folded into Q

typedef __attribute__((ext_vector_type(4))) float          f32x4;
typedef __attribute__((ext_vector_type(4))) float          float4_t;
typedef __attribute__((ext_vector_type(8))) short          bfrag;     // 8 bf16
typedef __attribute__((ext_vector_type(4))) unsigned short ushort4_t;
typedef __attribute__((ext_vector_type(8))) unsigned short ushort8_t;

__device__ inline unsigned short f2bf(float f) {
    unsigned int u = __builtin_bit_cast(unsigned int, f);
    u += 0x7fff + ((u >> 16) & 1);          // RNE
    return (unsigned short)(u >> 16);
}
// truncating convert — P matrix only (values in [0,1], re-normalized)
__device__ inline unsigned short f2bf_t(float f) {
    return (unsigned short)(__builtin_bit_cast(unsigned int, f) >> 16);
}

// async global->LDS, 16 B per lane. LDS dest is wave-uniform base + lane*16.
__device__ inline void gload_lds16(const void* g, void* l) {
    __builtin_amdgcn_global_load_lds(
        (const __attribute__((address_space(1))) unsigned int*)g,
        (__attribute__((address_space(3))) unsigned int*)l,
        16, 0, 0);
}

// ---------------------------------------------------------------------------
// Batched transpose+convert of the four 384x384 weights: W[K][N] f32 -> Wt[N][K] bf16.
// ---------------------------------------------------------------------------
__global__ __launch_bounds__(256)
void transpose_w4(const float* __restrict__ Wq, const float* __restrict__ Wk,
                  const float* __restrict__ Wv, const float* __restrict__ Wo,
                  unsigned short* __restrict__ Dq, unsigned short* __restrict__ Dk,
                  unsigned short* __restrict__ Dv, unsigned short* __restrict__ Do_)
{
    __shared__ float tile[32][33];
    const int z = blockIdx.z;
    const float* W = z == 0 ? Wq : (z == 1 ? Wk : (z == 2 ? Wv : Wo));
    unsigned short* D = z == 0 ? Dq : (z == 1 ? Dk : (z == 2 ? Dv : Do_));
    const int tx = threadIdx.x, ty = threadIdx.y;
    const int n0 = blockIdx.x * 32, k0 = blockIdx.y * 32;
    #pragma unroll
    for (int i = 0; i < 32; i += 8)
        tile[ty + i][tx] = W[(size_t)(k0 + ty + i) * C_DIM + n0 + tx];
    __syncthreads();
    #pragma unroll
    for (int i = 0; i < 32; i += 8)
        D[(size_t)(n0 + ty + i) * C_DIM + k0 + tx] = f2bf(tile[tx][ty + i]);
}

// generic transpose: W[K][N] f32 -> Wt[N][K] bf16
__global__ __launch_bounds__(256)
void transpose_w(const float* __restrict__ W, unsigned short* __restrict__ Wt, int K, int N)
{
    __shared__ float tile[32][33];
    const int tx = threadIdx.x, ty = threadIdx.y;
    const int n0 = blockIdx.x * 32, k0 = blockIdx.y * 32;
    #pragma unroll
    for (int i = 0; i < 32; i += 8)
        tile[ty + i][tx] = W[(size_t)(k0 + ty + i) * N + n0 + tx];
    __syncthreads();
    #pragma unroll
    for (int i = 0; i < 32; i += 8)
        Wt[(size_t)(n0 + ty + i) * K + k0 + tx] = f2bf(tile[tx][ty + i]);
}

__global__ __launch_bounds__(256)
void cvt_f32_bf16_x4(const float* __restrict__ in, unsigned short* __restrict__ out, int n4)
{
    int i = blockIdx.x * 256 + threadIdx.x;
    if (i >= n4) return;
    float4_t v = ((const float4_t*)in)[i];
    ushort4_t o = { f2bf(v.x), f2bf(v.y), f2bf(v.z), f2bf(v.w) };
    ((ushort4_t*)out)[i] = o;
}

// ---------------------------------------------------------------------------
// V transpose + K repack: qkv v-cols -> vt[bh][d][t]; qkv k-cols -> ktc[bh][t][d]
// ---------------------------------------------------------------------------
__global__ __launch_bounds__(256)
void vtrans_kernel(const unsigned short* __restrict__ qkv,
                   unsigned short* __restrict__ vt,
                   unsigned short* __restrict__ ktc)
{
    __shared__ unsigned short tile[32][34];
    const int tx = threadIdx.x, ty = threadIdx.y;
    const int bh = blockIdx.z, b = bh / HEADS, h = bh % HEADS;
    const int t0 = blockIdx.x * 32, d0 = blockIdx.y * 32;
    #pragma unroll
    for (int i = 0; i < 32; i += 8) {
        tile[ty + i][tx] = qkv[(size_t)(b * TSEQ + t0 + ty + i) * 1152 + 2 * C_DIM + h * HD + d0 + tx];
        ktc[((size_t)bh * TSEQ + t0 + ty + i) * HD + d0 + tx] =
            qkv[(size_t)(b * TSEQ + t0 + ty + i) * 1152 + C_DIM + h * HD + d0 + tx];
    }
    __syncthreads();
    #pragma unroll
    for (int i = 0; i < 32; i += 8)
        vt[((size_t)bh * HD + d0 + ty + i) * TSEQ + t0 + tx] = tile[tx][ty + i];
}

// ---------------------------------------------------------------------------
// LDS-staged bf16 MFMA GEMM, BM=128 x BN=128 (m97 structure), fragment-major
// gload_lds staging. QSCALE: scale output cols < C_DIM by QK_SCALE.
// ---------------------------------------------------------------------------
template<int OBF16, int BIAS, int RELU, int QSCALE>
__global__ __launch_bounds__(256)
void gemm_lds(const unsigned short* __restrict__ A, const unsigned short* __restrict__ Bt,
              const float* __restrict__ bias, void* __restrict__ Cv,
              int M, int N, int K)
{
    __shared__ __align__(16) unsigned short As[16 * 512];   // 16 frags x 1KB
    __shared__ __align__(16) unsigned short Bs[16 * 512];

    const int t = threadIdx.x, lane = t & 63, w = t >> 6;
    const int ln16 = lane & 15, hi16 = lane >> 4;
    const int wr = w >> 1, wc = w & 1;
    const int row0 = blockIdx.y * 128, col0 = blockIdx.x * 128;

    f32x4 acc[4][4] = {};

    for (int k0 = 0; k0 < K; k0 += 64) {
        #pragma unroll
        for (int i = 0; i < 4; ++i) {
            const int f  = w * 4 + i;
            const int ks = f >> 3, rf = f & 7;
            const int row = rf * 16 + ln16;
            const int kc  = k0 + ks * 32 + hi16 * 8;
            gload_lds16(&A [(size_t)(row0 + row) * K + kc], &As[f * 512]);
            gload_lds16(&Bt[(size_t)(col0 + row) * K + kc], &Bs[f * 512]);
        }
        __syncthreads();
        #pragma unroll
        for (int ks = 0; ks < 2; ++ks) {
            bfrag a[4], b[4];
            #pragma unroll
            for (int i = 0; i < 4; ++i)
                a[i] = *(const bfrag*)&As[(ks * 8 + wr * 4 + i) * 512 + lane * 8];
            #pragma unroll
            for (int j = 0; j < 4; ++j)
                b[j] = *(const bfrag*)&Bs[(ks * 8 + wc * 4 + j) * 512 + lane * 8];
            #pragma unroll
            for (int i = 0; i < 4; ++i)
                #pragma unroll
                for (int j = 0; j < 4; ++j)
                    acc[i][j] = __builtin_amdgcn_mfma_f32_16x16x32_bf16(a[i], b[j], acc[i][j], 0, 0, 0);
        }
        __syncthreads();
    }

    #pragma unroll
    for (int j = 0; j < 4; ++j) {
        const int col = col0 + wc * 64 + j * 16 + ln16;
        const float bv = BIAS ? bias[col] : 0.0f;
        const float sc = (QSCALE && col < C_DIM) ? QK_SCALE : 1.0f;
        #pragma unroll
        for (int i = 0; i < 4; ++i) {
            #pragma unroll
            for (int e = 0; e < 4; ++e) {
                const int row = row0 + wr * 64 + i * 16 + hi16 * 4 + e;
                float v = acc[i][j][e] + bv;
                if (RELU) v = fmaxf(v, 0.0f);
                if (QSCALE) v *= sc;
                if (OBF16) ((unsigned short*)Cv)[(size_t)row * N + col] = f2bf(v);
                else       ((float*)Cv)[(size_t)row * N + col] = v;
            }
        }
    }
}

// ---------------------------------------------------------------------------
// LDS-staged bf16 MFMA GEMM, BM=64 x BN=128 — for small-N GEMMs (N=384).
// ---------------------------------------------------------------------------
template<int OBF16, int BIAS, int RELU>
__global__ __launch_bounds__(256)
void gemm_lds64(const unsigned short* __restrict__ A, const unsigned short* __restrict__ Bt,
                const float* __restrict__ bias, void* __restrict__ Cv,
                int M, int N, int K)
{
    __shared__ __align__(16) unsigned short As[8 * 512];    // 8 frags x 1KB (64x64)
    __shared__ __align__(16) unsigned short Bs[16 * 512];   // 16 frags (128x64)

    const int t = threadIdx.x, lane = t & 63, w = t >> 6;
    const int ln16 = lane & 15, hi16 = lane >> 4;
    const int wr = w >> 1, wc = w & 1;
    const int row0 = blockIdx.y * 64, col0 = blockIdx.x * 128;

    f32x4 acc[2][4] = {};

    for (int k0 = 0; k0 < K; k0 += 64) {
        #pragma unroll
        for (int i = 0; i < 2; ++i) {
            const int f  = w * 2 + i;
            const int ks = f >> 2, rf = f & 3;
            gload_lds16(&A[(size_t)(row0 + rf * 16 + ln16) * K + k0 + ks * 32 + hi16 * 8],
                        &As[f * 512]);
        }
        #pragma unroll
        for (int i = 0; i < 4; ++i) {
            const int f  = w * 4 + i;
            const int ks = f >> 3, cf = f & 7;
            gload_lds16(&Bt[(size_t)(col0 + cf * 16 + ln16) * K + k0 + ks * 32 + hi16 * 8],
                        &Bs[f * 512]);
        }
        __syncthreads();
        #pragma unroll
        for (int ks = 0; ks < 2; ++ks) {
            bfrag a[2], b[4];
            #pragma unroll
            for (int i = 0; i < 2; ++i)
                a[i] = *(const bfrag*)&As[(ks * 4 + wr * 2 + i) * 512 + lane * 8];
            #pragma unroll
            for (int j = 0; j < 4; ++j)
                b[j] = *(const bfrag*)&Bs[(ks * 8 + wc * 4 + j) * 512 + lane * 8];
            #pragma unroll
            for (int i = 0; i < 2; ++i)
                #pragma unroll
                for (int j = 0; j < 4; ++j)
                    acc[i][j] = __builtin_amdgcn_mfma_f32_16x16x32_bf16(a[i], b[j], acc[i][j], 0, 0, 0);
        }
        __syncthreads();
    }

    #pragma unroll
    for (int j = 0; j < 4; ++j) {
        const int col = col0 + wc * 64 + j * 16 + ln16;
        const float bv = BIAS ? bias[col] : 0.0f;
        #pragma unroll
        for (int i = 0; i < 2; ++i) {
            #pragma unroll
            for (int e = 0; e < 4; ++e) {
                const int row = row0 + wr * 32 + i * 16 + hi16 * 4 + e;
                float v = acc[i][j][e] + bv;
                if (RELU) v = fmaxf(v, 0.0f);
                if (OBF16) ((unsigned short*)Cv)[(size_t)row * N + col] = f2bf(v);
                else       ((float*)Cv)[(size_t)row * N + col] = v;
            }
        }
    }
}

// ---------------------------------------------------------------------------
// attention helpers
// ---------------------------------------------------------------------------
__device__ inline void qk16(const bfrag (&qf)[2][2], const bfrag (&kf)[4][2],
                            f32x4 (&sf)[2][4])
{
    #pragma unroll
    for (int jt = 0; jt < 4; ++jt)
        #pragma unroll
        for (int ks = 0; ks < 2; ++ks) {
            sf[0][jt] = __builtin_amdgcn_mfma_f32_16x16x32_bf16(qf[0][ks], kf[jt][ks], sf[0][jt], 0, 0, 0);
            sf[1][jt] = __builtin_amdgcn_mfma_f32_16x16x32_bf16(qf[1][ks], kf[jt][ks], sf[1][jt], 0, 0, 0);
        }
}

// softmax + PV. Mask applied on the fly.
__device__ inline void softmax_pv(f32x4 (&sf)[2][4], const bfrag (&vf)[4][2],
                                  f32x4 (&acc)[2][4],
                                  float (&mrow)[2][4], float (&lrow)[2][4],
                                  unsigned short (*Ps)[72],
                                  int tok0, int kt, bool last, int ln16, int hi16)
{
    float lmax[2][4];
    bool need = false;
    #pragma unroll
    for (int rf = 0; rf < 2; ++rf)
        #pragma unroll
        for (int e = 0; e < 4; ++e) {
            const int row = tok0 + rf * 16 + hi16 * 4 + e;
            float mx = -1e30f;
            #pragma unroll
            for (int jt = 0; jt < 4; ++jt) {
                float sv = sf[rf][jt][e];
                if (last && (kt * 64 + jt * 16 + ln16 > row)) sv = -1e30f;
                mx = fmaxf(mx, sv);
            }
            lmax[rf][e] = mx;
            need = need || (mx > mrow[rf][e] + 8.0f);
        }
    if (__any(need)) {
        #pragma unroll
        for (int rf = 0; rf < 2; ++rf)
            #pragma unroll
            for (int e = 0; e < 4; ++e) {
                float rm = lmax[rf][e];
                rm = fmaxf(rm, __shfl_xor(rm, 1));
                rm = fmaxf(rm, __shfl_xor(rm, 2));
                rm = fmaxf(rm, __shfl_xor(rm, 4));
                rm = fmaxf(rm, __shfl_xor(rm, 8));
                const float mn = fmaxf(mrow[rf][e], rm);
                const float corr = exp2f(mrow[rf][e] - mn);
                mrow[rf][e] = mn;
                lrow[rf][e] *= corr;
                #pragma unroll
                for (int dt = 0; dt < 4; ++dt) acc[rf][dt][e] *= corr;
            }
    }

    #pragma unroll
    for (int rf = 0; rf < 2; ++rf)
        #pragma unroll
        for (int jt = 0; jt < 4; ++jt)
            #pragma unroll
            for (int e = 0; e < 4; ++e) {
                const int row = tok0 + rf * 16 + hi16 * 4 + e;
                float sv = sf[rf][jt][e];
                if (last && (kt * 64 + jt * 16 + ln16 > row)) sv = -1e30f;
                const float pe = exp2f(sv - mrow[rf][e]);
                lrow[rf][e] += pe;
                Ps[rf * 16 + hi16 * 4 + e][jt * 16 + ln16] = f2bf_t(pe);
            }

    bfrag pf[2][2];
    #pragma unroll
    for (int rf = 0; rf < 2; ++rf)
        #pragma unroll
        for (int ks = 0; ks < 2; ++ks)
            pf[rf][ks] = *(const bfrag*)&Ps[rf * 16 + ln16][ks * 32 + hi16 * 8];
    #pragma unroll
    for (int ks = 0; ks < 2; ++ks)
        #pragma unroll
        for (int rf = 0; rf < 2; ++rf)
            #pragma unroll
            for (int dt = 0; dt < 4; ++dt)
                acc[rf][dt] = __builtin_amdgcn_mfma_f32_16x16x32_bf16(pf[rf][ks], vf[dt][ks], acc[rf][dt], 0, 0, 0);
}

// ---------------------------------------------------------------------------
// Split-K flash attention (moderate split). 2304 one-wave blocks:
//   heavy strips (qw>=32, NT=17..32): 2 chunks each, <=16 tiles -> partials
//   light strips (qw<32,  NT<=16):    direct normalized store
// Longest serial chain drops 32 -> 16 tiles. Heavy chunks dispatch first
// (bids 0..1535). bid&7 XCD swizzle (round-robin confirmed r10).
// ---------------------------------------------------------------------------
__global__ __launch_bounds__(64)
void attn_kernel(const unsigned short* __restrict__ qkv,
                 const unsigned short* __restrict__ ktc,
                 const unsigned short* __restrict__ vt,
                 unsigned short* __restrict__ att,
                 unsigned short* __restrict__ pacc,
                 float* __restrict__ pml)
{
    __shared__ __align__(16) unsigned short Ps[32][72];
    const int lane = threadIdx.x;
    const int ln16 = lane & 15, hi16 = lane >> 4;
    const int bid = blockIdx.x;            // 0..2303
    const int xcd = bid & 7;
    const int i   = bid >> 3;              // 0..287
    int bh, qw, kt0, kte, ck = 0;
    bool heavy;
    if (i < 192) {                         // heavy chunk waves, qw descending
        qw = 63 - (i / 6);                 // 63..32
        const int r = i % 6;
        bh = xcd * 3 + (r >> 1);
        ck = r & 1;
        const int NT = (qw >> 1) + 1;      // 17..32
        const int half = NT >> 1;          // 8..16
        kt0 = ck ? half : 0;
        kte = ck ? NT : half;
        heavy = true;
    } else {                               // light strips
        const int j = i - 192;             // 0..95
        qw = 31 - (j / 3);                 // 31..0
        bh = xcd * 3 + (j % 3);
        kt0 = 0;
        kte = (qw >> 1) + 1;               // <= 16
        heavy = false;
    }
    const int NTfull = (qw >> 1) + 1;
    const int b = bh / HEADS, h = bh % HEADS;
    const int tok0 = qw * 32;
    const size_t qrow0 = (size_t)b * TSEQ;

    bfrag qf[2][2];
    #pragma unroll
    for (int rf = 0; rf < 2; ++rf)
        #pragma unroll
        for (int ks = 0; ks < 2; ++ks)
            qf[rf][ks] = *(const bfrag*)&qkv[(qrow0 + tok0 + rf * 16 + ln16) * 1152 + h * HD + ks * 32 + hi16 * 8];

    f32x4 acc[2][4] = {};
    float mrow[2][4], lrow[2][4];
    #pragma unroll
    for (int rf = 0; rf < 2; ++rf)
        #pragma unroll
        for (int e = 0; e < 4; ++e) { mrow[rf][e] = -1e30f; lrow[rf][e] = 0.0f; }

    const unsigned short* Kb = ktc + (size_t)bh * TSEQ * HD;
    const unsigned short* Vb = vt  + (size_t)bh * HD * TSEQ;

    bfrag kf[4][2];
    #pragma unroll
    for (int jt = 0; jt < 4; ++jt)
        #pragma unroll
        for (int ks = 0; ks < 2; ++ks)
            kf[jt][ks] = *(const bfrag*)&Kb[(size_t)(kt0 * 64 + jt * 16 + ln16) * HD + ks * 32 + hi16 * 8];

    for (int kt = kt0; kt < kte; ++kt) {
        // V fragments: issue early, consumed after softmax
        bfrag vf[4][2];
        #pragma unroll
        for (int dt = 0; dt < 4; ++dt)
            #pragma unroll
            for (int ks = 0; ks < 2; ++ks)
                vf[dt][ks] = *(const bfrag*)&Vb[(size_t)(dt * 16 + ln16) * TSEQ + kt * 64 + ks * 32 + hi16 * 8];

        f32x4 sf[2][4] = {};
        qk16(qf, kf, sf);

        // prefetch next K tile under softmax/PV
        if (kt + 1 < kte) {
            #pragma unroll
            for (int jt = 0; jt < 4; ++jt)
                #pragma unroll
                for (int ks = 0; ks < 2; ++ks)
                    kf[jt][ks] = *(const bfrag*)&Kb[(size_t)((kt + 1) * 64 + jt * 16 + ln16) * HD + ks * 32 + hi16 * 8];
        }

        softmax_pv(sf, vf, acc, mrow, lrow, Ps, tok0, kt, kt == NTfull - 1, ln16, hi16);
    }

    // reduce l across the 16-lane groups
    float lsum[2][4];
    #pragma unroll
    for (int rf = 0; rf < 2; ++rf)
        #pragma unroll
        for (int e = 0; e < 4; ++e) {
            float l = lrow[rf][e];
            l += __shfl_xor(l, 1);
            l += __shfl_xor(l, 2);
            l += __shfl_xor(l, 4);
            l += __shfl_xor(l, 8);
            lsum[rf][e] = l;
        }

    if (!heavy) {
        #pragma unroll
        for (int rf = 0; rf < 2; ++rf)
            #pragma unroll
            for (int e = 0; e < 4; ++e) {
                const float inv = 1.0f / lsum[rf][e];
                const size_t row = qrow0 + tok0 + rf * 16 + hi16 * 4 + e;
                #pragma unroll
                for (int dt = 0; dt < 4; ++dt)
                    att[row * C_DIM + h * HD + dt * 16 + ln16] = f2bf(acc[rf][dt][e] * inv);
            }
    } else {
        const int sidx = bh * 32 + (qw - 32);     // 0..767
        const size_t pb = (size_t)sidx * 2 + ck;
        #pragma unroll
        for (int rf = 0; rf < 2; ++rf)
            #pragma unroll
            for (int dt = 0; dt < 4; ++dt)
                #pragma unroll
                for (int e = 0; e < 4; ++e) {
                    const int row = rf * 16 + hi16 * 4 + e;
                    pacc[(pb * 32 + row) * 64 + dt * 16 + ln16] = f2bf(acc[rf][dt][e]);
                }
        if (ln16 == 0) {
            #pragma unroll
            for (int rf = 0; rf < 2; ++rf)
                #pragma unroll
                for (int e = 0; e < 4; ++e) {
                    const int row = rf * 16 + hi16 * 4 + e;
                    pml[pb * 64 + row * 2 + 0] = mrow[rf][e];
                    pml[pb * 64 + row * 2 + 1] = lsum[rf][e];
                }
        }
    }
}

// ---------------------------------------------------------------------------
// Combine the 2 chunks of each heavy strip. 768 blocks x 256 thr.
// ---------------------------------------------------------------------------
__global__ __launch_bounds__(256)
void attn_combine(const unsigned short* __restrict__ pacc,
                  const float* __restrict__ pml,
                  unsigned short* __restrict__ att)
{
    const int sidx = blockIdx.x;           // 0..767
    const int bh = sidx >> 5;
    const int qw = 32 + (sidx & 31);
    const int b = bh / HEADS, h = bh % HEADS;
    const int tid = threadIdx.x;
    const int row = tid >> 3;              // 0..31
    const int d0  = (tid & 7) * 8;

    const float m0 = pml[((size_t)sidx * 2 + 0) * 64 + row * 2 + 0];
    const float l0 = pml[((size_t)sidx * 2 + 0) * 64 + row * 2 + 1];
    const float m1 = pml[((size_t)sidx * 2 + 1) * 64 + row * 2 + 0];
    const float l1 = pml[((size_t)sidx * 2 + 1) * 64 + row * 2 + 1];
    const float M  = fmaxf(m0, m1);
    const float w0 = exp2f(m0 - M), w1 = exp2f(m1 - M);
    const float invL = 1.0f / (l0 * w0 + l1 * w1);

    ushort8_t a0 = *(const ushort8_t*)&pacc[(((size_t)sidx * 2 + 0) * 32 + row) * 64 + d0];
    ushort8_t a1 = *(const ushort8_t*)&pacc[(((size_t)sidx * 2 + 1) * 32 + row) * 64 + d0];
    ushort8_t rv;
    #pragma unroll
    for (int k = 0; k < 8; ++k) {
        const float v0 = __builtin_bit_cast(float, (unsigned int)a0[k] << 16);
        const float v1 = __builtin_bit_cast(float, (unsigned int)a1[k] << 16);
        rv[k] = f2bf((v0 * w0 + v1 * w1) * invL);
    }
    const size_t grow = (size_t)b * TSEQ + qw * 32 + row;
    *(ushort8_t*)&att[grow * C_DIM + h * HD + d0] = rv;
}

// ---------------------------------------------------------------------------
// Fused residual add + LayerNorm; optionally also emits bf16 copy.
// ---------------------------------------------------------------------------
template<int WB>
__global__ __launch_bounds__(256)
void ln_residual_kernel(const float* __restrict__ A, const float* __restrict__ R,
                        const float* __restrict__ gamma, const float* __restrict__ beta,
                        float* __restrict__ out, unsigned short* __restrict__ outb, int Mrows)
{
    const int lane = threadIdx.x & 63;
    const int wv   = threadIdx.x >> 6;
    const int row  = blockIdx.x * 4 + wv;
    if (row >= Mrows) return;
    const size_t off = (size_t)row * C_DIM;

    float v[6];
    float sum = 0.0f;
    #pragma unroll
    for (int j = 0; j < 6; ++j) {
        const int c = lane + 64 * j;
        v[j] = A[off + c] + R[off + c];
        sum += v[j];
    }
    #pragma unroll
    for (int o = 1; o < 64; o <<= 1) sum += __shfl_xor(sum, o);
    const float mu = sum * (1.0f / C_DIM);

    float sq = 0.0f;
    #pragma unroll
    for (int j = 0; j < 6; ++j) { const float d = v[j] - mu; sq = fmaf(d, d, sq); }
    #pragma unroll
    for (int o = 1; o < 64; o <<= 1) sq += __shfl_xor(sq, o);
    const float rstd = rsqrtf(sq * (1.0f / C_DIM) + LN_EPS);

    #pragma unroll
    for (int j = 0; j < 6; ++j) {
        const int c = lane + 64 * j;
        const float r = (v[j] - mu) * rstd * gamma[c] + beta[c];
        out[off + c] = r;
        if (WB) outb[off + c] = f2bf(r);
    }
}

// ---------------------------------------------------------------------------
extern "C" void kernel_launch(void* const* d_in, const int* in_sizes, int n_in,
                              void* d_out, int out_size, void* d_ws, size_t ws_size,
                              hipStream_t stream)
{
    const float* x   = (const float*)d_in[0];
    const float* Wq  = (const float*)d_in[1];
    const float* Wk  = (const float*)d_in[2];
    const float* Wv  = (const float*)d_in[3];
    const float* Wo  = (const float*)d_in[4];
    const float* bo  = (const float*)d_in[5];
    const float* W1  = (const float*)d_in[6];
    const float* b1  = (const float*)d_in[7];
    const float* W2  = (const float*)d_in[8];
    const float* b2  = (const float*)d_in[9];
    const float* g1  = (const float*)d_in[10];
    const float* be1 = (const float*)d_in[11];
    const float* g2  = (const float*)d_in[12];
    const float* be2 = (const float*)d_in[13];
    float* out = (float*)d_out;

    const int M = BATCH * TSEQ;                  // 8192
    const size_t MC = (size_t)M * C_DIM;

    // ---- workspace layout (bytes) ----
    char* ws = (char*)d_ws;
    unsigned short* qkv = (unsigned short*)ws;                       // M*1152*2 = 18.87 MB
    unsigned short* vt  = (unsigned short*)(ws + (size_t)M*1152*2);  // 6.29 MB
    unsigned short* att = (unsigned short*)(ws + (size_t)M*1152*2 + (size_t)BATCH*HEADS*HD*TSEQ*2); // 6.29 MB
    unsigned short* h1  = (unsigned short*)ws;                       // M*1536*2, aliases qkv+vt
    char* p2 = ws + (size_t)M*1152*2 + (size_t)BATCH*HEADS*HD*TSEQ*2 + MC*2;   // 31.46 MB mark
    unsigned short* xb  = (unsigned short*)p2;                       // MC bf16 (dead after QKV gemm)
    unsigned short* ktc = xb;                                        // aliases xb: 24*2048*64 bf16
    float* y   = (float*)(p2 + MC*2);                                // MC f32
    float* x1  = (float*)(p2 + MC*2 + MC*4);                         // MC f32
    unsigned short* x1b = (unsigned short*)(p2 + MC*2 + 2*MC*4);     // MC bf16
    char* p3 = p2 + MC*2 + 2*MC*4 + MC*2;
    unsigned short* Wqkv_t = (unsigned short*)p3;                        // [1152][384]
    unsigned short* Wo_t   = Wqkv_t + (size_t)3*C_DIM*C_DIM;             // [384][384]
    unsigned short* W1_t   = Wo_t   + (size_t)C_DIM*C_DIM;               // [1536][384]
    unsigned short* W2_t   = W1_t   + (size_t)FF_DIM*C_DIM;              // [384][1536]

    // split-K partials live in the y region (dead during attn):
    // pacc 1536 x 32 x 64 bf16 = 6.29 MB, pml 1536 x 64 f32 = 0.39 MB  (y = 12.58 MB)
    unsigned short* pacc = (unsigned short*)(p2 + MC*2);
    float* pml = (float*)(p2 + MC*2 + (size_t)1536*32*64*2);

    dim3 b256(256), b328(32, 8);

    // ---- weight transposes (f32 -> bf16 [N][K]) ----
    transpose_w4<<<dim3(C_DIM/32, C_DIM/32, 4), b328, 0, stream>>>(
        Wq, Wk, Wv, Wo,
        Wqkv_t, Wqkv_t + (size_t)C_DIM*C_DIM, Wqkv_t + (size_t)2*C_DIM*C_DIM, Wo_t);
    transpose_w<<<dim3(FF_DIM/32, C_DIM/32), b328, 0, stream>>>(W1, W1_t, C_DIM, FF_DIM);
    transpose_w<<<dim3(C_DIM/32, FF_DIM/32), b328, 0, stream>>>(W2, W2_t, FF_DIM, C_DIM);

    // ---- x -> bf16 ----
    cvt_f32_bf16_x4<<<dim3((MC/4 + 255)/256), b256, 0, stream>>>(x, xb, (int)(MC/4));

    // ---- qkv = xb @ Wqkv (Q cols pre-scaled by 0.125*log2e) ----
    gemm_lds<1, 0, 0, 1><<<dim3(3*C_DIM/128, M/128), b256, 0, stream>>>(
        xb, Wqkv_t, nullptr, qkv, M, 3*C_DIM, C_DIM);

    // ---- V transpose + K repack (ktc overwrites dead xb) ----
    vtrans_kernel<<<dim3(TSEQ/32, HD/32, BATCH*HEADS), b328, 0, stream>>>(qkv, vt, ktc);

    // ---- attention: 2304 waves (heavy strips split in 2), then combine ----
    attn_kernel<<<dim3(2304), dim3(64), 0, stream>>>(qkv, ktc, vt, att, pacc, pml);
    attn_combine<<<dim3(768), b256, 0, stream>>>(pacc, pml, att);

    // ---- y = att @ Wo + bo  (BM=64: 384 blocks) ----
    gemm_lds64<0, 1, 0><<<dim3(C_DIM/128, M/64), b256, 0, stream>>>(
        att, Wo_t, bo, y, M, C_DIM, C_DIM);

    // ---- x1 = LN(x + y), also bf16 ----
    ln_residual_kernel<1><<<dim3(M/4), b256, 0, stream>>>(x, y, g1, be1, x1, x1b, M);

    // ---- h1 = relu(x1b @ W1 + b1) ----
    gemm_lds<1, 1, 1, 0><<<dim3(FF_DIM/128, M/128), b256, 0, stream>>>(
        x1b, W1_t, b1, h1, M, FF_DIM, C_DIM);

    // ---- y = h1 @ W2 + b2  (BM=64: 384 blocks, K=1536) ----
    gemm_lds64<0, 1, 0><<<dim3(C_DIM/128, M/64), b256, 0, stream>>>(
        h1, W2_t, b2, y, M, C_DIM, FF_DIM);

    // ---- out = LN(x1 + y) ----
    ln_residual_kernel<0><<<dim3(M/4), b256, 0, stream>>>(x1, y, g2, be2, out, nullptr, M);
}

// Round 16
// 195.377 us; speedup vs baseline: 1.1430x; 1.0444x over previous
//
#include <hip/hip_runtime.h>

#define C_DIM  384
#define HEADS  6
#define HD     64
#define FF_DIM 1536
#define LN_EPS 1e-3f
#define TSEQ   2048
#define BATCH  4
#define LOG2E  1.4426950408889634f
#define QK_SCALE 0.18033688011112042f   // 0.125 * log2(e), folded into Q

typedef __attribute__((ext_vector_type(4))) float          f32x4;
typedef __attribute__((ext_vector_type(4))) float          float4_t;
typedef __attribute__((ext_vector_type(8))) short          bfrag;     // 8 bf16
typedef __attribute__((ext_vector_type(4))) unsigned short ushort4_t;
typedef __attribute__((ext_vector_type(8))) unsigned short ushort8_t;

__device__ inline unsigned short f2bf(float f) {
    unsigned int u = __builtin_bit_cast(unsigned int, f);
    u += 0x7fff + ((u >> 16) & 1);          // RNE
    return (unsigned short)(u >> 16);
}
// truncating convert — P matrix only (values in [0,1], re-normalized)
__device__ inline unsigned short f2bf_t(float f) {
    return (unsigned short)(__builtin_bit_cast(unsigned int, f) >> 16);
}
__device__ inline float bf2f(unsigned short u) {
    return __builtin_bit_cast(float, (unsigned int)u << 16);
}

// async global->LDS, 16 B per lane. LDS dest is wave-uniform base + lane*16.
__device__ inline void gload_lds16(const void* g, void* l) {
    __builtin_amdgcn_global_load_lds(
        (const __attribute__((address_space(1))) unsigned int*)g,
        (__attribute__((address_space(3))) unsigned int*)l,
        16, 0, 0);
}

// ---------------------------------------------------------------------------
// Fused transpose+convert of ALL weights: W[K][N] f32 -> Wt[N][K] bf16.
// Flat block decode: 0..575 = four 384x384 (144 tiles each);
// 576..1151 = W1 (384x1536); 1152..1727 = W2 (1536x384). block (32,8).
// ---------------------------------------------------------------------------
__global__ __launch_bounds__(256)
void transpose_all(const float* __restrict__ Wq, const float* __restrict__ Wk,
                   const float* __restrict__ Wv, const float* __restrict__ Wo,
                   const float* __restrict__ W1, const float* __restrict__ W2,
                   unsigned short* __restrict__ Dqkv, unsigned short* __restrict__ Do_,
                   unsigned short* __restrict__ D1, unsigned short* __restrict__ D2)
{
    __shared__ float tile[32][33];
    const int bidx = blockIdx.x;
    const float* W; unsigned short* D;
    int K, N, nx, ny;
    if (bidx < 576) {
        const int z = bidx / 144, r = bidx % 144;
        W = z == 0 ? Wq : (z == 1 ? Wk : (z == 2 ? Wv : Wo));
        D = z == 3 ? Do_ : Dqkv + (size_t)z * C_DIM * C_DIM;
        K = N = C_DIM; nx = r % 12; ny = r / 12;
    } else if (bidx < 1152) {
        const int r = bidx - 576;
        W = W1; D = D1; K = C_DIM; N = FF_DIM; nx = r % 48; ny = r / 48;
    } else {
        const int r = bidx - 1152;
        W = W2; D = D2; K = FF_DIM; N = C_DIM; nx = r % 12; ny = r / 12;
    }
    const int tx = threadIdx.x, ty = threadIdx.y;
    const int n0 = nx * 32, k0 = ny * 32;
    #pragma unroll
    for (int i = 0; i < 32; i += 8)
        tile[ty + i][tx] = W[(size_t)(k0 + ty + i) * N + n0 + tx];
    __syncthreads();
    #pragma unroll
    for (int i = 0; i < 32; i += 8)
        D[(size_t)(n0 + ty + i) * K + k0 + tx] = f2bf(tile[tx][ty + i]);
}

__global__ __launch_bounds__(256)
void cvt_f32_bf16_x4(const float* __restrict__ in, unsigned short* __restrict__ out, int n4)
{
    int i = blockIdx.x * 256 + threadIdx.x;
    if (i >= n4) return;
    float4_t v = ((const float4_t*)in)[i];
    ushort4_t o = { f2bf(v.x), f2bf(v.y), f2bf(v.z), f2bf(v.w) };
    ((ushort4_t*)out)[i] = o;
}

// ---------------------------------------------------------------------------
// V transpose only: qkv v-cols -> vt[bh][d][t] bf16.
// ---------------------------------------------------------------------------
__global__ __launch_bounds__(256)
void vtrans_kernel(const unsigned short* __restrict__ qkv,
                   unsigned short* __restrict__ vt)
{
    __shared__ unsigned short tile[32][34];
    const int tx = threadIdx.x, ty = threadIdx.y;
    const int bh = blockIdx.z, b = bh / HEADS, h = bh % HEADS;
    const int t0 = blockIdx.x * 32, d0 = blockIdx.y * 32;
    #pragma unroll
    for (int i = 0; i < 32; i += 8)
        tile[ty + i][tx] = qkv[(size_t)(b * TSEQ + t0 + ty + i) * 1152 + 2 * C_DIM + h * HD + d0 + tx];
    __syncthreads();
    #pragma unroll
    for (int i = 0; i < 32; i += 8)
        vt[((size_t)bh * HD + d0 + ty + i) * TSEQ + t0 + tx] = tile[tx][ty + i];
}

// ---------------------------------------------------------------------------
// LDS-staged bf16 MFMA GEMM, BM=128 x BN=128 (m97 structure), fragment-major
// gload_lds staging. QSCALE: scale output cols < C_DIM by QK_SCALE.
// KSPLIT: cols [C_DIM, 2*C_DIM) are written to ktc[bh][t][d] instead (K-repack
// fused into the QKV GEMM epilogue; branch is wave-uniform per fragment).
// ---------------------------------------------------------------------------
template<int OBF16, int BIAS, int RELU, int QSCALE, int KSPLIT>
__global__ __launch_bounds__(256)
void gemm_lds(const unsigned short* __restrict__ A, const unsigned short* __restrict__ Bt,
              const float* __restrict__ bias, void* __restrict__ Cv,
              unsigned short* __restrict__ ktc,
              int M, int N, int K)
{
    __shared__ __align__(16) unsigned short As[16 * 512];   // 16 frags x 1KB
    __shared__ __align__(16) unsigned short Bs[16 * 512];

    const int t = threadIdx.x, lane = t & 63, w = t >> 6;
    const int ln16 = lane & 15, hi16 = lane >> 4;
    const int wr = w >> 1, wc = w & 1;
    const int row0 = blockIdx.y * 128, col0 = blockIdx.x * 128;

    f32x4 acc[4][4] = {};

    for (int k0 = 0; k0 < K; k0 += 64) {
        #pragma unroll
        for (int i = 0; i < 4; ++i) {
            const int f  = w * 4 + i;
            const int ks = f >> 3, rf = f & 7;
            const int row = rf * 16 + ln16;
            const int kc  = k0 + ks * 32 + hi16 * 8;
            gload_lds16(&A [(size_t)(row0 + row) * K + kc], &As[f * 512]);
            gload_lds16(&Bt[(size_t)(col0 + row) * K + kc], &Bs[f * 512]);
        }
        __syncthreads();
        #pragma unroll
        for (int ks = 0; ks < 2; ++ks) {
            bfrag a[4], b[4];
            #pragma unroll
            for (int i = 0; i < 4; ++i)
                a[i] = *(const bfrag*)&As[(ks * 8 + wr * 4 + i) * 512 + lane * 8];
            #pragma unroll
            for (int j = 0; j < 4; ++j)
                b[j] = *(const bfrag*)&Bs[(ks * 8 + wc * 4 + j) * 512 + lane * 8];
            #pragma unroll
            for (int i = 0; i < 4; ++i)
                #pragma unroll
                for (int j = 0; j < 4; ++j)
                    acc[i][j] = __builtin_amdgcn_mfma_f32_16x16x32_bf16(a[i], b[j], acc[i][j], 0, 0, 0);
        }
        __syncthreads();
    }

    #pragma unroll
    for (int j = 0; j < 4; ++j) {
        const int cbase = col0 + wc * 64 + j * 16;      // 16-aligned, head-uniform
        const int col = cbase + ln16;
        const float bv = BIAS ? bias[col] : 0.0f;
        const float sc = (QSCALE && col < C_DIM) ? QK_SCALE : 1.0f;
        const bool kdest = KSPLIT && (cbase >= C_DIM) && (cbase < 2 * C_DIM);
        #pragma unroll
        for (int i = 0; i < 4; ++i) {
            #pragma unroll
            for (int e = 0; e < 4; ++e) {
                const int row = row0 + wr * 64 + i * 16 + hi16 * 4 + e;
                float v = acc[i][j][e] + bv;
                if (RELU) v = fmaxf(v, 0.0f);
                if (QSCALE) v *= sc;
                if (kdest) {
                    const int b  = row >> 11, tt = row & 2047;
                    const int hd = col - C_DIM;                 // h*64 + d
                    const int bh = b * HEADS + (hd >> 6);
                    ktc[((size_t)bh * TSEQ + tt) * HD + (hd & 63)] = f2bf(v);
                } else if (OBF16) {
                    ((unsigned short*)Cv)[(size_t)row * N + col] = f2bf(v);
                } else {
                    ((float*)Cv)[(size_t)row * N + col] = v;
                }
            }
        }
    }
}

// ---------------------------------------------------------------------------
// LDS-staged bf16 MFMA GEMM, BM=64 x BN=128 — for small-N GEMMs (N=384).
// ---------------------------------------------------------------------------
template<int OBF16, int BIAS, int RELU>
__global__ __launch_bounds__(256)
void gemm_lds64(const unsigned short* __restrict__ A, const unsigned short* __restrict__ Bt,
                const float* __restrict__ bias, void* __restrict__ Cv,
                int M, int N, int K)
{
    __shared__ __align__(16) unsigned short As[8 * 512];    // 8 frags x 1KB (64x64)
    __shared__ __align__(16) unsigned short Bs[16 * 512];   // 16 frags (128x64)

    const int t = threadIdx.x, lane = t & 63, w = t >> 6;
    const int ln16 = lane & 15, hi16 = lane >> 4;
    const int wr = w >> 1, wc = w & 1;
    const int row0 = blockIdx.y * 64, col0 = blockIdx.x * 128;

    f32x4 acc[2][4] = {};

    for (int k0 = 0; k0 < K; k0 += 64) {
        #pragma unroll
        for (int i = 0; i < 2; ++i) {
            const int f  = w * 2 + i;
            const int ks = f >> 2, rf = f & 3;
            gload_lds16(&A[(size_t)(row0 + rf * 16 + ln16) * K + k0 + ks * 32 + hi16 * 8],
                        &As[f * 512]);
        }
        #pragma unroll
        for (int i = 0; i < 4; ++i) {
            const int f  = w * 4 + i;
            const int ks = f >> 3, cf = f & 7;
            gload_lds16(&Bt[(size_t)(col0 + cf * 16 + ln16) * K + k0 + ks * 32 + hi16 * 8],
                        &Bs[f * 512]);
        }
        __syncthreads();
        #pragma unroll
        for (int ks = 0; ks < 2; ++ks) {
            bfrag a[2], b[4];
            #pragma unroll
            for (int i = 0; i < 2; ++i)
                a[i] = *(const bfrag*)&As[(ks * 4 + wr * 2 + i) * 512 + lane * 8];
            #pragma unroll
            for (int j = 0; j < 4; ++j)
                b[j] = *(const bfrag*)&Bs[(ks * 8 + wc * 4 + j) * 512 + lane * 8];
            #pragma unroll
            for (int i = 0; i < 2; ++i)
                #pragma unroll
                for (int j = 0; j < 4; ++j)
                    acc[i][j] = __builtin_amdgcn_mfma_f32_16x16x32_bf16(a[i], b[j], acc[i][j], 0, 0, 0);
        }
        __syncthreads();
    }

    #pragma unroll
    for (int j = 0; j < 4; ++j) {
        const int col = col0 + wc * 64 + j * 16 + ln16;
        const float bv = BIAS ? bias[col] : 0.0f;
        #pragma unroll
        for (int i = 0; i < 2; ++i) {
            #pragma unroll
            for (int e = 0; e < 4; ++e) {
                const int row = row0 + wr * 32 + i * 16 + hi16 * 4 + e;
                float v = acc[i][j][e] + bv;
                if (RELU) v = fmaxf(v, 0.0f);
                if (OBF16) ((unsigned short*)Cv)[(size_t)row * N + col] = f2bf(v);
                else       ((float*)Cv)[(size_t)row * N + col] = v;
            }
        }
    }
}

// ---------------------------------------------------------------------------
// attention helpers (s_setprio(1) around MFMA clusters — T5, attn-verified)
// ---------------------------------------------------------------------------
__device__ inline void qk16(const bfrag (&qf)[2][2], const bfrag (&kf)[4][2],
                            f32x4 (&sf)[2][4])
{
    __builtin_amdgcn_s_setprio(1);
    #pragma unroll
    for (int jt = 0; jt < 4; ++jt)
        #pragma unroll
        for (int ks = 0; ks < 2; ++ks) {
            sf[0][jt] = __builtin_amdgcn_mfma_f32_16x16x32_bf16(qf[0][ks], kf[jt][ks], sf[0][jt], 0, 0, 0);
            sf[1][jt] = __builtin_amdgcn_mfma_f32_16x16x32_bf16(qf[1][ks], kf[jt][ks], sf[1][jt], 0, 0, 0);
        }
    __builtin_amdgcn_s_setprio(0);
}

// softmax + PV. Mask applied on the fly.
__device__ inline void softmax_pv(f32x4 (&sf)[2][4], const bfrag (&vf)[4][2],
                                  f32x4 (&acc)[2][4],
                                  float (&mrow)[2][4], float (&lrow)[2][4],
                                  unsigned short (*Ps)[72],
                                  int tok0, int kt, bool last, int ln16, int hi16)
{
    float lmax[2][4];
    bool need = false;
    #pragma unroll
    for (int rf = 0; rf < 2; ++rf)
        #pragma unroll
        for (int e = 0; e < 4; ++e) {
            const int row = tok0 + rf * 16 + hi16 * 4 + e;
            float mx = -1e30f;
            #pragma unroll
            for (int jt = 0; jt < 4; ++jt) {
                float sv = sf[rf][jt][e];
                if (last && (kt * 64 + jt * 16 + ln16 > row)) sv = -1e30f;
                mx = fmaxf(mx, sv);
            }
            lmax[rf][e] = mx;
            need = need || (mx > mrow[rf][e] + 8.0f);
        }
    if (__any(need)) {
        #pragma unroll
        for (int rf = 0; rf < 2; ++rf)
            #pragma unroll
            for (int e = 0; e < 4; ++e) {
                float rm = lmax[rf][e];
                rm = fmaxf(rm, __shfl_xor(rm, 1));
                rm = fmaxf(rm, __shfl_xor(rm, 2));
                rm = fmaxf(rm, __shfl_xor(rm, 4));
                rm = fmaxf(rm, __shfl_xor(rm, 8));
                const float mn = fmaxf(mrow[rf][e], rm);
                const float corr = exp2f(mrow[rf][e] - mn);
                mrow[rf][e] = mn;
                lrow[rf][e] *= corr;
                #pragma unroll
                for (int dt = 0; dt < 4; ++dt) acc[rf][dt][e] *= corr;
            }
    }

    #pragma unroll
    for (int rf = 0; rf < 2; ++rf)
        #pragma unroll
        for (int jt = 0; jt < 4; ++jt)
            #pragma unroll
            for (int e = 0; e < 4; ++e) {
                const int row = tok0 + rf * 16 + hi16 * 4 + e;
                float sv = sf[rf][jt][e];
                if (last && (kt * 64 + jt * 16 + ln16 > row)) sv = -1e30f;
                const float pe = exp2f(sv - mrow[rf][e]);
                lrow[rf][e] += pe;
                Ps[rf * 16 + hi16 * 4 + e][jt * 16 + ln16] = f2bf_t(pe);
            }

    bfrag pf[2][2];
    #pragma unroll
    for (int rf = 0; rf < 2; ++rf)
        #pragma unroll
        for (int ks = 0; ks < 2; ++ks)
            pf[rf][ks] = *(const bfrag*)&Ps[rf * 16 + ln16][ks * 32 + hi16 * 8];
    __builtin_amdgcn_s_setprio(1);
    #pragma unroll
    for (int ks = 0; ks < 2; ++ks)
        #pragma unroll
        for (int rf = 0; rf < 2; ++rf)
            #pragma unroll
            for (int dt = 0; dt < 4; ++dt)
                acc[rf][dt] = __builtin_amdgcn_mfma_f32_16x16x32_bf16(pf[rf][ks], vf[dt][ks], acc[rf][dt], 0, 0, 0);
    __builtin_amdgcn_s_setprio(0);
}

// ---------------------------------------------------------------------------
// Split-K flash attention (moderate split, r15 structure — at its
// concurrency-throughput floor; only micro-tweaks remain).
// ---------------------------------------------------------------------------
__global__ __launch_bounds__(64)
void attn_kernel(const unsigned short* __restrict__ qkv,
                 const unsigned short* __restrict__ ktc,
                 const unsigned short* __restrict__ vt,
                 unsigned short* __restrict__ att,
                 unsigned short* __restrict__ pacc,
                 float* __restrict__ pml)
{
    __shared__ __align__(16) unsigned short Ps[32][72];
    const int lane = threadIdx.x;
    const int ln16 = lane & 15, hi16 = lane >> 4;
    const int bid = blockIdx.x;            // 0..2303
    const int xcd = bid & 7;
    const int i   = bid >> 3;              // 0..287
    int bh, qw, kt0, kte, ck = 0;
    bool heavy;
    if (i < 192) {                         // heavy chunk waves, qw descending
        qw = 63 - (i / 6);                 // 63..32
        const int r = i % 6;
        bh = xcd * 3 + (r >> 1);
        ck = r & 1;
        const int NT = (qw >> 1) + 1;      // 17..32
        const int half = NT >> 1;          // 8..16
        kt0 = ck ? half : 0;
        kte = ck ? NT : half;
        heavy = true;
    } else {                               // light strips
        const int j = i - 192;             // 0..95
        qw = 31 - (j / 3);                 // 31..0
        bh = xcd * 3 + (j % 3);
        kt0 = 0;
        kte = (qw >> 1) + 1;               // <= 16
        heavy = false;
    }
    const int NTfull = (qw >> 1) + 1;
    const int b = bh / HEADS, h = bh % HEADS;
    const int tok0 = qw * 32;
    const size_t qrow0 = (size_t)b * TSEQ;

    bfrag qf[2][2];
    #pragma unroll
    for (int rf = 0; rf < 2; ++rf)
        #pragma unroll
        for (int ks = 0; ks < 2; ++ks)
            qf[rf][ks] = *(const bfrag*)&qkv[(qrow0 + tok0 + rf * 16 + ln16) * 1152 + h * HD + ks * 32 + hi16 * 8];

    f32x4 acc[2][4] = {};
    float mrow[2][4], lrow[2][4];
    #pragma unroll
    for (int rf = 0; rf < 2; ++rf)
        #pragma unroll
        for (int e = 0; e < 4; ++e) { mrow[rf][e] = -1e30f; lrow[rf][e] = 0.0f; }

    const unsigned short* Kb = ktc + (size_t)bh * TSEQ * HD;
    const unsigned short* Vb = vt  + (size_t)bh * HD * TSEQ;

    bfrag kf[4][2];
    #pragma unroll
    for (int jt = 0; jt < 4; ++jt)
        #pragma unroll
        for (int ks = 0; ks < 2; ++ks)
            kf[jt][ks] = *(const bfrag*)&Kb[(size_t)(kt0 * 64 + jt * 16 + ln16) * HD + ks * 32 + hi16 * 8];

    for (int kt = kt0; kt < kte; ++kt) {
        bfrag vf[4][2];
        #pragma unroll
        for (int dt = 0; dt < 4; ++dt)
            #pragma unroll
            for (int ks = 0; ks < 2; ++ks)
                vf[dt][ks] = *(const bfrag*)&Vb[(size_t)(dt * 16 + ln16) * TSEQ + kt * 64 + ks * 32 + hi16 * 8];

        f32x4 sf[2][4] = {};
        qk16(qf, kf, sf);

        if (kt + 1 < kte) {
            #pragma unroll
            for (int jt = 0; jt < 4; ++jt)
                #pragma unroll
                for (int ks = 0; ks < 2; ++ks)
                    kf[jt][ks] = *(const bfrag*)&Kb[(size_t)((kt + 1) * 64 + jt * 16 + ln16) * HD + ks * 32 + hi16 * 8];
        }

        softmax_pv(sf, vf, acc, mrow, lrow, Ps, tok0, kt, kt == NTfull - 1, ln16, hi16);
    }

    float lsum[2][4];
    #pragma unroll
    for (int rf = 0; rf < 2; ++rf)
        #pragma unroll
        for (int e = 0; e < 4; ++e) {
            float l = lrow[rf][e];
            l += __shfl_xor(l, 1);
            l += __shfl_xor(l, 2);
            l += __shfl_xor(l, 4);
            l += __shfl_xor(l, 8);
            lsum[rf][e] = l;
        }

    if (!heavy) {
        #pragma unroll
        for (int rf = 0; rf < 2; ++rf)
            #pragma unroll
            for (int e = 0; e < 4; ++e) {
                const float inv = 1.0f / lsum[rf][e];
                const size_t row = qrow0 + tok0 + rf * 16 + hi16 * 4 + e;
                #pragma unroll
                for (int dt = 0; dt < 4; ++dt)
                    att[row * C_DIM + h * HD + dt * 16 + ln16] = f2bf(acc[rf][dt][e] * inv);
            }
    } else {
        const int sidx = bh * 32 + (qw - 32);     // 0..767
        const size_t pb = (size_t)sidx * 2 + ck;
        #pragma unroll
        for (int rf = 0; rf < 2; ++rf)
            #pragma unroll
            for (int dt = 0; dt < 4; ++dt)
                #pragma unroll
                for (int e = 0; e < 4; ++e) {
                    const int row = rf * 16 + hi16 * 4 + e;
                    pacc[(pb * 32 + row) * 64 + dt * 16 + ln16] = f2bf(acc[rf][dt][e]);
                }
        if (ln16 == 0) {
            #pragma unroll
            for (int rf = 0; rf < 2; ++rf)
                #pragma unroll
                for (int e = 0; e < 4; ++e) {
                    const int row = rf * 16 + hi16 * 4 + e;
                    pml[pb * 64 + row * 2 + 0] = mrow[rf][e];
                    pml[pb * 64 + row * 2 + 1] = lsum[rf][e];
                }
        }
    }
}

// ---------------------------------------------------------------------------
// Combine the 2 chunks of each heavy strip. 768 blocks x 256 thr.
// ---------------------------------------------------------------------------
__global__ __launch_bounds__(256)
void attn_combine(const unsigned short* __restrict__ pacc,
                  const float* __restrict__ pml,
                  unsigned short* __restrict__ att)
{
    const int sidx = blockIdx.x;           // 0..767
    const int bh = sidx >> 5;
    const int qw = 32 + (sidx & 31);
    const int b = bh / HEADS, h = bh % HEADS;
    const int tid = threadIdx.x;
    const int row = tid >> 3;              // 0..31
    const int d0  = (tid & 7) * 8;

    const float m0 = pml[((size_t)sidx * 2 + 0) * 64 + row * 2 + 0];
    const float l0 = pml[((size_t)sidx * 2 + 0) * 64 + row * 2 + 1];
    const float m1 = pml[((size_t)sidx * 2 + 1) * 64 + row * 2 + 0];
    const float l1 = pml[((size_t)sidx * 2 + 1) * 64 + row * 2 + 1];
    const float M  = fmaxf(m0, m1);
    const float w0 = exp2f(m0 - M), w1 = exp2f(m1 - M);
    const float invL = 1.0f / (l0 * w0 + l1 * w1);

    ushort8_t a0 = *(const ushort8_t*)&pacc[(((size_t)sidx * 2 + 0) * 32 + row) * 64 + d0];
    ushort8_t a1 = *(const ushort8_t*)&pacc[(((size_t)sidx * 2 + 1) * 32 + row) * 64 + d0];
    ushort8_t rv;
    #pragma unroll
    for (int k = 0; k < 8; ++k) {
        const float v0 = bf2f(a0[k]);
        const float v1 = bf2f(a1[k]);
        rv[k] = f2bf((v0 * w0 + v1 * w1) * invL);
    }
    const size_t grow = (size_t)b * TSEQ + qw * 32 + row;
    *(ushort8_t*)&att[grow * C_DIM + h * HD + d0] = rv;
}

// ---------------------------------------------------------------------------
// Fused residual add + LayerNorm.
// ABF16: residual input A is bf16. WF32: write f32 out. WBF: write bf16 out.
// ---------------------------------------------------------------------------
template<int ABF16, int WF32, int WBF>
__global__ __launch_bounds__(256)
void ln_residual_kernel(const void* __restrict__ Av, const float* __restrict__ R,
                        const float* __restrict__ gamma, const float* __restrict__ beta,
                        float* __restrict__ out, unsigned short* __restrict__ outb, int Mrows)
{
    const int lane = threadIdx.x & 63;
    const int wv   = threadIdx.x >> 6;
    const int row  = blockIdx.x * 4 + wv;
    if (row >= Mrows) return;
    const size_t off = (size_t)row * C_DIM;

    float v[6];
    float sum = 0.0f;
    #pragma unroll
    for (int j = 0; j < 6; ++j) {
        const int c = lane + 64 * j;
        const float a = ABF16 ? bf2f(((const unsigned short*)Av)[off + c])
                              : ((const float*)Av)[off + c];
        v[j] = a + R[off + c];
        sum += v[j];
    }
    #pragma unroll
    for (int o = 1; o < 64; o <<= 1) sum += __shfl_xor(sum, o);
    const float mu = sum * (1.0f / C_DIM);

    float sq = 0.0f;
    #pragma unroll
    for (int j = 0; j < 6; ++j) { const float d = v[j] - mu; sq = fmaf(d, d, sq); }
    #pragma unroll
    for (int o = 1; o < 64; o <<= 1) sq += __shfl_xor(sq, o);
    const float rstd = rsqrtf(sq * (1.0f / C_DIM) + LN_EPS);

    #pragma unroll
    for (int j = 0; j < 6; ++j) {
        const int c = lane + 64 * j;
        const float r = (v[j] - mu) * rstd * gamma[c] + beta[c];
        if (WF32) out[off + c] = r;
        if (WBF)  outb[off + c] = f2bf(r);
    }
}

// ---------------------------------------------------------------------------
extern "C" void kernel_launch(void* const* d_in, const int* in_sizes, int n_in,
                              void* d_out, int out_size, void* d_ws, size_t ws_size,
                              hipStream_t stream)
{
    const float* x   = (const float*)d_in[0];
    const float* Wq  = (const float*)d_in[1];
    const float* Wk  = (const float*)d_in[2];
    const float* Wv  = (const float*)d_in[3];
    const float* Wo  = (const float*)d_in[4];
    const float* bo  = (const float*)d_in[5];
    const float* W1  = (const float*)d_in[6];
    const float* b1  = (const float*)d_in[7];
    const float* W2  = (const float*)d_in[8];
    const float* b2  = (const float*)d_in[9];
    const float* g1  = (const float*)d_in[10];
    const float* be1 = (const float*)d_in[11];
    const float* g2  = (const float*)d_in[12];
    const float* be2 = (const float*)d_in[13];
    float* out = (float*)d_out;

    const int M = BATCH * TSEQ;                  // 8192
    const size_t MC = (size_t)M * C_DIM;

    // ---- workspace layout (bytes) ----
    char* ws = (char*)d_ws;
    unsigned short* qkv = (unsigned short*)ws;                       // M*1152*2 = 18.87 MB
    unsigned short* vt  = (unsigned short*)(ws + (size_t)M*1152*2);  // 6.29 MB
    unsigned short* att = (unsigned short*)(ws + (size_t)M*1152*2 + (size_t)BATCH*HEADS*HD*TSEQ*2); // 6.29 MB
    unsigned short* h1  = (unsigned short*)ws;                       // M*1536*2, aliases qkv+vt
    char* p2 = ws + (size_t)M*1152*2 + (size_t)BATCH*HEADS*HD*TSEQ*2 + MC*2;   // 31.46 MB mark
    unsigned short* xb  = (unsigned short*)p2;                       // MC bf16 (QKV gemm input)
    float* y   = (float*)(p2 + MC*2);                                // MC f32
    unsigned short* ktc = (unsigned short*)(p2 + MC*2 + MC*4);       // 6.29 MB (old x1 slot)
    unsigned short* x1b = (unsigned short*)(p2 + MC*2 + 2*MC*4);     // MC bf16
    char* p3 = p2 + MC*2 + 2*MC*4 + MC*2;
    unsigned short* Wqkv_t = (unsigned short*)p3;                        // [1152][384]
    unsigned short* Wo_t   = Wqkv_t + (size_t)3*C_DIM*C_DIM;             // [384][384]
    unsigned short* W1_t   = Wo_t   + (size_t)C_DIM*C_DIM;               // [1536][384]
    unsigned short* W2_t   = W1_t   + (size_t)FF_DIM*C_DIM;              // [384][1536]

    // split-K partials in y region (dead during attn):
    unsigned short* pacc = (unsigned short*)(p2 + MC*2);
    float* pml = (float*)(p2 + MC*2 + (size_t)1536*32*64*2);

    dim3 b256(256), b328(32, 8);

    // ---- all weight transposes in one launch ----
    transpose_all<<<dim3(1728), b328, 0, stream>>>(
        Wq, Wk, Wv, Wo, W1, W2, Wqkv_t, Wo_t, W1_t, W2_t);

    // ---- x -> bf16 ----
    cvt_f32_bf16_x4<<<dim3((MC/4 + 255)/256), b256, 0, stream>>>(x, xb, (int)(MC/4));

    // ---- qkv = xb @ Wqkv (Q pre-scaled; K written straight to ktc) ----
    gemm_lds<1, 0, 0, 1, 1><<<dim3(3*C_DIM/128, M/128), b256, 0, stream>>>(
        xb, Wqkv_t, nullptr, qkv, ktc, M, 3*C_DIM, C_DIM);

    // ---- V transpose ----
    vtrans_kernel<<<dim3(TSEQ/32, HD/32, BATCH*HEADS), b328, 0, stream>>>(qkv, vt);

    // ---- attention: 2304 waves (heavy strips split in 2), then combine ----
    attn_kernel<<<dim3(2304), dim3(64), 0, stream>>>(qkv, ktc, vt, att, pacc, pml);
    attn_combine<<<dim3(768), b256, 0, stream>>>(pacc, pml, att);

    // ---- y = att @ Wo + bo  (BM=64: 384 blocks) ----
    gemm_lds64<0, 1, 0><<<dim3(C_DIM/128, M/64), b256, 0, stream>>>(
        att, Wo_t, bo, y, M, C_DIM, C_DIM);

    // ---- x1b = LN(x + y)  (bf16 only) ----
    ln_residual_kernel<0, 0, 1><<<dim3(M/4), b256, 0, stream>>>(
        x, y, g1, be1, nullptr, x1b, M);

    // ---- h1 = relu(x1b @ W1 + b1) ----
    gemm_lds<1, 1, 1, 0, 0><<<dim3(FF_DIM/128, M/128), b256, 0, stream>>>(
        x1b, W1_t, b1, h1, nullptr, M, FF_DIM, C_DIM);

    // ---- y = h1 @ W2 + b2  (BM=64: 384 blocks, K=1536) ----
    gemm_lds64<0, 1, 0><<<dim3(C_DIM/128, M/64), b256, 0, stream>>>(
        h1, W2_t, b2, y, M, C_DIM, FF_DIM);

    // ---- out = LN(x1b + y) ----
    ln_residual_kernel<1, 1, 0><<<dim3(M/4), b256, 0, stream>>>(
        x1b, y, g2, be2, out, nullptr, M);
}

// Round 17
// 192.773 us; speedup vs baseline: 1.1585x; 1.0135x over previous
//
#include <hip/hip_runtime.h>

#define C_DIM  384
#define HEADS  6
#define HD     64
#define FF_DIM 1536
#define LN_EPS 1e-3f
#define TSEQ   2048
#define BATCH  4
#define LOG2E  1.4426950408889634f
#define QK_SCALE 0.18033688011112042f   // 0.125 * log2(e), folded into Q

typedef __attribute__((ext_vector_type(2))) float          f32x2;
typedef __attribute__((ext_vector_type(4))) float          f32x4;
typedef __attribute__((ext_vector_type(4))) float          float4_t;
typedef __attribute__((ext_vector_type(8))) short          bfrag;     // 8 bf16
typedef __attribute__((ext_vector_type(4))) unsigned short ushort4_t;
typedef __attribute__((ext_vector_type(8))) unsigned short ushort8_t;

__device__ inline unsigned short f2bf(float f) {
    unsigned int u = __builtin_bit_cast(unsigned int, f);
    u += 0x7fff + ((u >> 16) & 1);          // RNE
    return (unsigned short)(u >> 16);
}
// truncating convert — P matrix only (values in [0,1], re-normalized)
__device__ inline unsigned short f2bf_t(float f) {
    return (unsigned short)(__builtin_bit_cast(unsigned int, f) >> 16);
}
__device__ inline float bf2f(unsigned short u) {
    return __builtin_bit_cast(float, (unsigned int)u << 16);
}

// async global->LDS, 16 B per lane. LDS dest is wave-uniform base + lane*16.
__device__ inline void gload_lds16(const void* g, void* l) {
    __builtin_amdgcn_global_load_lds(
        (const __attribute__((address_space(1))) unsigned int*)g,
        (__attribute__((address_space(3))) unsigned int*)l,
        16, 0, 0);
}

// chunked XCD swizzle: HW maps flat blockIdx round-robin (bid&7 = XCD, r10).
// Remap so each XCD owns a CONTIGUOUS logical range (A-panel L2 locality).
// Requires nwg % 8 == 0 (true for all GEMM grids here).
__device__ inline int xcd_chunk(int flat, int nwg) {
    return (flat >> 3) + (flat & 7) * (nwg >> 3);
}

// ---------------------------------------------------------------------------
// Fused: all weight transposes (W[K][N] f32 -> Wt[N][K] bf16) + x -> bf16.
// Blocks 0..575: four 384x384; 576..1151: W1; 1152..1727: W2;
// 1728..4799: cvt x (3072 blocks x 256 float4 = exact). block (32,8).
// ---------------------------------------------------------------------------
__global__ __launch_bounds__(256)
void prep_all(const float* __restrict__ Wq, const float* __restrict__ Wk,
              const float* __restrict__ Wv, const float* __restrict__ Wo,
              const float* __restrict__ W1, const float* __restrict__ W2,
              const float* __restrict__ x,
              unsigned short* __restrict__ Dqkv, unsigned short* __restrict__ Do_,
              unsigned short* __restrict__ D1, unsigned short* __restrict__ D2,
              unsigned short* __restrict__ xb)
{
    __shared__ float tile[32][33];
    const int bidx = blockIdx.x;
    const int tx = threadIdx.x, ty = threadIdx.y;
    if (bidx >= 1728) {
        const int i = (bidx - 1728) * 256 + ty * 32 + tx;
        float4_t v = ((const float4_t*)x)[i];
        ushort4_t o = { f2bf(v.x), f2bf(v.y), f2bf(v.z), f2bf(v.w) };
        ((ushort4_t*)xb)[i] = o;
        return;
    }
    const float* W; unsigned short* D;
    int K, N, nx, ny;
    if (bidx < 576) {
        const int z = bidx / 144, r = bidx % 144;
        W = z == 0 ? Wq : (z == 1 ? Wk : (z == 2 ? Wv : Wo));
        D = z == 3 ? Do_ : Dqkv + (size_t)z * C_DIM * C_DIM;
        K = N = C_DIM; nx = r % 12; ny = r / 12;
    } else if (bidx < 1152) {
        const int r = bidx - 576;
        W = W1; D = D1; K = C_DIM; N = FF_DIM; nx = r % 48; ny = r / 48;
    } else {
        const int r = bidx - 1152;
        W = W2; D = D2; K = FF_DIM; N = C_DIM; nx = r % 12; ny = r / 12;
    }
    const int n0 = nx * 32, k0 = ny * 32;
    #pragma unroll
    for (int i = 0; i < 32; i += 8)
        tile[ty + i][tx] = W[(size_t)(k0 + ty + i) * N + n0 + tx];
    __syncthreads();
    #pragma unroll
    for (int i = 0; i < 32; i += 8)
        D[(size_t)(n0 + ty + i) * K + k0 + tx] = f2bf(tile[tx][ty + i]);
}

// ---------------------------------------------------------------------------
// V transpose only: qkv v-cols -> vt[bh][d][t] bf16.
// ---------------------------------------------------------------------------
__global__ __launch_bounds__(256)
void vtrans_kernel(const unsigned short* __restrict__ qkv,
                   unsigned short* __restrict__ vt)
{
    __shared__ unsigned short tile[32][34];
    const int tx = threadIdx.x, ty = threadIdx.y;
    const int bh = blockIdx.z, b = bh / HEADS, h = bh % HEADS;
    const int t0 = blockIdx.x * 32, d0 = blockIdx.y * 32;
    #pragma unroll
    for (int i = 0; i < 32; i += 8)
        tile[ty + i][tx] = qkv[(size_t)(b * TSEQ + t0 + ty + i) * 1152 + 2 * C_DIM + h * HD + d0 + tx];
    __syncthreads();
    #pragma unroll
    for (int i = 0; i < 32; i += 8)
        vt[((size_t)bh * HD + d0 + ty + i) * TSEQ + t0 + tx] = tile[tx][ty + i];
}

// ---------------------------------------------------------------------------
// LDS-staged bf16 MFMA GEMM, BM=128 x BN=128 (m97 structure), fragment-major
// gload_lds staging. QSCALE: scale output cols < C_DIM by QK_SCALE.
// KSPLIT: cols [C_DIM, 2*C_DIM) written to ktc[bh][t][d] (fused K-repack).
// Chunked XCD swizzle on the flat block id (T1).
// ---------------------------------------------------------------------------
template<int OBF16, int BIAS, int RELU, int QSCALE, int KSPLIT>
__global__ __launch_bounds__(256)
void gemm_lds(const unsigned short* __restrict__ A, const unsigned short* __restrict__ Bt,
              const float* __restrict__ bias, void* __restrict__ Cv,
              unsigned short* __restrict__ ktc,
              int M, int N, int K)
{
    __shared__ __align__(16) unsigned short As[16 * 512];   // 16 frags x 1KB
    __shared__ __align__(16) unsigned short Bs[16 * 512];

    const int t = threadIdx.x, lane = t & 63, w = t >> 6;
    const int ln16 = lane & 15, hi16 = lane >> 4;
    const int wr = w >> 1, wc = w & 1;
    const int nwg = gridDim.x * gridDim.y;
    const int L = xcd_chunk(blockIdx.y * gridDim.x + blockIdx.x, nwg);
    const int row0 = (L / gridDim.x) * 128, col0 = (L % gridDim.x) * 128;

    f32x4 acc[4][4] = {};

    for (int k0 = 0; k0 < K; k0 += 64) {
        #pragma unroll
        for (int i = 0; i < 4; ++i) {
            const int f  = w * 4 + i;
            const int ks = f >> 3, rf = f & 7;
            const int row = rf * 16 + ln16;
            const int kc  = k0 + ks * 32 + hi16 * 8;
            gload_lds16(&A [(size_t)(row0 + row) * K + kc], &As[f * 512]);
            gload_lds16(&Bt[(size_t)(col0 + row) * K + kc], &Bs[f * 512]);
        }
        __syncthreads();
        #pragma unroll
        for (int ks = 0; ks < 2; ++ks) {
            bfrag a[4], b[4];
            #pragma unroll
            for (int i = 0; i < 4; ++i)
                a[i] = *(const bfrag*)&As[(ks * 8 + wr * 4 + i) * 512 + lane * 8];
            #pragma unroll
            for (int j = 0; j < 4; ++j)
                b[j] = *(const bfrag*)&Bs[(ks * 8 + wc * 4 + j) * 512 + lane * 8];
            #pragma unroll
            for (int i = 0; i < 4; ++i)
                #pragma unroll
                for (int j = 0; j < 4; ++j)
                    acc[i][j] = __builtin_amdgcn_mfma_f32_16x16x32_bf16(a[i], b[j], acc[i][j], 0, 0, 0);
        }
        __syncthreads();
    }

    #pragma unroll
    for (int j = 0; j < 4; ++j) {
        const int cbase = col0 + wc * 64 + j * 16;      // 16-aligned, head-uniform
        const int col = cbase + ln16;
        const float bv = BIAS ? bias[col] : 0.0f;
        const float sc = (QSCALE && col < C_DIM) ? QK_SCALE : 1.0f;
        const bool kdest = KSPLIT && (cbase >= C_DIM) && (cbase < 2 * C_DIM);
        #pragma unroll
        for (int i = 0; i < 4; ++i) {
            #pragma unroll
            for (int e = 0; e < 4; ++e) {
                const int row = row0 + wr * 64 + i * 16 + hi16 * 4 + e;
                float v = acc[i][j][e] + bv;
                if (RELU) v = fmaxf(v, 0.0f);
                if (QSCALE) v *= sc;
                if (kdest) {
                    const int b  = row >> 11, tt = row & 2047;
                    const int hd = col - C_DIM;                 // h*64 + d
                    const int bh = b * HEADS + (hd >> 6);
                    ktc[((size_t)bh * TSEQ + tt) * HD + (hd & 63)] = f2bf(v);
                } else if (OBF16) {
                    ((unsigned short*)Cv)[(size_t)row * N + col] = f2bf(v);
                } else {
                    ((float*)Cv)[(size_t)row * N + col] = v;
                }
            }
        }
    }
}

// ---------------------------------------------------------------------------
// LDS-staged bf16 MFMA GEMM, BM=64 x BN=128 — for small-N GEMMs (N=384).
// Chunked XCD swizzle on the flat block id (T1).
// ---------------------------------------------------------------------------
template<int OBF16, int BIAS, int RELU>
__global__ __launch_bounds__(256)
void gemm_lds64(const unsigned short* __restrict__ A, const unsigned short* __restrict__ Bt,
                const float* __restrict__ bias, void* __restrict__ Cv,
                int M, int N, int K)
{
    __shared__ __align__(16) unsigned short As[8 * 512];    // 8 frags x 1KB (64x64)
    __shared__ __align__(16) unsigned short Bs[16 * 512];   // 16 frags (128x64)

    const int t = threadIdx.x, lane = t & 63, w = t >> 6;
    const int ln16 = lane & 15, hi16 = lane >> 4;
    const int wr = w >> 1, wc = w & 1;
    const int nwg = gridDim.x * gridDim.y;
    const int L = xcd_chunk(blockIdx.y * gridDim.x + blockIdx.x, nwg);
    const int row0 = (L / gridDim.x) * 64, col0 = (L % gridDim.x) * 128;

    f32x4 acc[2][4] = {};

    for (int k0 = 0; k0 < K; k0 += 64) {
        #pragma unroll
        for (int i = 0; i < 2; ++i) {
            const int f  = w * 2 + i;
            const int ks = f >> 2, rf = f & 3;
            gload_lds16(&A[(size_t)(row0 + rf * 16 + ln16) * K + k0 + ks * 32 + hi16 * 8],
                        &As[f * 512]);
        }
        #pragma unroll
        for (int i = 0; i < 4; ++i) {
            const int f  = w * 4 + i;
            const int ks = f >> 3, cf = f & 7;
            gload_lds16(&Bt[(size_t)(col0 + cf * 16 + ln16) * K + k0 + ks * 32 + hi16 * 8],
                        &Bs[f * 512]);
        }
        __syncthreads();
        #pragma unroll
        for (int ks = 0; ks < 2; ++ks) {
            bfrag a[2], b[4];
            #pragma unroll
            for (int i = 0; i < 2; ++i)
                a[i] = *(const bfrag*)&As[(ks * 4 + wr * 2 + i) * 512 + lane * 8];
            #pragma unroll
            for (int j = 0; j < 4; ++j)
                b[j] = *(const bfrag*)&Bs[(ks * 8 + wc * 4 + j) * 512 + lane * 8];
            #pragma unroll
            for (int i = 0; i < 2; ++i)
                #pragma unroll
                for (int j = 0; j < 4; ++j)
                    acc[i][j] = __builtin_amdgcn_mfma_f32_16x16x32_bf16(a[i], b[j], acc[i][j], 0, 0, 0);
        }
        __syncthreads();
    }

    #pragma unroll
    for (int j = 0; j < 4; ++j) {
        const int col = col0 + wc * 64 + j * 16 + ln16;
        const float bv = BIAS ? bias[col] : 0.0f;
        #pragma unroll
        for (int i = 0; i < 2; ++i) {
            #pragma unroll
            for (int e = 0; e < 4; ++e) {
                const int row = row0 + wr * 32 + i * 16 + hi16 * 4 + e;
                float v = acc[i][j][e] + bv;
                if (RELU) v = fmaxf(v, 0.0f);
                if (OBF16) ((unsigned short*)Cv)[(size_t)row * N + col] = f2bf(v);
                else       ((float*)Cv)[(size_t)row * N + col] = v;
            }
        }
    }
}

// ---------------------------------------------------------------------------
// attention helpers (s_setprio(1) around MFMA clusters — T5)
// ---------------------------------------------------------------------------
__device__ inline void qk16(const bfrag (&qf)[2][2], const bfrag (&kf)[4][2],
                            f32x4 (&sf)[2][4])
{
    __builtin_amdgcn_s_setprio(1);
    #pragma unroll
    for (int jt = 0; jt < 4; ++jt)
        #pragma unroll
        for (int ks = 0; ks < 2; ++ks) {
            sf[0][jt] = __builtin_amdgcn_mfma_f32_16x16x32_bf16(qf[0][ks], kf[jt][ks], sf[0][jt], 0, 0, 0);
            sf[1][jt] = __builtin_amdgcn_mfma_f32_16x16x32_bf16(qf[1][ks], kf[jt][ks], sf[1][jt], 0, 0, 0);
        }
    __builtin_amdgcn_s_setprio(0);
}

// softmax + PV. Mask applied on the fly.
__device__ inline void softmax_pv(f32x4 (&sf)[2][4], const bfrag (&vf)[4][2],
                                  f32x4 (&acc)[2][4],
                                  float (&mrow)[2][4], float (&lrow)[2][4],
                                  unsigned short (*Ps)[72],
                                  int tok0, int kt, bool last, int ln16, int hi16)
{
    float lmax[2][4];
    bool need = false;
    #pragma unroll
    for (int rf = 0; rf < 2; ++rf)
        #pragma unroll
        for (int e = 0; e < 4; ++e) {
            const int row = tok0 + rf * 16 + hi16 * 4 + e;
            float mx = -1e30f;
            #pragma unroll
            for (int jt = 0; jt < 4; ++jt) {
                float sv = sf[rf][jt][e];
                if (last && (kt * 64 + jt * 16 + ln16 > row)) sv = -1e30f;
                mx = fmaxf(mx, sv);
            }
            lmax[rf][e] = mx;
            need = need || (mx > mrow[rf][e] + 8.0f);
        }
    if (__any(need)) {
        #pragma unroll
        for (int rf = 0; rf < 2; ++rf)
            #pragma unroll
            for (int e = 0; e < 4; ++e) {
                float rm = lmax[rf][e];
                rm = fmaxf(rm, __shfl_xor(rm, 1));
                rm = fmaxf(rm, __shfl_xor(rm, 2));
                rm = fmaxf(rm, __shfl_xor(rm, 4));
                rm = fmaxf(rm, __shfl_xor(rm, 8));
                const float mn = fmaxf(mrow[rf][e], rm);
                const float corr = exp2f(mrow[rf][e] - mn);
                mrow[rf][e] = mn;
                lrow[rf][e] *= corr;
                #pragma unroll
                for (int dt = 0; dt < 4; ++dt) acc[rf][dt][e] *= corr;
            }
    }

    #pragma unroll
    for (int rf = 0; rf < 2; ++rf)
        #pragma unroll
        for (int jt = 0; jt < 4; ++jt)
            #pragma unroll
            for (int e = 0; e < 4; ++e) {
                const int row = tok0 + rf * 16 + hi16 * 4 + e;
                float sv = sf[rf][jt][e];
                if (last && (kt * 64 + jt * 16 + ln16 > row)) sv = -1e30f;
                const float pe = exp2f(sv - mrow[rf][e]);
                lrow[rf][e] += pe;
                Ps[rf * 16 + hi16 * 4 + e][jt * 16 + ln16] = f2bf_t(pe);
            }

    bfrag pf[2][2];
    #pragma unroll
    for (int rf = 0; rf < 2; ++rf)
        #pragma unroll
        for (int ks = 0; ks < 2; ++ks)
            pf[rf][ks] = *(const bfrag*)&Ps[rf * 16 + ln16][ks * 32 + hi16 * 8];
    __builtin_amdgcn_s_setprio(1);
    #pragma unroll
    for (int ks = 0; ks < 2; ++ks)
        #pragma unroll
        for (int rf = 0; rf < 2; ++rf)
            #pragma unroll
            for (int dt = 0; dt < 4; ++dt)
                acc[rf][dt] = __builtin_amdgcn_mfma_f32_16x16x32_bf16(pf[rf][ks], vf[dt][ks], acc[rf][dt], 0, 0, 0);
    __builtin_amdgcn_s_setprio(0);
}

// ---------------------------------------------------------------------------
// Split-K flash attention (moderate split, r15 structure — at its
// concurrency-throughput floor).
// ---------------------------------------------------------------------------
__global__ __launch_bounds__(64)
void attn_kernel(const unsigned short* __restrict__ qkv,
                 const unsigned short* __restrict__ ktc,
                 const unsigned short* __restrict__ vt,
                 unsigned short* __restrict__ att,
                 unsigned short* __restrict__ pacc,
                 float* __restrict__ pml)
{
    __shared__ __align__(16) unsigned short Ps[32][72];
    const int lane = threadIdx.x;
    const int ln16 = lane & 15, hi16 = lane >> 4;
    const int bid = blockIdx.x;            // 0..2303
    const int xcd = bid & 7;
    const int i   = bid >> 3;              // 0..287
    int bh, qw, kt0, kte, ck = 0;
    bool heavy;
    if (i < 192) {                         // heavy chunk waves, qw descending
        qw = 63 - (i / 6);                 // 63..32
        const int r = i % 6;
        bh = xcd * 3 + (r >> 1);
        ck = r & 1;
        const int NT = (qw >> 1) + 1;      // 17..32
        const int half = NT >> 1;          // 8..16
        kt0 = ck ? half : 0;
        kte = ck ? NT : half;
        heavy = true;
    } else {                               // light strips
        const int j = i - 192;             // 0..95
        qw = 31 - (j / 3);                 // 31..0
        bh = xcd * 3 + (j % 3);
        kt0 = 0;
        kte = (qw >> 1) + 1;               // <= 16
        heavy = false;
    }
    const int NTfull = (qw >> 1) + 1;
    const int b = bh / HEADS, h = bh % HEADS;
    const int tok0 = qw * 32;
    const size_t qrow0 = (size_t)b * TSEQ;

    bfrag qf[2][2];
    #pragma unroll
    for (int rf = 0; rf < 2; ++rf)
        #pragma unroll
        for (int ks = 0; ks < 2; ++ks)
            qf[rf][ks] = *(const bfrag*)&qkv[(qrow0 + tok0 + rf * 16 + ln16) * 1152 + h * HD + ks * 32 + hi16 * 8];

    f32x4 acc[2][4] = {};
    float mrow[2][4], lrow[2][4];
    #pragma unroll
    for (int rf = 0; rf < 2; ++rf)
        #pragma unroll
        for (int e = 0; e < 4; ++e) { mrow[rf][e] = -1e30f; lrow[rf][e] = 0.0f; }

    const unsigned short* Kb = ktc + (size_t)bh * TSEQ * HD;
    const unsigned short* Vb = vt  + (size_t)bh * HD * TSEQ;

    bfrag kf[4][2];
    #pragma unroll
    for (int jt = 0; jt < 4; ++jt)
        #pragma unroll
        for (int ks = 0; ks < 2; ++ks)
            kf[jt][ks] = *(const bfrag*)&Kb[(size_t)(kt0 * 64 + jt * 16 + ln16) * HD + ks * 32 + hi16 * 8];

    for (int kt = kt0; kt < kte; ++kt) {
        bfrag vf[4][2];
        #pragma unroll
        for (int dt = 0; dt < 4; ++dt)
            #pragma unroll
            for (int ks = 0; ks < 2; ++ks)
                vf[dt][ks] = *(const bfrag*)&Vb[(size_t)(dt * 16 + ln16) * TSEQ + kt * 64 + ks * 32 + hi16 * 8];

        f32x4 sf[2][4] = {};
        qk16(qf, kf, sf);

        if (kt + 1 < kte) {
            #pragma unroll
            for (int jt = 0; jt < 4; ++jt)
                #pragma unroll
                for (int ks = 0; ks < 2; ++ks)
                    kf[jt][ks] = *(const bfrag*)&Kb[(size_t)((kt + 1) * 64 + jt * 16 + ln16) * HD + ks * 32 + hi16 * 8];
        }

        softmax_pv(sf, vf, acc, mrow, lrow, Ps, tok0, kt, kt == NTfull - 1, ln16, hi16);
    }

    float lsum[2][4];
    #pragma unroll
    for (int rf = 0; rf < 2; ++rf)
        #pragma unroll
        for (int e = 0; e < 4; ++e) {
            float l = lrow[rf][e];
            l += __shfl_xor(l, 1);
            l += __shfl_xor(l, 2);
            l += __shfl_xor(l, 4);
            l += __shfl_xor(l, 8);
            lsum[rf][e] = l;
        }

    if (!heavy) {
        #pragma unroll
        for (int rf = 0; rf < 2; ++rf)
            #pragma unroll
            for (int e = 0; e < 4; ++e) {
                const float inv = 1.0f / lsum[rf][e];
                const size_t row = qrow0 + tok0 + rf * 16 + hi16 * 4 + e;
                #pragma unroll
                for (int dt = 0; dt < 4; ++dt)
                    att[row * C_DIM + h * HD + dt * 16 + ln16] = f2bf(acc[rf][dt][e] * inv);
            }
    } else {
        const int sidx = bh * 32 + (qw - 32);     // 0..767
        const size_t pb = (size_t)sidx * 2 + ck;
        #pragma unroll
        for (int rf = 0; rf < 2; ++rf)
            #pragma unroll
            for (int dt = 0; dt < 4; ++dt)
                #pragma unroll
                for (int e = 0; e < 4; ++e) {
                    const int row = rf * 16 + hi16 * 4 + e;
                    pacc[(pb * 32 + row) * 64 + dt * 16 + ln16] = f2bf(acc[rf][dt][e]);
                }
        if (ln16 == 0) {
            #pragma unroll
            for (int rf = 0; rf < 2; ++rf)
                #pragma unroll
                for (int e = 0; e < 4; ++e) {
                    const int row = rf * 16 + hi16 * 4 + e;
                    pml[pb * 64 + row * 2 + 0] = mrow[rf][e];
                    pml[pb * 64 + row * 2 + 1] = lsum[rf][e];
                }
        }
    }
}

// ---------------------------------------------------------------------------
// Combine the 2 chunks of each heavy strip. 768 blocks x 256 thr.
// ---------------------------------------------------------------------------
__global__ __launch_bounds__(256)
void attn_combine(const unsigned short* __restrict__ pacc,
                  const float* __restrict__ pml,
                  unsigned short* __restrict__ att)
{
    const int sidx = blockIdx.x;           // 0..767
    const int bh = sidx >> 5;
    const int qw = 32 + (sidx & 31);
    const int b = bh / HEADS, h = bh % HEADS;
    const int tid = threadIdx.x;
    const int row = tid >> 3;              // 0..31
    const int d0  = (tid & 7) * 8;

    const float m0 = pml[((size_t)sidx * 2 + 0) * 64 + row * 2 + 0];
    const float l0 = pml[((size_t)sidx * 2 + 0) * 64 + row * 2 + 1];
    const float m1 = pml[((size_t)sidx * 2 + 1) * 64 + row * 2 + 0];
    const float l1 = pml[((size_t)sidx * 2 + 1) * 64 + row * 2 + 1];
    const float M  = fmaxf(m0, m1);
    const float w0 = exp2f(m0 - M), w1 = exp2f(m1 - M);
    const float invL = 1.0f / (l0 * w0 + l1 * w1);

    ushort8_t a0 = *(const ushort8_t*)&pacc[(((size_t)sidx * 2 + 0) * 32 + row) * 64 + d0];
    ushort8_t a1 = *(const ushort8_t*)&pacc[(((size_t)sidx * 2 + 1) * 32 + row) * 64 + d0];
    ushort8_t rv;
    #pragma unroll
    for (int k = 0; k < 8; ++k) {
        const float v0 = bf2f(a0[k]);
        const float v1 = bf2f(a1[k]);
        rv[k] = f2bf((v0 * w0 + v1 * w1) * invL);
    }
    const size_t grow = (size_t)b * TSEQ + qw * 32 + row;
    *(ushort8_t*)&att[grow * C_DIM + h * HD + d0] = rv;
}

// ---------------------------------------------------------------------------
// Fused residual add + LayerNorm, vectorized (f32x2 / packed-u32 paths).
// ABF16: residual input A is bf16. WF32: write f32 out. WBF: write bf16 out.
// ---------------------------------------------------------------------------
template<int ABF16, int WF32, int WBF>
__global__ __launch_bounds__(256)
void ln_residual_kernel(const void* __restrict__ Av, const float* __restrict__ R,
                        const float* __restrict__ gamma, const float* __restrict__ beta,
                        float* __restrict__ out, unsigned short* __restrict__ outb, int Mrows)
{
    const int lane = threadIdx.x & 63;
    const int wv   = threadIdx.x >> 6;
    const int row  = blockIdx.x * 4 + wv;
    if (row >= Mrows) return;
    const size_t off = (size_t)row * C_DIM;

    float v[6];
    float sum = 0.0f;
    #pragma unroll
    for (int j = 0; j < 3; ++j) {
        const int c = lane * 2 + 128 * j;
        float a0, a1;
        if (ABF16) {
            const unsigned int u = *(const unsigned int*)&((const unsigned short*)Av)[off + c];
            a0 = bf2f((unsigned short)(u & 0xffff));
            a1 = bf2f((unsigned short)(u >> 16));
        } else {
            f32x2 a = *(const f32x2*)&((const float*)Av)[off + c];
            a0 = a.x; a1 = a.y;
        }
        f32x2 r = *(const f32x2*)&R[off + c];
        v[2 * j]     = a0 + r.x;
        v[2 * j + 1] = a1 + r.y;
        sum += v[2 * j] + v[2 * j + 1];
    }
    #pragma unroll
    for (int o = 1; o < 64; o <<= 1) sum += __shfl_xor(sum, o);
    const float mu = sum * (1.0f / C_DIM);

    float sq = 0.0f;
    #pragma unroll
    for (int j = 0; j < 6; ++j) { const float d = v[j] - mu; sq = fmaf(d, d, sq); }
    #pragma unroll
    for (int o = 1; o < 64; o <<= 1) sq += __shfl_xor(sq, o);
    const float rstd = rsqrtf(sq * (1.0f / C_DIM) + LN_EPS);

    #pragma unroll
    for (int j = 0; j < 3; ++j) {
        const int c = lane * 2 + 128 * j;
        f32x2 g  = *(const f32x2*)&gamma[c];
        f32x2 be = *(const f32x2*)&beta[c];
        const float r0 = (v[2 * j]     - mu) * rstd * g.x + be.x;
        const float r1 = (v[2 * j + 1] - mu) * rstd * g.y + be.y;
        if (WF32) { f32x2 o = { r0, r1 }; *(f32x2*)&out[off + c] = o; }
        if (WBF) {
            const unsigned int o = (unsigned int)f2bf(r0) | ((unsigned int)f2bf(r1) << 16);
            *(unsigned int*)&outb[off + c] = o;
        }
    }
}

// ---------------------------------------------------------------------------
extern "C" void kernel_launch(void* const* d_in, const int* in_sizes, int n_in,
                              void* d_out, int out_size, void* d_ws, size_t ws_size,
                              hipStream_t stream)
{
    const float* x   = (const float*)d_in[0];
    const float* Wq  = (const float*)d_in[1];
    const float* Wk  = (const float*)d_in[2];
    const float* Wv  = (const float*)d_in[3];
    const float* Wo  = (const float*)d_in[4];
    const float* bo  = (const float*)d_in[5];
    const float* W1  = (const float*)d_in[6];
    const float* b1  = (const float*)d_in[7];
    const float* W2  = (const float*)d_in[8];
    const float* b2  = (const float*)d_in[9];
    const float* g1  = (const float*)d_in[10];
    const float* be1 = (const float*)d_in[11];
    const float* g2  = (const float*)d_in[12];
    const float* be2 = (const float*)d_in[13];
    float* out = (float*)d_out;

    const int M = BATCH * TSEQ;                  // 8192
    const size_t MC = (size_t)M * C_DIM;

    // ---- workspace layout (bytes) ----
    char* ws = (char*)d_ws;
    unsigned short* qkv = (unsigned short*)ws;                       // M*1152*2 = 18.87 MB
    unsigned short* vt  = (unsigned short*)(ws + (size_t)M*1152*2);  // 6.29 MB
    unsigned short* att = (unsigned short*)(ws + (size_t)M*1152*2 + (size_t)BATCH*HEADS*HD*TSEQ*2); // 6.29 MB
    unsigned short* h1  = (unsigned short*)ws;                       // M*1536*2, aliases qkv+vt
    char* p2 = ws + (size_t)M*1152*2 + (size_t)BATCH*HEADS*HD*TSEQ*2 + MC*2;   // 31.46 MB mark
    unsigned short* xb  = (unsigned short*)p2;                       // MC bf16 (QKV gemm input)
    float* y   = (float*)(p2 + MC*2);                                // MC f32
    unsigned short* ktc = (unsigned short*)(p2 + MC*2 + MC*4);       // 6.29 MB
    unsigned short* x1b = (unsigned short*)(p2 + MC*2 + 2*MC*4);     // MC bf16
    char* p3 = p2 + MC*2 + 2*MC*4 + MC*2;
    unsigned short* Wqkv_t = (unsigned short*)p3;                        // [1152][384]
    unsigned short* Wo_t   = Wqkv_t + (size_t)3*C_DIM*C_DIM;             // [384][384]
    unsigned short* W1_t   = Wo_t   + (size_t)C_DIM*C_DIM;               // [1536][384]
    unsigned short* W2_t   = W1_t   + (size_t)FF_DIM*C_DIM;              // [384][1536]

    // split-K partials in y region (dead during attn):
    unsigned short* pacc = (unsigned short*)(p2 + MC*2);
    float* pml = (float*)(p2 + MC*2 + (size_t)1536*32*64*2);

    dim3 b256(256), b328(32, 8);

    // ---- all weight transposes + x->bf16 in ONE launch ----
    prep_all<<<dim3(1728 + 3072), b328, 0, stream>>>(
        Wq, Wk, Wv, Wo, W1, W2, x, Wqkv_t, Wo_t, W1_t, W2_t, xb);

    // ---- qkv = xb @ Wqkv (Q pre-scaled; K written straight to ktc) ----
    gemm_lds<1, 0, 0, 1, 1><<<dim3(3*C_DIM/128, M/128), b256, 0, stream>>>(
        xb, Wqkv_t, nullptr, qkv, ktc, M, 3*C_DIM, C_DIM);

    // ---- V transpose ----
    vtrans_kernel<<<dim3(TSEQ/32, HD/32, BATCH*HEADS), b328, 0, stream>>>(qkv, vt);

    // ---- attention: 2304 waves (heavy strips split in 2), then combine ----
    attn_kernel<<<dim3(2304), dim3(64), 0, stream>>>(qkv, ktc, vt, att, pacc, pml);
    attn_combine<<<dim3(768), b256, 0, stream>>>(pacc, pml, att);

    // ---- y = att @ Wo + bo  (BM=64: 384 blocks) ----
    gemm_lds64<0, 1, 0><<<dim3(C_DIM/128, M/64), b256, 0, stream>>>(
        att, Wo_t, bo, y, M, C_DIM, C_DIM);

    // ---- x1b = LN(x + y)  (bf16 only) ----
    ln_residual_kernel<0, 0, 1><<<dim3(M/4), b256, 0, stream>>>(
        x, y, g1, be1, nullptr, x1b, M);

    // ---- h1 = relu(x1b @ W1 + b1) ----
    gemm_lds<1, 1, 1, 0, 0><<<dim3(FF_DIM/128, M/128), b256, 0, stream>>>(
        x1b, W1_t, b1, h1, nullptr, M, FF_DIM, C_DIM);

    // ---- y = h1 @ W2 + b2  (BM=64: 384 blocks, K=1536) ----
    gemm_lds64<0, 1, 0><<<dim3(C_DIM/128, M/64), b256, 0, stream>>>(
        h1, W2_t, b2, y, M, C_DIM, FF_DIM);

    // ---- out = LN(x1b + y) ----
    ln_residual_kernel<1, 1, 0><<<dim3(M/4), b256, 0, stream>>>(
        x1b, y, g2, be2, out, nullptr, M);
}

// Round 18
// 191.721 us; speedup vs baseline: 1.1648x; 1.0055x over previous
//
#include <hip/hip_runtime.h>

#define C_DIM  384
#define HEADS  6
#define HD     64
#define FF_DIM 1536
#define LN_EPS 1e-3f
#define TSEQ   2048
#define BATCH  4
#define LOG2E  1.4426950408889634f
#define QK_SCALE 0.18033688011112042f   // 0.125 * log2(e), folded into Q

typedef __attribute__((ext_vector_type(2))) float          f32x2;
typedef __attribute__((ext_vector_type(4))) float          f32x4;
typedef __attribute__((ext_vector_type(4))) float          float4_t;
typedef __attribute__((ext_vector_type(8))) short          bfrag;     // 8 bf16
typedef __attribute__((ext_vector_type(4))) unsigned short ushort4_t;
typedef __attribute__((ext_vector_type(8))) unsigned short ushort8_t;

__device__ inline unsigned short f2bf(float f) {
    unsigned int u = __builtin_bit_cast(unsigned int, f);
    u += 0x7fff + ((u >> 16) & 1);          // RNE
    return (unsigned short)(u >> 16);
}
// truncating convert — P matrix only (values in [0,1], re-normalized)
__device__ inline unsigned short f2bf_t(float f) {
    return (unsigned short)(__builtin_bit_cast(unsigned int, f) >> 16);
}
__device__ inline float bf2f(unsigned short u) {
    return __builtin_bit_cast(float, (unsigned int)u << 16);
}

// async global->LDS, 16 B per lane. LDS dest is wave-uniform base + lane*16.
__device__ inline void gload_lds16(const void* g, void* l) {
    __builtin_amdgcn_global_load_lds(
        (const __attribute__((address_space(1))) unsigned int*)g,
        (__attribute__((address_space(3))) unsigned int*)l,
        16, 0, 0);
}

// chunked XCD swizzle: HW maps flat blockIdx round-robin (bid&7 = XCD, r10).
// Remap so each XCD owns a CONTIGUOUS logical range (A-panel L2 locality).
// Requires nwg % 8 == 0 (true for all GEMM grids here).
__device__ inline int xcd_chunk(int flat, int nwg) {
    return (flat >> 3) + (flat & 7) * (nwg >> 3);
}

// ---------------------------------------------------------------------------
// Fused: all weight transposes (W[K][N] f32 -> Wt[N][K] bf16) + x -> bf16.
// Blocks 0..575: four 384x384; 576..1151: W1; 1152..1727: W2;
// 1728..4799: cvt x (3072 blocks x 256 float4 = exact). block (32,8).
// ---------------------------------------------------------------------------
__global__ __launch_bounds__(256)
void prep_all(const float* __restrict__ Wq, const float* __restrict__ Wk,
              const float* __restrict__ Wv, const float* __restrict__ Wo,
              const float* __restrict__ W1, const float* __restrict__ W2,
              const float* __restrict__ x,
              unsigned short* __restrict__ Dqkv, unsigned short* __restrict__ Do_,
              unsigned short* __restrict__ D1, unsigned short* __restrict__ D2,
              unsigned short* __restrict__ xb)
{
    __shared__ float tile[32][33];
    const int bidx = blockIdx.x;
    const int tx = threadIdx.x, ty = threadIdx.y;
    if (bidx >= 1728) {
        const int i = (bidx - 1728) * 256 + ty * 32 + tx;
        float4_t v = ((const float4_t*)x)[i];
        ushort4_t o = { f2bf(v.x), f2bf(v.y), f2bf(v.z), f2bf(v.w) };
        ((ushort4_t*)xb)[i] = o;
        return;
    }
    const float* W; unsigned short* D;
    int K, N, nx, ny;
    if (bidx < 576) {
        const int z = bidx / 144, r = bidx % 144;
        W = z == 0 ? Wq : (z == 1 ? Wk : (z == 2 ? Wv : Wo));
        D = z == 3 ? Do_ : Dqkv + (size_t)z * C_DIM * C_DIM;
        K = N = C_DIM; nx = r % 12; ny = r / 12;
    } else if (bidx < 1152) {
        const int r = bidx - 576;
        W = W1; D = D1; K = C_DIM; N = FF_DIM; nx = r % 48; ny = r / 48;
    } else {
        const int r = bidx - 1152;
        W = W2; D = D2; K = FF_DIM; N = C_DIM; nx = r % 12; ny = r / 12;
    }
    const int n0 = nx * 32, k0 = ny * 32;
    #pragma unroll
    for (int i = 0; i < 32; i += 8)
        tile[ty + i][tx] = W[(size_t)(k0 + ty + i) * N + n0 + tx];
    __syncthreads();
    #pragma unroll
    for (int i = 0; i < 32; i += 8)
        D[(size_t)(n0 + ty + i) * K + k0 + tx] = f2bf(tile[tx][ty + i]);
}

// ---------------------------------------------------------------------------
// V transpose only: qkv v-cols -> vt[bh][d][t] bf16.
// ---------------------------------------------------------------------------
__global__ __launch_bounds__(256)
void vtrans_kernel(const unsigned short* __restrict__ qkv,
                   unsigned short* __restrict__ vt)
{
    __shared__ unsigned short tile[32][34];
    const int tx = threadIdx.x, ty = threadIdx.y;
    const int bh = blockIdx.z, b = bh / HEADS, h = bh % HEADS;
    const int t0 = blockIdx.x * 32, d0 = blockIdx.y * 32;
    #pragma unroll
    for (int i = 0; i < 32; i += 8)
        tile[ty + i][tx] = qkv[(size_t)(b * TSEQ + t0 + ty + i) * 1152 + 2 * C_DIM + h * HD + d0 + tx];
    __syncthreads();
    #pragma unroll
    for (int i = 0; i < 32; i += 8)
        vt[((size_t)bh * HD + d0 + ty + i) * TSEQ + t0 + tx] = tile[tx][ty + i];
}

// ---------------------------------------------------------------------------
// LDS-staged bf16 MFMA GEMM, BM=128 x BN=128 (m97 structure), fragment-major
// gload_lds staging. QSCALE: scale output cols < C_DIM by QK_SCALE.
// KSPLIT: cols [C_DIM, 2*C_DIM) written to ktc[bh][t][d] (fused K-repack).
// Chunked XCD swizzle on the flat block id (T1).
// ---------------------------------------------------------------------------
template<int OBF16, int BIAS, int RELU, int QSCALE, int KSPLIT>
__global__ __launch_bounds__(256)
void gemm_lds(const unsigned short* __restrict__ A, const unsigned short* __restrict__ Bt,
              const float* __restrict__ bias, void* __restrict__ Cv,
              unsigned short* __restrict__ ktc,
              int M, int N, int K)
{
    __shared__ __align__(16) unsigned short As[16 * 512];   // 16 frags x 1KB
    __shared__ __align__(16) unsigned short Bs[16 * 512];

    const int t = threadIdx.x, lane = t & 63, w = t >> 6;
    const int ln16 = lane & 15, hi16 = lane >> 4;
    const int wr = w >> 1, wc = w & 1;
    const int nwg = gridDim.x * gridDim.y;
    const int L = xcd_chunk(blockIdx.y * gridDim.x + blockIdx.x, nwg);
    const int row0 = (L / gridDim.x) * 128, col0 = (L % gridDim.x) * 128;

    f32x4 acc[4][4] = {};

    for (int k0 = 0; k0 < K; k0 += 64) {
        #pragma unroll
        for (int i = 0; i < 4; ++i) {
            const int f  = w * 4 + i;
            const int ks = f >> 3, rf = f & 7;
            const int row = rf * 16 + ln16;
            const int kc  = k0 + ks * 32 + hi16 * 8;
            gload_lds16(&A [(size_t)(row0 + row) * K + kc], &As[f * 512]);
            gload_lds16(&Bt[(size_t)(col0 + row) * K + kc], &Bs[f * 512]);
        }
        __syncthreads();
        #pragma unroll
        for (int ks = 0; ks < 2; ++ks) {
            bfrag a[4], b[4];
            #pragma unroll
            for (int i = 0; i < 4; ++i)
                a[i] = *(const bfrag*)&As[(ks * 8 + wr * 4 + i) * 512 + lane * 8];
            #pragma unroll
            for (int j = 0; j < 4; ++j)
                b[j] = *(const bfrag*)&Bs[(ks * 8 + wc * 4 + j) * 512 + lane * 8];
            #pragma unroll
            for (int i = 0; i < 4; ++i)
                #pragma unroll
                for (int j = 0; j < 4; ++j)
                    acc[i][j] = __builtin_amdgcn_mfma_f32_16x16x32_bf16(a[i], b[j], acc[i][j], 0, 0, 0);
        }
        __syncthreads();
    }

    #pragma unroll
    for (int j = 0; j < 4; ++j) {
        const int cbase = col0 + wc * 64 + j * 16;      // 16-aligned, head-uniform
        const int col = cbase + ln16;
        const float bv = BIAS ? bias[col] : 0.0f;
        const float sc = (QSCALE && col < C_DIM) ? QK_SCALE : 1.0f;
        const bool kdest = KSPLIT && (cbase >= C_DIM) && (cbase < 2 * C_DIM);
        #pragma unroll
        for (int i = 0; i < 4; ++i) {
            #pragma unroll
            for (int e = 0; e < 4; ++e) {
                const int row = row0 + wr * 64 + i * 16 + hi16 * 4 + e;
                float v = acc[i][j][e] + bv;
                if (RELU) v = fmaxf(v, 0.0f);
                if (QSCALE) v *= sc;
                if (kdest) {
                    const int b  = row >> 11, tt = row & 2047;
                    const int hd = col - C_DIM;                 // h*64 + d
                    const int bh = b * HEADS + (hd >> 6);
                    ktc[((size_t)bh * TSEQ + tt) * HD + (hd & 63)] = f2bf(v);
                } else if (OBF16) {
                    ((unsigned short*)Cv)[(size_t)row * N + col] = f2bf(v);
                } else {
                    ((float*)Cv)[(size_t)row * N + col] = v;
                }
            }
        }
    }
}

// ---------------------------------------------------------------------------
// LDS-staged bf16 MFMA GEMM, BM=64 x BN=128 — for small-N GEMMs (N=384).
// DOUBLE-BUFFERED LDS (T3-minimum 2-phase): stage(k+1) issued right after the
// barrier, before compute(k); one __syncthreads per K-step drains staging
// vmcnt and guards buffer reuse. 48 KB LDS -> 3 blocks/CU (>= 1.5 launched,
// no occupancy loss; m132 hazard doesn't apply). Chunked XCD swizzle (T1).
// ---------------------------------------------------------------------------
template<int OBF16, int BIAS, int RELU>
__global__ __launch_bounds__(256)
void gemm_lds64(const unsigned short* __restrict__ A, const unsigned short* __restrict__ Bt,
                const float* __restrict__ bias, void* __restrict__ Cv,
                int M, int N, int K)
{
    __shared__ __align__(16) unsigned short As[2][8 * 512];    // 2 x 8 frags
    __shared__ __align__(16) unsigned short Bs[2][16 * 512];   // 2 x 16 frags

    const int t = threadIdx.x, lane = t & 63, w = t >> 6;
    const int ln16 = lane & 15, hi16 = lane >> 4;
    const int wr = w >> 1, wc = w & 1;
    const int nwg = gridDim.x * gridDim.y;
    const int L = xcd_chunk(blockIdx.y * gridDim.x + blockIdx.x, nwg);
    const int row0 = (L / gridDim.x) * 64, col0 = (L % gridDim.x) * 128;

    f32x4 acc[2][4] = {};

    auto stage = [&](int bf, int k0) {
        #pragma unroll
        for (int i = 0; i < 2; ++i) {
            const int f  = w * 2 + i;
            const int ks = f >> 2, rf = f & 3;
            gload_lds16(&A[(size_t)(row0 + rf * 16 + ln16) * K + k0 + ks * 32 + hi16 * 8],
                        &As[bf][f * 512]);
        }
        #pragma unroll
        for (int i = 0; i < 4; ++i) {
            const int f  = w * 4 + i;
            const int ks = f >> 3, cf = f & 7;
            gload_lds16(&Bt[(size_t)(col0 + cf * 16 + ln16) * K + k0 + ks * 32 + hi16 * 8],
                        &Bs[bf][f * 512]);
        }
    };

    int buf = 0;
    stage(0, 0);
    __syncthreads();                       // buf0 staged

    for (int k0 = 0; k0 < K; k0 += 64) {
        if (k0 + 64 < K) stage(buf ^ 1, k0 + 64);   // async, in flight over compute
        #pragma unroll
        for (int ks = 0; ks < 2; ++ks) {
            bfrag a[2], b[4];
            #pragma unroll
            for (int i = 0; i < 2; ++i)
                a[i] = *(const bfrag*)&As[buf][(ks * 4 + wr * 2 + i) * 512 + lane * 8];
            #pragma unroll
            for (int j = 0; j < 4; ++j)
                b[j] = *(const bfrag*)&Bs[buf][(ks * 8 + wc * 4 + j) * 512 + lane * 8];
            #pragma unroll
            for (int i = 0; i < 2; ++i)
                #pragma unroll
                for (int j = 0; j < 4; ++j)
                    acc[i][j] = __builtin_amdgcn_mfma_f32_16x16x32_bf16(a[i], b[j], acc[i][j], 0, 0, 0);
        }
        __syncthreads();                   // drains staging vmcnt + guards reuse
        buf ^= 1;
    }

    #pragma unroll
    for (int j = 0; j < 4; ++j) {
        const int col = col0 + wc * 64 + j * 16 + ln16;
        const float bv = BIAS ? bias[col] : 0.0f;
        #pragma unroll
        for (int i = 0; i < 2; ++i) {
            #pragma unroll
            for (int e = 0; e < 4; ++e) {
                const int row = row0 + wr * 32 + i * 16 + hi16 * 4 + e;
                float v = acc[i][j][e] + bv;
                if (RELU) v = fmaxf(v, 0.0f);
                if (OBF16) ((unsigned short*)Cv)[(size_t)row * N + col] = f2bf(v);
                else       ((float*)Cv)[(size_t)row * N + col] = v;
            }
        }
    }
}

// ---------------------------------------------------------------------------
// attention helpers (s_setprio(1) around MFMA clusters — T5)
// ---------------------------------------------------------------------------
__device__ inline void qk16(const bfrag (&qf)[2][2], const bfrag (&kf)[4][2],
                            f32x4 (&sf)[2][4])
{
    __builtin_amdgcn_s_setprio(1);
    #pragma unroll
    for (int jt = 0; jt < 4; ++jt)
        #pragma unroll
        for (int ks = 0; ks < 2; ++ks) {
            sf[0][jt] = __builtin_amdgcn_mfma_f32_16x16x32_bf16(qf[0][ks], kf[jt][ks], sf[0][jt], 0, 0, 0);
            sf[1][jt] = __builtin_amdgcn_mfma_f32_16x16x32_bf16(qf[1][ks], kf[jt][ks], sf[1][jt], 0, 0, 0);
        }
    __builtin_amdgcn_s_setprio(0);
}

// softmax + PV. Mask applied on the fly.
__device__ inline void softmax_pv(f32x4 (&sf)[2][4], const bfrag (&vf)[4][2],
                                  f32x4 (&acc)[2][4],
                                  float (&mrow)[2][4], float (&lrow)[2][4],
                                  unsigned short (*Ps)[72],
                                  int tok0, int kt, bool last, int ln16, int hi16)
{
    float lmax[2][4];
    bool need = false;
    #pragma unroll
    for (int rf = 0; rf < 2; ++rf)
        #pragma unroll
        for (int e = 0; e < 4; ++e) {
            const int row = tok0 + rf * 16 + hi16 * 4 + e;
            float mx = -1e30f;
            #pragma unroll
            for (int jt = 0; jt < 4; ++jt) {
                float sv = sf[rf][jt][e];
                if (last && (kt * 64 + jt * 16 + ln16 > row)) sv = -1e30f;
                mx = fmaxf(mx, sv);
            }
            lmax[rf][e] = mx;
            need = need || (mx > mrow[rf][e] + 8.0f);
        }
    if (__any(need)) {
        #pragma unroll
        for (int rf = 0; rf < 2; ++rf)
            #pragma unroll
            for (int e = 0; e < 4; ++e) {
                float rm = lmax[rf][e];
                rm = fmaxf(rm, __shfl_xor(rm, 1));
                rm = fmaxf(rm, __shfl_xor(rm, 2));
                rm = fmaxf(rm, __shfl_xor(rm, 4));
                rm = fmaxf(rm, __shfl_xor(rm, 8));
                const float mn = fmaxf(mrow[rf][e], rm);
                const float corr = exp2f(mrow[rf][e] - mn);
                mrow[rf][e] = mn;
                lrow[rf][e] *= corr;
                #pragma unroll
                for (int dt = 0; dt < 4; ++dt) acc[rf][dt][e] *= corr;
            }
    }

    #pragma unroll
    for (int rf = 0; rf < 2; ++rf)
        #pragma unroll
        for (int jt = 0; jt < 4; ++jt)
            #pragma unroll
            for (int e = 0; e < 4; ++e) {
                const int row = tok0 + rf * 16 + hi16 * 4 + e;
                float sv = sf[rf][jt][e];
                if (last && (kt * 64 + jt * 16 + ln16 > row)) sv = -1e30f;
                const float pe = exp2f(sv - mrow[rf][e]);
                lrow[rf][e] += pe;
                Ps[rf * 16 + hi16 * 4 + e][jt * 16 + ln16] = f2bf_t(pe);
            }

    bfrag pf[2][2];
    #pragma unroll
    for (int rf = 0; rf < 2; ++rf)
        #pragma unroll
        for (int ks = 0; ks < 2; ++ks)
            pf[rf][ks] = *(const bfrag*)&Ps[rf * 16 + ln16][ks * 32 + hi16 * 8];
    __builtin_amdgcn_s_setprio(1);
    #pragma unroll
    for (int ks = 0; ks < 2; ++ks)
        #pragma unroll
        for (int rf = 0; rf < 2; ++rf)
            #pragma unroll
            for (int dt = 0; dt < 4; ++dt)
                acc[rf][dt] = __builtin_amdgcn_mfma_f32_16x16x32_bf16(pf[rf][ks], vf[dt][ks], acc[rf][dt], 0, 0, 0);
    __builtin_amdgcn_s_setprio(0);
}

// ---------------------------------------------------------------------------
// Split-K flash attention (moderate split, r15 structure — at its
// concurrency-throughput floor).
// ---------------------------------------------------------------------------
__global__ __launch_bounds__(64)
void attn_kernel(const unsigned short* __restrict__ qkv,
                 const unsigned short* __restrict__ ktc,
                 const unsigned short* __restrict__ vt,
                 unsigned short* __restrict__ att,
                 unsigned short* __restrict__ pacc,
                 float* __restrict__ pml)
{
    __shared__ __align__(16) unsigned short Ps[32][72];
    const int lane = threadIdx.x;
    const int ln16 = lane & 15, hi16 = lane >> 4;
    const int bid = blockIdx.x;            // 0..2303
    const int xcd = bid & 7;
    const int i   = bid >> 3;              // 0..287
    int bh, qw, kt0, kte, ck = 0;
    bool heavy;
    if (i < 192) {                         // heavy chunk waves, qw descending
        qw = 63 - (i / 6);                 // 63..32
        const int r = i % 6;
        bh = xcd * 3 + (r >> 1);
        ck = r & 1;
        const int NT = (qw >> 1) + 1;      // 17..32
        const int half = NT >> 1;          // 8..16
        kt0 = ck ? half : 0;
        kte = ck ? NT : half;
        heavy = true;
    } else {                               // light strips
        const int j = i - 192;             // 0..95
        qw = 31 - (j / 3);                 // 31..0
        bh = xcd * 3 + (j % 3);
        kt0 = 0;
        kte = (qw >> 1) + 1;               // <= 16
        heavy = false;
    }
    const int NTfull = (qw >> 1) + 1;
    const int b = bh / HEADS, h = bh % HEADS;
    const int tok0 = qw * 32;
    const size_t qrow0 = (size_t)b * TSEQ;

    bfrag qf[2][2];
    #pragma unroll
    for (int rf = 0; rf < 2; ++rf)
        #pragma unroll
        for (int ks = 0; ks < 2; ++ks)
            qf[rf][ks] = *(const bfrag*)&qkv[(qrow0 + tok0 + rf * 16 + ln16) * 1152 + h * HD + ks * 32 + hi16 * 8];

    f32x4 acc[2][4] = {};
    float mrow[2][4], lrow[2][4];
    #pragma unroll
    for (int rf = 0; rf < 2; ++rf)
        #pragma unroll
        for (int e = 0; e < 4; ++e) { mrow[rf][e] = -1e30f; lrow[rf][e] = 0.0f; }

    const unsigned short* Kb = ktc + (size_t)bh * TSEQ * HD;
    const unsigned short* Vb = vt  + (size_t)bh * HD * TSEQ;

    bfrag kf[4][2];
    #pragma unroll
    for (int jt = 0; jt < 4; ++jt)
        #pragma unroll
        for (int ks = 0; ks < 2; ++ks)
            kf[jt][ks] = *(const bfrag*)&Kb[(size_t)(kt0 * 64 + jt * 16 + ln16) * HD + ks * 32 + hi16 * 8];

    for (int kt = kt0; kt < kte; ++kt) {
        bfrag vf[4][2];
        #pragma unroll
        for (int dt = 0; dt < 4; ++dt)
            #pragma unroll
            for (int ks = 0; ks < 2; ++ks)
                vf[dt][ks] = *(const bfrag*)&Vb[(size_t)(dt * 16 + ln16) * TSEQ + kt * 64 + ks * 32 + hi16 * 8];

        f32x4 sf[2][4] = {};
        qk16(qf, kf, sf);

        if (kt + 1 < kte) {
            #pragma unroll
            for (int jt = 0; jt < 4; ++jt)
                #pragma unroll
                for (int ks = 0; ks < 2; ++ks)
                    kf[jt][ks] = *(const bfrag*)&Kb[(size_t)((kt + 1) * 64 + jt * 16 + ln16) * HD + ks * 32 + hi16 * 8];
        }

        softmax_pv(sf, vf, acc, mrow, lrow, Ps, tok0, kt, kt == NTfull - 1, ln16, hi16);
    }

    float lsum[2][4];
    #pragma unroll
    for (int rf = 0; rf < 2; ++rf)
        #pragma unroll
        for (int e = 0; e < 4; ++e) {
            float l = lrow[rf][e];
            l += __shfl_xor(l, 1);
            l += __shfl_xor(l, 2);
            l += __shfl_xor(l, 4);
            l += __shfl_xor(l, 8);
            lsum[rf][e] = l;
        }

    if (!heavy) {
        #pragma unroll
        for (int rf = 0; rf < 2; ++rf)
            #pragma unroll
            for (int e = 0; e < 4; ++e) {
                const float inv = 1.0f / lsum[rf][e];
                const size_t row = qrow0 + tok0 + rf * 16 + hi16 * 4 + e;
                #pragma unroll
                for (int dt = 0; dt < 4; ++dt)
                    att[row * C_DIM + h * HD + dt * 16 + ln16] = f2bf(acc[rf][dt][e] * inv);
            }
    } else {
        const int sidx = bh * 32 + (qw - 32);     // 0..767
        const size_t pb = (size_t)sidx * 2 + ck;
        #pragma unroll
        for (int rf = 0; rf < 2; ++rf)
            #pragma unroll
            for (int dt = 0; dt < 4; ++dt)
                #pragma unroll
                for (int e = 0; e < 4; ++e) {
                    const int row = rf * 16 + hi16 * 4 + e;
                    pacc[(pb * 32 + row) * 64 + dt * 16 + ln16] = f2bf(acc[rf][dt][e]);
                }
        if (ln16 == 0) {
            #pragma unroll
            for (int rf = 0; rf < 2; ++rf)
                #pragma unroll
                for (int e = 0; e < 4; ++e) {
                    const int row = rf * 16 + hi16 * 4 + e;
                    pml[pb * 64 + row * 2 + 0] = mrow[rf][e];
                    pml[pb * 64 + row * 2 + 1] = lsum[rf][e];
                }
        }
    }
}

// ---------------------------------------------------------------------------
// Combine the 2 chunks of each heavy strip. 768 blocks x 256 thr.
// ---------------------------------------------------------------------------
__global__ __launch_bounds__(256)
void attn_combine(const unsigned short* __restrict__ pacc,
                  const float* __restrict__ pml,
                  unsigned short* __restrict__ att)
{
    const int sidx = blockIdx.x;           // 0..767
    const int bh = sidx >> 5;
    const int qw = 32 + (sidx & 31);
    const int b = bh / HEADS, h = bh % HEADS;
    const int tid = threadIdx.x;
    const int row = tid >> 3;              // 0..31
    const int d0  = (tid & 7) * 8;

    const float m0 = pml[((size_t)sidx * 2 + 0) * 64 + row * 2 + 0];
    const float l0 = pml[((size_t)sidx * 2 + 0) * 64 + row * 2 + 1];
    const float m1 = pml[((size_t)sidx * 2 + 1) * 64 + row * 2 + 0];
    const float l1 = pml[((size_t)sidx * 2 + 1) * 64 + row * 2 + 1];
    const float M  = fmaxf(m0, m1);
    const float w0 = exp2f(m0 - M), w1 = exp2f(m1 - M);
    const float invL = 1.0f / (l0 * w0 + l1 * w1);

    ushort8_t a0 = *(const ushort8_t*)&pacc[(((size_t)sidx * 2 + 0) * 32 + row) * 64 + d0];
    ushort8_t a1 = *(const ushort8_t*)&pacc[(((size_t)sidx * 2 + 1) * 32 + row) * 64 + d0];
    ushort8_t rv;
    #pragma unroll
    for (int k = 0; k < 8; ++k) {
        const float v0 = bf2f(a0[k]);
        const float v1 = bf2f(a1[k]);
        rv[k] = f2bf((v0 * w0 + v1 * w1) * invL);
    }
    const size_t grow = (size_t)b * TSEQ + qw * 32 + row;
    *(ushort8_t*)&att[grow * C_DIM + h * HD + d0] = rv;
}

// ---------------------------------------------------------------------------
// Fused residual add + LayerNorm, vectorized (f32x2 / packed-u32 paths).
// ABF16: residual input A is bf16. WF32: write f32 out. WBF: write bf16 out.
// ---------------------------------------------------------------------------
template<int ABF16, int WF32, int WBF>
__global__ __launch_bounds__(256)
void ln_residual_kernel(const void* __restrict__ Av, const float* __restrict__ R,
                        const float* __restrict__ gamma, const float* __restrict__ beta,
                        float* __restrict__ out, unsigned short* __restrict__ outb, int Mrows)
{
    const int lane = threadIdx.x & 63;
    const int wv   = threadIdx.x >> 6;
    const int row  = blockIdx.x * 4 + wv;
    if (row >= Mrows) return;
    const size_t off = (size_t)row * C_DIM;

    float v[6];
    float sum = 0.0f;
    #pragma unroll
    for (int j = 0; j < 3; ++j) {
        const int c = lane * 2 + 128 * j;
        float a0, a1;
        if (ABF16) {
            const unsigned int u = *(const unsigned int*)&((const unsigned short*)Av)[off + c];
            a0 = bf2f((unsigned short)(u & 0xffff));
            a1 = bf2f((unsigned short)(u >> 16));
        } else {
            f32x2 a = *(const f32x2*)&((const float*)Av)[off + c];
            a0 = a.x; a1 = a.y;
        }
        f32x2 r = *(const f32x2*)&R[off + c];
        v[2 * j]     = a0 + r.x;
        v[2 * j + 1] = a1 + r.y;
        sum += v[2 * j] + v[2 * j + 1];
    }
    #pragma unroll
    for (int o = 1; o < 64; o <<= 1) sum += __shfl_xor(sum, o);
    const float mu = sum * (1.0f / C_DIM);

    float sq = 0.0f;
    #pragma unroll
    for (int j = 0; j < 6; ++j) { const float d = v[j] - mu; sq = fmaf(d, d, sq); }
    #pragma unroll
    for (int o = 1; o < 64; o <<= 1) sq += __shfl_xor(sq, o);
    const float rstd = rsqrtf(sq * (1.0f / C_DIM) + LN_EPS);

    #pragma unroll
    for (int j = 0; j < 3; ++j) {
        const int c = lane * 2 + 128 * j;
        f32x2 g  = *(const f32x2*)&gamma[c];
        f32x2 be = *(const f32x2*)&beta[c];
        const float r0 = (v[2 * j]     - mu) * rstd * g.x + be.x;
        const float r1 = (v[2 * j + 1] - mu) * rstd * g.y + be.y;
        if (WF32) { f32x2 o = { r0, r1 }; *(f32x2*)&out[off + c] = o; }
        if (WBF) {
            const unsigned int o = (unsigned int)f2bf(r0) | ((unsigned int)f2bf(r1) << 16);
            *(unsigned int*)&outb[off + c] = o;
        }
    }
}

// ---------------------------------------------------------------------------
extern "C" void kernel_launch(void* const* d_in, const int* in_sizes, int n_in,
                              void* d_out, int out_size, void* d_ws, size_t ws_size,
                              hipStream_t stream)
{
    const float* x   = (const float*)d_in[0];
    const float* Wq  = (const float*)d_in[1];
    const float* Wk  = (const float*)d_in[2];
    const float* Wv  = (const float*)d_in[3];
    const float* Wo  = (const float*)d_in[4];
    const float* bo  = (const float*)d_in[5];
    const float* W1  = (const float*)d_in[6];
    const float* b1  = (const float*)d_in[7];
    const float* W2  = (const float*)d_in[8];
    const float* b2  = (const float*)d_in[9];
    const float* g1  = (const float*)d_in[10];
    const float* be1 = (const float*)d_in[11];
    const float* g2  = (const float*)d_in[12];
    const float* be2 = (const float*)d_in[13];
    float* out = (float*)d_out;

    const int M = BATCH * TSEQ;                  // 8192
    const size_t MC = (size_t)M * C_DIM;

    // ---- workspace layout (bytes) ----
    char* ws = (char*)d_ws;
    unsigned short* qkv = (unsigned short*)ws;                       // M*1152*2 = 18.87 MB
    unsigned short* vt  = (unsigned short*)(ws + (size_t)M*1152*2);  // 6.29 MB
    unsigned short* att = (unsigned short*)(ws + (size_t)M*1152*2 + (size_t)BATCH*HEADS*HD*TSEQ*2); // 6.29 MB
    unsigned short* h1  = (unsigned short*)ws;                       // M*1536*2, aliases qkv+vt
    char* p2 = ws + (size_t)M*1152*2 + (size_t)BATCH*HEADS*HD*TSEQ*2 + MC*2;   // 31.46 MB mark
    unsigned short* xb  = (unsigned short*)p2;                       // MC bf16 (QKV gemm input)
    float* y   = (float*)(p2 + MC*2);                                // MC f32
    unsigned short* ktc = (unsigned short*)(p2 + MC*2 + MC*4);       // 6.29 MB
    unsigned short* x1b = (unsigned short*)(p2 + MC*2 + 2*MC*4);     // MC bf16
    char* p3 = p2 + MC*2 + 2*MC*4 + MC*2;
    unsigned short* Wqkv_t = (unsigned short*)p3;                        // [1152][384]
    unsigned short* Wo_t   = Wqkv_t + (size_t)3*C_DIM*C_DIM;             // [384][384]
    unsigned short* W1_t   = Wo_t   + (size_t)C_DIM*C_DIM;               // [1536][384]
    unsigned short* W2_t   = W1_t   + (size_t)FF_DIM*C_DIM;              // [384][1536]

    // split-K partials in y region (dead during attn):
    unsigned short* pacc = (unsigned short*)(p2 + MC*2);
    float* pml = (float*)(p2 + MC*2 + (size_t)1536*32*64*2);

    dim3 b256(256), b328(32, 8);

    // ---- all weight transposes + x->bf16 in ONE launch ----
    prep_all<<<dim3(1728 + 3072), b328, 0, stream>>>(
        Wq, Wk, Wv, Wo, W1, W2, x, Wqkv_t, Wo_t, W1_t, W2_t, xb);

    // ---- qkv = xb @ Wqkv (Q pre-scaled; K written straight to ktc) ----
    gemm_lds<1, 0, 0, 1, 1><<<dim3(3*C_DIM/128, M/128), b256, 0, stream>>>(
        xb, Wqkv_t, nullptr, qkv, ktc, M, 3*C_DIM, C_DIM);

    // ---- V transpose ----
    vtrans_kernel<<<dim3(TSEQ/32, HD/32, BATCH*HEADS), b328, 0, stream>>>(qkv, vt);

    // ---- attention: 2304 waves (heavy strips split in 2), then combine ----
    attn_kernel<<<dim3(2304), dim3(64), 0, stream>>>(qkv, ktc, vt, att, pacc, pml);
    attn_combine<<<dim3(768), b256, 0, stream>>>(pacc, pml, att);

    // ---- y = att @ Wo + bo  (BM=64, double-buffered) ----
    gemm_lds64<0, 1, 0><<<dim3(C_DIM/128, M/64), b256, 0, stream>>>(
        att, Wo_t, bo, y, M, C_DIM, C_DIM);

    // ---- x1b = LN(x + y)  (bf16 only) ----
    ln_residual_kernel<0, 0, 1><<<dim3(M/4), b256, 0, stream>>>(
        x, y, g1, be1, nullptr, x1b, M);

    // ---- h1 = relu(x1b @ W1 + b1) ----
    gemm_lds<1, 1, 1, 0, 0><<<dim3(FF_DIM/128, M/128), b256, 0, stream>>>(
        x1b, W1_t, b1, h1, nullptr, M, FF_DIM, C_DIM);

    // ---- y = h1 @ W2 + b2  (BM=64, double-buffered, K=1536) ----
    gemm_lds64<0, 1, 0><<<dim3(C_DIM/128, M/64), b256, 0, stream>>>(
        h1, W2_t, b2, y, M, C_DIM, FF_DIM);

    // ---- out = LN(x1b + y) ----
    ln_residual_kernel<1, 1, 0><<<dim3(M/4), b256, 0, stream>>>(
        x1b, y, g2, be2, out, nullptr, M);
}